// Round 3
// baseline (890.983 us; speedup 1.0000x reference)
//
#include <hip/hip_runtime.h>
#include <math.h>

#define N_NODES 50000
#define N_EDGES 800000
#define E_TOTAL (N_EDGES + N_NODES)   // self-loops appended
#define N_GRAPHS 256
#define HEADS 4
#define OUT_CH 32
#define HIDDEN 128
#define NUM_LAYERS 3
#define NEG_SLOPE 0.2f
#define BN_EPS 1e-5f

// ---------------------------------------------------------------- utilities

__global__ void zero_kernel(unsigned int* __restrict__ p, int n) {
    int i = blockIdx.x * blockDim.x + threadIdx.x;
    if (i < n) p[i] = 0u;
}

// ---------------------------------------------------------------- CSR build

__global__ void hist_kernel(const int* __restrict__ dst, int* __restrict__ deg) {
    int e = blockIdx.x * blockDim.x + threadIdx.x;
    if (e >= E_TOTAL) return;
    int d = (e < N_EDGES) ? dst[e] : (e - N_EDGES);
    atomicAdd(&deg[d], 1);
}

// single-block scan, 1024 threads: chunk-serial + wave shfl-scan (2 barriers total)
__global__ __launch_bounds__(1024) void scan_kernel(const int* __restrict__ deg,
                                                    int* __restrict__ rowoff, int n) {
    const int CHUNK = (n + 1023) / 1024;
    int t = threadIdx.x;
    int beg = t * CHUNK;
    int end = min(beg + CHUNK, n);
    int sum = 0;
    for (int i = beg; i < end; ++i) sum += deg[i];
    // wave-inclusive scan of per-thread sums
    int lane = t & 63, wave = t >> 6;   // 16 waves
    int v = sum;
    for (int off = 1; off < 64; off <<= 1) {
        int u = __shfl_up(v, off);
        if (lane >= off) v += u;
    }
    __shared__ int wsum[16];
    __shared__ int wpre[16];
    if (lane == 63) wsum[wave] = v;
    __syncthreads();
    if (t == 0) {
        int c = 0;
        for (int w = 0; w < 16; ++w) { wpre[w] = c; c += wsum[w]; }
        rowoff[0] = 0;
    }
    __syncthreads();
    int excl = wpre[wave] + v - sum;    // exclusive prefix of this thread's chunk
    int run = excl;
    for (int i = beg; i < end; ++i) {
        run += deg[i];
        rowoff[i + 1] = run;
    }
}

__global__ void scatter_kernel(const int* __restrict__ src, const int* __restrict__ dst,
                               const int* __restrict__ rowoff, int* __restrict__ cursor,
                               int* __restrict__ col) {
    int e = blockIdx.x * blockDim.x + threadIdx.x;
    if (e >= E_TOTAL) return;
    int s, d;
    if (e < N_EDGES) { s = src[e]; d = dst[e]; }
    else             { s = e - N_EDGES; d = s; }
    int pos = rowoff[d] + atomicAdd(&cursor[d], 1);
    col[pos] = s;
}

// ---------------------------------------------------------------- GEMM h = X @ W (n x 128 @ 128 x 128)
// fused epilogue: alpha_src / alpha_dst per (node, head) via 8-lane butterfly

__global__ __launch_bounds__(256) void gemm_xw(const float* __restrict__ X,
                                               const float* __restrict__ W,
                                               const float* __restrict__ att_src,
                                               const float* __restrict__ att_dst,
                                               float* __restrict__ H,
                                               float* __restrict__ as4,
                                               float* __restrict__ ad4, int n) {
    __shared__ float xs[32][33];     // 32 rows x 32 k (padded)
    __shared__ float ws[32][128];    // 32 k x 128 cols
    const int row0 = blockIdx.x * 32;
    const int cg = threadIdx.x & 31;   // col group: cols cg*4..cg*4+3
    const int rg = threadIdx.x >> 5;   // row group: rows rg*4..rg*4+3
    float acc[4][4];
#pragma unroll
    for (int r = 0; r < 4; ++r)
#pragma unroll
        for (int j = 0; j < 4; ++j) acc[r][j] = 0.f;

    for (int k0 = 0; k0 < 128; k0 += 32) {
        for (int i = threadIdx.x; i < 32 * 32 / 4; i += 256) {
            int p = i * 4;
            int r = p >> 5, kk = p & 31;
            int gr = row0 + r;
            float4 v = make_float4(0.f, 0.f, 0.f, 0.f);
            if (gr < n) v = *reinterpret_cast<const float4*>(&X[gr * 128 + k0 + kk]);
            xs[r][kk + 0] = v.x; xs[r][kk + 1] = v.y; xs[r][kk + 2] = v.z; xs[r][kk + 3] = v.w;
        }
        for (int i = threadIdx.x; i < 32 * 128 / 4; i += 256) {
            int p = i * 4;
            int kk = p >> 7, cc = p & 127;
            *reinterpret_cast<float4*>(&ws[kk][cc]) =
                *reinterpret_cast<const float4*>(&W[(k0 + kk) * 128 + cc]);
        }
        __syncthreads();
#pragma unroll
        for (int kk = 0; kk < 32; ++kk) {
            float4 wv = *reinterpret_cast<const float4*>(&ws[kk][cg * 4]);
            float xv0 = xs[rg * 4 + 0][kk];
            float xv1 = xs[rg * 4 + 1][kk];
            float xv2 = xs[rg * 4 + 2][kk];
            float xv3 = xs[rg * 4 + 3][kk];
            acc[0][0] += xv0 * wv.x; acc[0][1] += xv0 * wv.y; acc[0][2] += xv0 * wv.z; acc[0][3] += xv0 * wv.w;
            acc[1][0] += xv1 * wv.x; acc[1][1] += xv1 * wv.y; acc[1][2] += xv1 * wv.z; acc[1][3] += xv1 * wv.w;
            acc[2][0] += xv2 * wv.x; acc[2][1] += xv2 * wv.y; acc[2][2] += xv2 * wv.z; acc[2][3] += xv2 * wv.w;
            acc[3][0] += xv3 * wv.x; acc[3][1] += xv3 * wv.y; acc[3][2] += xv3 * wv.z; acc[3][3] += xv3 * wv.w;
        }
        __syncthreads();
    }

    // write H tile
#pragma unroll
    for (int r = 0; r < 4; ++r) {
        int gr = row0 + rg * 4 + r;
        if (gr < n) {
            float4 v = make_float4(acc[r][0], acc[r][1], acc[r][2], acc[r][3]);
            *reinterpret_cast<float4*>(&H[gr * 128 + cg * 4]) = v;
        }
    }

    // fused attention coefficients: head h = cg>>3 covers cols [32h, 32h+32)
    const int h = cg >> 3;
    const int co = (cg & 7) * 4;
    float4 asw = *reinterpret_cast<const float4*>(att_src + h * OUT_CH + co);
    float4 adw = *reinterpret_cast<const float4*>(att_dst + h * OUT_CH + co);
#pragma unroll
    for (int r = 0; r < 4; ++r) {
        float s = acc[r][0] * asw.x + acc[r][1] * asw.y + acc[r][2] * asw.z + acc[r][3] * asw.w;
        float d = acc[r][0] * adw.x + acc[r][1] * adw.y + acc[r][2] * adw.z + acc[r][3] * adw.w;
        s += __shfl_xor(s, 1); d += __shfl_xor(d, 1);
        s += __shfl_xor(s, 2); d += __shfl_xor(d, 2);
        s += __shfl_xor(s, 4); d += __shfl_xor(d, 4);
        if ((cg & 7) == 0) {
            int gr = row0 + rg * 4 + r;
            if (gr < n) {
                as4[gr * 4 + h] = s;
                ad4[gr * 4 + h] = d;
            }
        }
    }
}

// ---------------------------------------------------------------- fused aggregation: online edge-softmax + message sum + bias + BN + ELU
// one wave (64 lanes) per destination node; lane l owns channels l and l+64

__global__ __launch_bounds__(256) void aggregate_kernel(
    const float* __restrict__ H, const float* __restrict__ as4, const float* __restrict__ ad4,
    const int* __restrict__ rowoff, const int* __restrict__ col,
    const float* __restrict__ bias, const float* __restrict__ gamma, const float* __restrict__ beta,
    const float* __restrict__ mean, const float* __restrict__ var,
    float* __restrict__ Xout, int n) {
    int wid = (blockIdx.x * blockDim.x + threadIdx.x) >> 6;
    if (wid >= n) return;
    int lane = threadIdx.x & 63;
    int c0 = lane, c1 = lane + 64;
    int h0 = lane >> 5;        // 0 or 1
    int h1 = 2 + (lane >> 5);  // 2 or 3

    float ad0 = ad4[wid * 4 + h0];
    float ad1 = ad4[wid * 4 + h1];

    int jbeg = rowoff[wid], jend = rowoff[wid + 1];

    float m0 = -INFINITY, m1 = -INFINITY;
    float s0 = 0.f, s1 = 0.f;
    float a0 = 0.f, a1 = 0.f;

    for (int base = jbeg; base < jend; base += 64) {
        int myj = base + lane;
        int mysrc = (myj < jend) ? col[myj] : 0;
        int cnt = min(64, jend - base);
        for (int t = 0; t < cnt; ++t) {
            int src = __shfl(mysrc, t);
            float asv = (lane < 4) ? as4[src * 4 + lane] : 0.f;
            float sc0 = __shfl(asv, h0) + ad0;
            float sc1 = __shfl(asv, h1) + ad1;
            sc0 = sc0 > 0.f ? sc0 : sc0 * NEG_SLOPE;
            sc1 = sc1 > 0.f ? sc1 : sc1 * NEG_SLOPE;
            float hv0 = H[(size_t)src * HIDDEN + c0];
            float hv1 = H[(size_t)src * HIDDEN + c1];
            float nm0 = fmaxf(m0, sc0);
            float e0 = expf(sc0 - nm0);
            float r0 = expf(m0 - nm0);
            s0 = s0 * r0 + e0;
            a0 = a0 * r0 + e0 * hv0;
            m0 = nm0;
            float nm1 = fmaxf(m1, sc1);
            float e1 = expf(sc1 - nm1);
            float r1 = expf(m1 - nm1);
            s1 = s1 * r1 + e1;
            a1 = a1 * r1 + e1 * hv1;
            m1 = nm1;
        }
    }

    float v0 = a0 / s0 + bias[c0];
    float v1 = a1 / s1 + bias[c1];
    v0 = (v0 - mean[c0]) * (gamma[c0] * rsqrtf(var[c0] + BN_EPS)) + beta[c0];
    v1 = (v1 - mean[c1]) * (gamma[c1] * rsqrtf(var[c1] + BN_EPS)) + beta[c1];
    v0 = v0 > 0.f ? v0 : expm1f(v0);
    v1 = v1 > 0.f ? v1 : expm1f(v1);
    Xout[(size_t)wid * HIDDEN + c0] = v0;
    Xout[(size_t)wid * HIDDEN + c1] = v1;
}

// ---------------------------------------------------------------- mean pool (sums + counts via atomics)

__global__ __launch_bounds__(256) void pool_kernel(const float* __restrict__ X,
                                                   const int* __restrict__ batch,
                                                   float* __restrict__ sums,
                                                   float* __restrict__ cnts, int n) {
    int wid = (blockIdx.x * blockDim.x + threadIdx.x) >> 6;
    if (wid >= n) return;
    int lane = threadIdx.x & 63;
    int g = batch[wid];
    atomicAdd(&sums[g * HIDDEN + lane], X[(size_t)wid * HIDDEN + lane]);
    atomicAdd(&sums[g * HIDDEN + 64 + lane], X[(size_t)wid * HIDDEN + 64 + lane]);
    if (lane == 0) atomicAdd(&cnts[g], 1.0f);
}

// ---------------------------------------------------------------- final MLP: one block (64 threads) per graph

__global__ __launch_bounds__(64) void fc_kernel(const float* __restrict__ sums,
                                                const float* __restrict__ cnts,
                                                const float* __restrict__ fc1w, const float* __restrict__ fc1b,
                                                const float* __restrict__ fc2w, const float* __restrict__ fc2b,
                                                float* __restrict__ out) {
    int g = blockIdx.x;
    int t = threadIdx.x;  // 0..63
    __shared__ float pool[128];
    __shared__ float hmid[64];
    float cnt = fmaxf(cnts[g], 1.0f);
    pool[t]      = sums[g * HIDDEN + t] / cnt;
    pool[t + 64] = sums[g * HIDDEN + 64 + t] / cnt;
    __syncthreads();
    float acc = fc1b[t];
    for (int k = 0; k < 128; ++k) acc += pool[k] * fc1w[k * 64 + t];
    hmid[t] = fmaxf(acc, 0.f);
    __syncthreads();
    if (t < 10) {
        float a = fc2b[t];
        for (int k = 0; k < 64; ++k) a += hmid[k] * fc2w[k * 10 + t];
        out[g * 10 + t] = a;
    }
}

// ---------------------------------------------------------------- launch

static inline size_t align_up(size_t x, size_t a) { return (x + a - 1) & ~(a - 1); }

extern "C" void kernel_launch(void* const* d_in, const int* in_sizes, int n_in,
                              void* d_out, int out_size, void* d_ws, size_t ws_size,
                              hipStream_t stream) {
    const float* x        = (const float*)d_in[0];
    const int*   eidx     = (const int*)d_in[1];   // [2, N_EDGES]
    const int*   batch    = (const int*)d_in[2];
    const float* W        = (const float*)d_in[3];   // [3,128,128]
    const float* att_src  = (const float*)d_in[4];   // [3,4,32]
    const float* att_dst  = (const float*)d_in[5];
    const float* bias     = (const float*)d_in[6];   // [3,128]
    const float* bn_gamma = (const float*)d_in[7];
    const float* bn_beta  = (const float*)d_in[8];
    const float* bn_mean  = (const float*)d_in[9];
    const float* bn_var   = (const float*)d_in[10];
    const float* fc1w     = (const float*)d_in[11];  // [128,64]
    const float* fc1b     = (const float*)d_in[12];
    const float* fc2w     = (const float*)d_in[13];  // [64,10]
    const float* fc2b     = (const float*)d_in[14];
    float* out = (float*)d_out;

    const int* src = eidx;
    const int* dst = eidx + N_EDGES;

    // ---- workspace layout
    char* p = (char*)d_ws;
    size_t off = 0;
    auto alloc = [&](size_t bytes) {
        size_t o = off;
        off = align_up(off + bytes, 256);
        return (void*)(p + o);
    };
    float* H       = (float*)alloc((size_t)N_NODES * HIDDEN * 4);
    float* Xbuf    = (float*)alloc((size_t)N_NODES * HIDDEN * 4);
    float* as4     = (float*)alloc((size_t)N_NODES * HEADS * 4);
    float* ad4     = (float*)alloc((size_t)N_NODES * HEADS * 4);
    float* poolbuf = (float*)alloc((size_t)(N_GRAPHS * HIDDEN + N_GRAPHS) * 4);
    int*   degcur  = (int*)alloc((size_t)2 * N_NODES * 4);
    int*   rowoff  = (int*)alloc((size_t)(N_NODES + 1) * 4);
    int*   col     = (int*)alloc((size_t)E_TOTAL * 4);
    float* sums = poolbuf;
    float* cnts = poolbuf + N_GRAPHS * HIDDEN;
    int* deg = degcur;
    int* cursor = degcur + N_NODES;
    (void)ws_size; (void)n_in; (void)in_sizes; (void)out_size;

    // ---- zero fills (deg+cursor, sums+cnts)
    zero_kernel<<<(2 * N_NODES + 255) / 256, 256, 0, stream>>>((unsigned int*)degcur, 2 * N_NODES);
    zero_kernel<<<(N_GRAPHS * HIDDEN + N_GRAPHS + 255) / 256, 256, 0, stream>>>(
        (unsigned int*)poolbuf, N_GRAPHS * HIDDEN + N_GRAPHS);

    // ---- CSR build (by destination), once per call
    hist_kernel<<<(E_TOTAL + 255) / 256, 256, 0, stream>>>(dst, deg);
    scan_kernel<<<1, 1024, 0, stream>>>(deg, rowoff, N_NODES);
    scatter_kernel<<<(E_TOTAL + 255) / 256, 256, 0, stream>>>(src, dst, rowoff, cursor, col);

    // ---- 3 GAT layers
    const float* xcur = x;
    for (int layer = 0; layer < NUM_LAYERS; ++layer) {
        const float* Wl  = W + (size_t)layer * HIDDEN * HIDDEN;
        const float* asl = att_src + (size_t)layer * HEADS * OUT_CH;
        const float* adl = att_dst + (size_t)layer * HEADS * OUT_CH;
        const float* bl  = bias + (size_t)layer * HIDDEN;
        const float* gl  = bn_gamma + (size_t)layer * HIDDEN;
        const float* btl = bn_beta + (size_t)layer * HIDDEN;
        const float* ml  = bn_mean + (size_t)layer * HIDDEN;
        const float* vl  = bn_var + (size_t)layer * HIDDEN;

        gemm_xw<<<(N_NODES + 31) / 32, 256, 0, stream>>>(xcur, Wl, asl, adl, H, as4, ad4, N_NODES);
        aggregate_kernel<<<(N_NODES * 64 + 255) / 256, 256, 0, stream>>>(
            H, as4, ad4, rowoff, col, bl, gl, btl, ml, vl, Xbuf, N_NODES);
        xcur = Xbuf;
    }

    // ---- pool + MLP
    pool_kernel<<<(N_NODES * 64 + 255) / 256, 256, 0, stream>>>(xcur, batch, sums, cnts, N_NODES);
    fc_kernel<<<N_GRAPHS, 64, 0, stream>>>(sums, cnts, fc1w, fc1b, fc2w, fc2b, out);
}

// Round 5
// 649.883 us; speedup vs baseline: 1.3710x; 1.3710x over previous
//
#include <hip/hip_runtime.h>
#include <math.h>

#define N_NODES 50000
#define N_EDGES 800000
#define E_TOTAL (N_EDGES + N_NODES)   // self-loops appended
#define N_GRAPHS 256
#define HEADS 4
#define OUT_CH 32
#define HIDDEN 128
#define NUM_LAYERS 3
#define NEG_SLOPE 0.2f
#define BN_EPS 1e-5f

// ---------------------------------------------------------------- utilities

__global__ void zero_kernel(unsigned int* __restrict__ p, int n) {
    int i = blockIdx.x * blockDim.x + threadIdx.x;
    if (i < n) p[i] = 0u;
}

// ---------------------------------------------------------------- CSR build

__global__ void hist_kernel(const int* __restrict__ dst, int* __restrict__ deg) {
    int e = blockIdx.x * blockDim.x + threadIdx.x;
    if (e >= E_TOTAL) return;
    int d = (e < N_EDGES) ? dst[e] : (e - N_EDGES);
    atomicAdd(&deg[d], 1);
}

// single-block scan, 1024 threads: chunk-serial + wave shfl-scan (2 barriers total)
__global__ __launch_bounds__(1024) void scan_kernel(const int* __restrict__ deg,
                                                    int* __restrict__ rowoff, int n) {
    const int CHUNK = (n + 1023) / 1024;
    int t = threadIdx.x;
    int beg = t * CHUNK;
    int end = min(beg + CHUNK, n);
    int sum = 0;
    for (int i = beg; i < end; ++i) sum += deg[i];
    int lane = t & 63, wave = t >> 6;   // 16 waves
    int v = sum;
    for (int off = 1; off < 64; off <<= 1) {
        int u = __shfl_up(v, off);
        if (lane >= off) v += u;
    }
    __shared__ int wsum[16];
    __shared__ int wpre[16];
    if (lane == 63) wsum[wave] = v;
    __syncthreads();
    if (t == 0) {
        int c = 0;
        for (int w = 0; w < 16; ++w) { wpre[w] = c; c += wsum[w]; }
        rowoff[0] = 0;
    }
    __syncthreads();
    int excl = wpre[wave] + v - sum;    // exclusive prefix of this thread's chunk
    int run = excl;
    for (int i = beg; i < end; ++i) {
        run += deg[i];
        rowoff[i + 1] = run;
    }
}

__global__ void scatter_kernel(const int* __restrict__ src, const int* __restrict__ dst,
                               const int* __restrict__ rowoff, int* __restrict__ cursor,
                               int* __restrict__ col) {
    int e = blockIdx.x * blockDim.x + threadIdx.x;
    if (e >= E_TOTAL) return;
    int s, d;
    if (e < N_EDGES) { s = src[e]; d = dst[e]; }
    else             { s = e - N_EDGES; d = s; }
    int pos = rowoff[d] + atomicAdd(&cursor[d], 1);
    col[pos] = s;
}

// ---------------------------------------------------------------- GEMM h = X @ W (n x 128 @ 128 x 128)
// fused epilogue: alpha_src / alpha_dst per (node, head) via 8-lane butterfly

__global__ __launch_bounds__(256) void gemm_xw(const float* __restrict__ X,
                                               const float* __restrict__ W,
                                               const float* __restrict__ att_src,
                                               const float* __restrict__ att_dst,
                                               float* __restrict__ H,
                                               float* __restrict__ as4,
                                               float* __restrict__ ad4, int n) {
    __shared__ float xs[32][33];     // 32 rows x 32 k (padded)
    __shared__ float ws[32][128];    // 32 k x 128 cols
    const int row0 = blockIdx.x * 32;
    const int cg = threadIdx.x & 31;   // col group: cols cg*4..cg*4+3
    const int rg = threadIdx.x >> 5;   // row group: rows rg*4..rg*4+3
    float acc[4][4];
#pragma unroll
    for (int r = 0; r < 4; ++r)
#pragma unroll
        for (int j = 0; j < 4; ++j) acc[r][j] = 0.f;

    for (int k0 = 0; k0 < 128; k0 += 32) {
        for (int i = threadIdx.x; i < 32 * 32 / 4; i += 256) {
            int p = i * 4;
            int r = p >> 5, kk = p & 31;
            int gr = row0 + r;
            float4 v = make_float4(0.f, 0.f, 0.f, 0.f);
            if (gr < n) v = *reinterpret_cast<const float4*>(&X[gr * 128 + k0 + kk]);
            xs[r][kk + 0] = v.x; xs[r][kk + 1] = v.y; xs[r][kk + 2] = v.z; xs[r][kk + 3] = v.w;
        }
        for (int i = threadIdx.x; i < 32 * 128 / 4; i += 256) {
            int p = i * 4;
            int kk = p >> 7, cc = p & 127;
            *reinterpret_cast<float4*>(&ws[kk][cc]) =
                *reinterpret_cast<const float4*>(&W[(k0 + kk) * 128 + cc]);
        }
        __syncthreads();
#pragma unroll
        for (int kk = 0; kk < 32; ++kk) {
            float4 wv = *reinterpret_cast<const float4*>(&ws[kk][cg * 4]);
            float xv0 = xs[rg * 4 + 0][kk];
            float xv1 = xs[rg * 4 + 1][kk];
            float xv2 = xs[rg * 4 + 2][kk];
            float xv3 = xs[rg * 4 + 3][kk];
            acc[0][0] += xv0 * wv.x; acc[0][1] += xv0 * wv.y; acc[0][2] += xv0 * wv.z; acc[0][3] += xv0 * wv.w;
            acc[1][0] += xv1 * wv.x; acc[1][1] += xv1 * wv.y; acc[1][2] += xv1 * wv.z; acc[1][3] += xv1 * wv.w;
            acc[2][0] += xv2 * wv.x; acc[2][1] += xv2 * wv.y; acc[2][2] += xv2 * wv.z; acc[2][3] += xv2 * wv.w;
            acc[3][0] += xv3 * wv.x; acc[3][1] += xv3 * wv.y; acc[3][2] += xv3 * wv.z; acc[3][3] += xv3 * wv.w;
        }
        __syncthreads();
    }

    // write H tile
#pragma unroll
    for (int r = 0; r < 4; ++r) {
        int gr = row0 + rg * 4 + r;
        if (gr < n) {
            float4 v = make_float4(acc[r][0], acc[r][1], acc[r][2], acc[r][3]);
            *reinterpret_cast<float4*>(&H[gr * 128 + cg * 4]) = v;
        }
    }

    // fused attention coefficients: head h = cg>>3 covers cols [32h, 32h+32)
    const int h = cg >> 3;
    const int co = (cg & 7) * 4;
    float4 asw = *reinterpret_cast<const float4*>(att_src + h * OUT_CH + co);
    float4 adw = *reinterpret_cast<const float4*>(att_dst + h * OUT_CH + co);
#pragma unroll
    for (int r = 0; r < 4; ++r) {
        float s = acc[r][0] * asw.x + acc[r][1] * asw.y + acc[r][2] * asw.z + acc[r][3] * asw.w;
        float d = acc[r][0] * adw.x + acc[r][1] * adw.y + acc[r][2] * adw.z + acc[r][3] * adw.w;
        s += __shfl_xor(s, 1); d += __shfl_xor(d, 1);
        s += __shfl_xor(s, 2); d += __shfl_xor(d, 2);
        s += __shfl_xor(s, 4); d += __shfl_xor(d, 4);
        if ((cg & 7) == 0) {
            int gr = row0 + rg * 4 + r;
            if (gr < n) {
                as4[gr * 4 + h] = s;
                ad4[gr * 4 + h] = d;
            }
        }
    }
}

// ---------------------------------------------------------------- fused aggregation: online edge-softmax + message sum + bias + BN + ELU
// one wave (64 lanes) per destination node; lane l owns channels l and l+64
// single-exp online update: exactly one nontrivial exp(-|sc-m|) per head per edge

__global__ __launch_bounds__(256) void aggregate_kernel(
    const float* __restrict__ H, const float* __restrict__ as4, const float* __restrict__ ad4,
    const int* __restrict__ rowoff, const int* __restrict__ col,
    const float* __restrict__ bias, const float* __restrict__ gamma, const float* __restrict__ beta,
    const float* __restrict__ mean, const float* __restrict__ var,
    float* __restrict__ Xout, int n) {
    int wid = (blockIdx.x * blockDim.x + threadIdx.x) >> 6;
    if (wid >= n) return;
    int lane = threadIdx.x & 63;
    int c0 = lane, c1 = lane + 64;
    int h0 = lane >> 5;        // 0 or 1
    int h1 = 2 + (lane >> 5);  // 2 or 3

    float ad0 = ad4[wid * 4 + h0];
    float ad1 = ad4[wid * 4 + h1];

    int jbeg = rowoff[wid], jend = rowoff[wid + 1];

    float m0 = -INFINITY, m1 = -INFINITY;
    float s0 = 0.f, s1 = 0.f;
    float a0 = 0.f, a1 = 0.f;

    for (int base = jbeg; base < jend; base += 64) {
        int myj = base + lane;
        int mysrc = (myj < jend) ? col[myj] : 0;
        int cnt = min(64, jend - base);
        for (int t = 0; t < cnt; ++t) {
            int src = __shfl(mysrc, t);
            float asv = (lane < 4) ? as4[src * 4 + lane] : 0.f;
            float sc0 = __shfl(asv, h0) + ad0;
            float sc1 = __shfl(asv, h1) + ad1;
            sc0 = sc0 > 0.f ? sc0 : sc0 * NEG_SLOPE;
            sc1 = sc1 > 0.f ? sc1 : sc1 * NEG_SLOPE;
            float hv0 = H[(size_t)src * HIDDEN + c0];
            float hv1 = H[(size_t)src * HIDDEN + c1];
            // head 0 slot: one exp
            float d0 = sc0 - m0;
            float t0 = __expf(-fabsf(d0));   // first iter: d0=+inf -> t0=0
            bool g0 = d0 > 0.f;
            float e0 = g0 ? 1.f : t0;
            float r0 = g0 ? t0 : 1.f;
            m0 = g0 ? sc0 : m0;
            s0 = s0 * r0 + e0;
            a0 = a0 * r0 + e0 * hv0;
            // head 1 slot
            float d1 = sc1 - m1;
            float t1 = __expf(-fabsf(d1));
            bool g1 = d1 > 0.f;
            float e1 = g1 ? 1.f : t1;
            float r1 = g1 ? t1 : 1.f;
            m1 = g1 ? sc1 : m1;
            s1 = s1 * r1 + e1;
            a1 = a1 * r1 + e1 * hv1;
        }
    }

    float v0 = a0 / s0 + bias[c0];
    float v1 = a1 / s1 + bias[c1];
    v0 = (v0 - mean[c0]) * (gamma[c0] * rsqrtf(var[c0] + BN_EPS)) + beta[c0];
    v1 = (v1 - mean[c1]) * (gamma[c1] * rsqrtf(var[c1] + BN_EPS)) + beta[c1];
    v0 = v0 > 0.f ? v0 : expm1f(v0);
    v1 = v1 > 0.f ? v1 : expm1f(v1);
    Xout[(size_t)wid * HIDDEN + c0] = v0;
    Xout[(size_t)wid * HIDDEN + c1] = v1;
}

// ---------------------------------------------------------------- fused mean-pool + MLP: one block (128 threads) per graph
// batch is SORTED -> each graph is a contiguous node range; no atomics.

__global__ __launch_bounds__(128) void pool_fc_kernel(
    const float* __restrict__ X, const int* __restrict__ batch,
    const float* __restrict__ fc1w, const float* __restrict__ fc1b,
    const float* __restrict__ fc2w, const float* __restrict__ fc2b,
    float* __restrict__ out) {
    int g = blockIdx.x;
    int t = threadIdx.x;  // 0..127, one channel each
    // lower_bound(batch, g) and lower_bound(batch, g+1) — uniform across threads
    int lo = 0, hi = N_NODES;
    while (lo < hi) { int mid = (lo + hi) >> 1; if (batch[mid] < g) lo = mid + 1; else hi = mid; }
    int lo2 = lo, hi2 = N_NODES;
    while (lo2 < hi2) { int mid = (lo2 + hi2) >> 1; if (batch[mid] < g + 1) lo2 = mid + 1; else hi2 = mid; }

    float s = 0.f;
    for (int i = lo; i < lo2; ++i) s += X[(size_t)i * HIDDEN + t];
    float cnt = fmaxf((float)(lo2 - lo), 1.0f);

    __shared__ float pooled[HIDDEN];
    __shared__ float hmid[64];
    pooled[t] = s / cnt;
    __syncthreads();
    if (t < 64) {
        float a = fc1b[t];
#pragma unroll 8
        for (int k = 0; k < 128; ++k) a += pooled[k] * fc1w[k * 64 + t];
        hmid[t] = fmaxf(a, 0.f);
    }
    __syncthreads();
    if (t < 10) {
        float a = fc2b[t];
#pragma unroll 8
        for (int k = 0; k < 64; ++k) a += hmid[k] * fc2w[k * 10 + t];
        out[g * 10 + t] = a;
    }
}

// ---------------------------------------------------------------- launch

static inline size_t align_up(size_t x, size_t a) { return (x + a - 1) & ~(a - 1); }

extern "C" void kernel_launch(void* const* d_in, const int* in_sizes, int n_in,
                              void* d_out, int out_size, void* d_ws, size_t ws_size,
                              hipStream_t stream) {
    const float* x        = (const float*)d_in[0];
    const int*   eidx     = (const int*)d_in[1];   // [2, N_EDGES]
    const int*   batch    = (const int*)d_in[2];
    const float* W        = (const float*)d_in[3];   // [3,128,128]
    const float* att_src  = (const float*)d_in[4];   // [3,4,32]
    const float* att_dst  = (const float*)d_in[5];
    const float* bias     = (const float*)d_in[6];   // [3,128]
    const float* bn_gamma = (const float*)d_in[7];
    const float* bn_beta  = (const float*)d_in[8];
    const float* bn_mean  = (const float*)d_in[9];
    const float* bn_var   = (const float*)d_in[10];
    const float* fc1w     = (const float*)d_in[11];  // [128,64]
    const float* fc1b     = (const float*)d_in[12];
    const float* fc2w     = (const float*)d_in[13];  // [64,10]
    const float* fc2b     = (const float*)d_in[14];
    float* out = (float*)d_out;

    const int* src = eidx;
    const int* dst = eidx + N_EDGES;

    // ---- workspace layout
    char* p = (char*)d_ws;
    size_t off = 0;
    auto alloc = [&](size_t bytes) {
        size_t o = off;
        off = align_up(off + bytes, 256);
        return (void*)(p + o);
    };
    float* H       = (float*)alloc((size_t)N_NODES * HIDDEN * 4);
    float* Xbuf    = (float*)alloc((size_t)N_NODES * HIDDEN * 4);
    float* as4     = (float*)alloc((size_t)N_NODES * HEADS * 4);
    float* ad4     = (float*)alloc((size_t)N_NODES * HEADS * 4);
    int*   degcur  = (int*)alloc((size_t)2 * N_NODES * 4);
    int*   rowoff  = (int*)alloc((size_t)(N_NODES + 1) * 4);
    int*   col     = (int*)alloc((size_t)E_TOTAL * 4);
    int* deg = degcur;
    int* cursor = degcur + N_NODES;
    (void)ws_size; (void)n_in; (void)in_sizes; (void)out_size;

    // ---- zero fill (deg+cursor)
    zero_kernel<<<(2 * N_NODES + 255) / 256, 256, 0, stream>>>((unsigned int*)degcur, 2 * N_NODES);

    // ---- CSR build (by destination), once per call
    hist_kernel<<<(E_TOTAL + 255) / 256, 256, 0, stream>>>(dst, deg);
    scan_kernel<<<1, 1024, 0, stream>>>(deg, rowoff, N_NODES);
    scatter_kernel<<<(E_TOTAL + 255) / 256, 256, 0, stream>>>(src, dst, rowoff, cursor, col);

    // ---- 3 GAT layers
    const float* xcur = x;
    for (int layer = 0; layer < NUM_LAYERS; ++layer) {
        const float* Wl  = W + (size_t)layer * HIDDEN * HIDDEN;
        const float* asl = att_src + (size_t)layer * HEADS * OUT_CH;
        const float* adl = att_dst + (size_t)layer * HEADS * OUT_CH;
        const float* bl  = bias + (size_t)layer * HIDDEN;
        const float* gl  = bn_gamma + (size_t)layer * HIDDEN;
        const float* btl = bn_beta + (size_t)layer * HIDDEN;
        const float* ml  = bn_mean + (size_t)layer * HIDDEN;
        const float* vl  = bn_var + (size_t)layer * HIDDEN;

        gemm_xw<<<(N_NODES + 31) / 32, 256, 0, stream>>>(xcur, Wl, asl, adl, H, as4, ad4, N_NODES);
        aggregate_kernel<<<(N_NODES * 64 + 255) / 256, 256, 0, stream>>>(
            H, as4, ad4, rowoff, col, bl, gl, btl, ml, vl, Xbuf, N_NODES);
        xcur = Xbuf;
    }

    // ---- fused pool + MLP (batch sorted -> contiguous ranges, no atomics)
    pool_fc_kernel<<<N_GRAPHS, 128, 0, stream>>>(xcur, batch, fc1w, fc1b, fc2w, fc2b, out);
}

// Round 6
// 629.322 us; speedup vs baseline: 1.4158x; 1.0327x over previous
//
#include <hip/hip_runtime.h>
#include <math.h>

#define N_NODES 50000
#define N_EDGES 800000
#define E_TOTAL (N_EDGES + N_NODES)   // self-loops appended
#define N_GRAPHS 256
#define HEADS 4
#define OUT_CH 32
#define HIDDEN 128
#define NUM_LAYERS 3
#define NEG_SLOPE 0.2f
#define BN_EPS 1e-5f

// ---------------------------------------------------------------- utilities

__global__ void zero_kernel(unsigned int* __restrict__ p, int n) {
    int i = blockIdx.x * blockDim.x + threadIdx.x;
    if (i < n) p[i] = 0u;
}

// ---------------------------------------------------------------- CSR build

__global__ void hist_kernel(const int* __restrict__ dst, int* __restrict__ deg) {
    int e = blockIdx.x * blockDim.x + threadIdx.x;
    if (e >= E_TOTAL) return;
    int d = (e < N_EDGES) ? dst[e] : (e - N_EDGES);
    atomicAdd(&deg[d], 1);
}

// single-block scan, 1024 threads: chunk-serial + wave shfl-scan (2 barriers total)
__global__ __launch_bounds__(1024) void scan_kernel(const int* __restrict__ deg,
                                                    int* __restrict__ rowoff, int n) {
    const int CHUNK = (n + 1023) / 1024;
    int t = threadIdx.x;
    int beg = t * CHUNK;
    int end = min(beg + CHUNK, n);
    int sum = 0;
    for (int i = beg; i < end; ++i) sum += deg[i];
    int lane = t & 63, wave = t >> 6;   // 16 waves
    int v = sum;
    for (int off = 1; off < 64; off <<= 1) {
        int u = __shfl_up(v, off);
        if (lane >= off) v += u;
    }
    __shared__ int wsum[16];
    __shared__ int wpre[16];
    if (lane == 63) wsum[wave] = v;
    __syncthreads();
    if (t == 0) {
        int c = 0;
        for (int w = 0; w < 16; ++w) { wpre[w] = c; c += wsum[w]; }
        rowoff[0] = 0;
    }
    __syncthreads();
    int excl = wpre[wave] + v - sum;    // exclusive prefix of this thread's chunk
    int run = excl;
    for (int i = beg; i < end; ++i) {
        run += deg[i];
        rowoff[i + 1] = run;
    }
}

__global__ void scatter_kernel(const int* __restrict__ src, const int* __restrict__ dst,
                               const int* __restrict__ rowoff, int* __restrict__ cursor,
                               int* __restrict__ col) {
    int e = blockIdx.x * blockDim.x + threadIdx.x;
    if (e >= E_TOTAL) return;
    int s, d;
    if (e < N_EDGES) { s = src[e]; d = dst[e]; }
    else             { s = e - N_EDGES; d = s; }
    int pos = rowoff[d] + atomicAdd(&cursor[d], 1);
    col[pos] = s;
}

// ---------------------------------------------------------------- GEMM h = X @ W (n x 128 @ 128 x 128)
// X tile stored transposed in LDS so inner loop reads are 2x ds_read_b128.
// fused epilogue: alpha_src / alpha_dst per (node, head) via 8-lane butterfly

__global__ __launch_bounds__(256) void gemm_xw(const float* __restrict__ X,
                                               const float* __restrict__ W,
                                               const float* __restrict__ att_src,
                                               const float* __restrict__ att_dst,
                                               float* __restrict__ H,
                                               float* __restrict__ as4,
                                               float* __restrict__ ad4, int n) {
    __shared__ float xst[32][36];    // [kk][r], rows 16B-aligned (36*4=144)
    __shared__ float ws[32][128];    // 32 k x 128 cols
    const int row0 = blockIdx.x * 32;
    const int cg = threadIdx.x & 31;   // col group: cols cg*4..cg*4+3
    const int rg = threadIdx.x >> 5;   // row group: rows rg*4..rg*4+3
    float acc[4][4];
#pragma unroll
    for (int r = 0; r < 4; ++r)
#pragma unroll
        for (int j = 0; j < 4; ++j) acc[r][j] = 0.f;

    for (int k0 = 0; k0 < 128; k0 += 32) {
        // stage X tile (transposed): thread tid handles row r=tid>>3, kk=(tid&7)*4
        {
            int r = threadIdx.x >> 3;
            int kk = (threadIdx.x & 7) * 4;
            int gr = row0 + r;
            float4 v = make_float4(0.f, 0.f, 0.f, 0.f);
            if (gr < n) v = *reinterpret_cast<const float4*>(&X[gr * 128 + k0 + kk]);
            xst[kk + 0][r] = v.x; xst[kk + 1][r] = v.y; xst[kk + 2][r] = v.z; xst[kk + 3][r] = v.w;
        }
        // stage W tile: 32x128
        for (int i = threadIdx.x; i < 32 * 128 / 4; i += 256) {
            int p = i * 4;
            int kk = p >> 7, cc = p & 127;
            *reinterpret_cast<float4*>(&ws[kk][cc]) =
                *reinterpret_cast<const float4*>(&W[(k0 + kk) * 128 + cc]);
        }
        __syncthreads();
#pragma unroll
        for (int kk = 0; kk < 32; ++kk) {
            float4 wv = *reinterpret_cast<const float4*>(&ws[kk][cg * 4]);
            float4 xv = *reinterpret_cast<const float4*>(&xst[kk][rg * 4]);
            acc[0][0] += xv.x * wv.x; acc[0][1] += xv.x * wv.y; acc[0][2] += xv.x * wv.z; acc[0][3] += xv.x * wv.w;
            acc[1][0] += xv.y * wv.x; acc[1][1] += xv.y * wv.y; acc[1][2] += xv.y * wv.z; acc[1][3] += xv.y * wv.w;
            acc[2][0] += xv.z * wv.x; acc[2][1] += xv.z * wv.y; acc[2][2] += xv.z * wv.z; acc[2][3] += xv.z * wv.w;
            acc[3][0] += xv.w * wv.x; acc[3][1] += xv.w * wv.y; acc[3][2] += xv.w * wv.z; acc[3][3] += xv.w * wv.w;
        }
        __syncthreads();
    }

    // write H tile
#pragma unroll
    for (int r = 0; r < 4; ++r) {
        int gr = row0 + rg * 4 + r;
        if (gr < n) {
            float4 v = make_float4(acc[r][0], acc[r][1], acc[r][2], acc[r][3]);
            *reinterpret_cast<float4*>(&H[gr * 128 + cg * 4]) = v;
        }
    }

    // fused attention coefficients: head h = cg>>3 covers cols [32h, 32h+32)
    const int h = cg >> 3;
    const int co = (cg & 7) * 4;
    float4 asw = *reinterpret_cast<const float4*>(att_src + h * OUT_CH + co);
    float4 adw = *reinterpret_cast<const float4*>(att_dst + h * OUT_CH + co);
#pragma unroll
    for (int r = 0; r < 4; ++r) {
        float s = acc[r][0] * asw.x + acc[r][1] * asw.y + acc[r][2] * asw.z + acc[r][3] * asw.w;
        float d = acc[r][0] * adw.x + acc[r][1] * adw.y + acc[r][2] * adw.z + acc[r][3] * adw.w;
        s += __shfl_xor(s, 1); d += __shfl_xor(d, 1);
        s += __shfl_xor(s, 2); d += __shfl_xor(d, 2);
        s += __shfl_xor(s, 4); d += __shfl_xor(d, 4);
        if ((cg & 7) == 0) {
            int gr = row0 + rg * 4 + r;
            if (gr < n) {
                as4[gr * 4 + h] = s;
                ad4[gr * 4 + h] = d;
            }
        }
    }
}

// ---------------------------------------------------------------- fused aggregation: edge-softmax + message sum + bias + BN + ELU
// one wave per destination node; lane l owns channels 2l, 2l+1 (head = l>>4).
// Direct exp (no max subtraction): numerator/denominator share the e^m factor,
// mathematically identical to the reference; scores are O(1) for this model.

__global__ __launch_bounds__(256) void aggregate_kernel(
    const float* __restrict__ H, const float* __restrict__ as4, const float* __restrict__ ad4,
    const int* __restrict__ rowoff, const int* __restrict__ col,
    const float* __restrict__ bias, const float* __restrict__ gamma, const float* __restrict__ beta,
    const float* __restrict__ mean, const float* __restrict__ var,
    float* __restrict__ Xout, int n) {
    int wid = (blockIdx.x * blockDim.x + threadIdx.x) >> 6;
    if (wid >= n) return;
    int lane = threadIdx.x & 63;
    int hd = lane >> 4;          // head 0..3
    int c = lane * 2;            // channels c, c+1 (same head)

    float adv = ad4[wid * 4 + hd];

    int jbeg = rowoff[wid], jend = rowoff[wid + 1];

    float s = 0.f, ax = 0.f, ay = 0.f;

    for (int base = jbeg; base < jend; base += 64) {
        int myj = base + lane;
        int mysrc = (myj < jend) ? col[myj] : 0;
        int cnt = min(64, jend - base);
        for (int t = 0; t < cnt; ++t) {
            int src = __shfl(mysrc, t);
            float sc = as4[src * 4 + hd] + adv;           // broadcast load (L2-resident)
            sc = sc > 0.f ? sc : sc * NEG_SLOPE;
            float e = __expf(sc);
            float2 hv = *reinterpret_cast<const float2*>(&H[(size_t)src * HIDDEN + c]);
            s += e;
            ax += e * hv.x;
            ay += e * hv.y;
        }
    }

    float inv = 1.f / s;
    float v0 = ax * inv + bias[c];
    float v1 = ay * inv + bias[c + 1];
    v0 = (v0 - mean[c])     * (gamma[c]     * rsqrtf(var[c]     + BN_EPS)) + beta[c];
    v1 = (v1 - mean[c + 1]) * (gamma[c + 1] * rsqrtf(var[c + 1] + BN_EPS)) + beta[c + 1];
    v0 = v0 > 0.f ? v0 : expm1f(v0);
    v1 = v1 > 0.f ? v1 : expm1f(v1);
    float2 o = make_float2(v0, v1);
    *reinterpret_cast<float2*>(&Xout[(size_t)wid * HIDDEN + c]) = o;
}

// ---------------------------------------------------------------- fused mean-pool + MLP: one block (128 threads) per graph
// batch is SORTED -> each graph is a contiguous node range; no atomics.

__global__ __launch_bounds__(128) void pool_fc_kernel(
    const float* __restrict__ X, const int* __restrict__ batch,
    const float* __restrict__ fc1w, const float* __restrict__ fc1b,
    const float* __restrict__ fc2w, const float* __restrict__ fc2b,
    float* __restrict__ out) {
    int g = blockIdx.x;
    int t = threadIdx.x;  // 0..127, one channel each
    int lo = 0, hi = N_NODES;
    while (lo < hi) { int mid = (lo + hi) >> 1; if (batch[mid] < g) lo = mid + 1; else hi = mid; }
    int lo2 = lo, hi2 = N_NODES;
    while (lo2 < hi2) { int mid = (lo2 + hi2) >> 1; if (batch[mid] < g + 1) lo2 = mid + 1; else hi2 = mid; }

    float s = 0.f;
    for (int i = lo; i < lo2; ++i) s += X[(size_t)i * HIDDEN + t];
    float cnt = fmaxf((float)(lo2 - lo), 1.0f);

    __shared__ float pooled[HIDDEN];
    __shared__ float hmid[64];
    pooled[t] = s / cnt;
    __syncthreads();
    if (t < 64) {
        float a = fc1b[t];
#pragma unroll 8
        for (int k = 0; k < 128; ++k) a += pooled[k] * fc1w[k * 64 + t];
        hmid[t] = fmaxf(a, 0.f);
    }
    __syncthreads();
    if (t < 10) {
        float a = fc2b[t];
#pragma unroll 8
        for (int k = 0; k < 64; ++k) a += hmid[k] * fc2w[k * 10 + t];
        out[g * 10 + t] = a;
    }
}

// ---------------------------------------------------------------- launch

static inline size_t align_up(size_t x, size_t a) { return (x + a - 1) & ~(a - 1); }

extern "C" void kernel_launch(void* const* d_in, const int* in_sizes, int n_in,
                              void* d_out, int out_size, void* d_ws, size_t ws_size,
                              hipStream_t stream) {
    const float* x        = (const float*)d_in[0];
    const int*   eidx     = (const int*)d_in[1];   // [2, N_EDGES]
    const int*   batch    = (const int*)d_in[2];
    const float* W        = (const float*)d_in[3];   // [3,128,128]
    const float* att_src  = (const float*)d_in[4];   // [3,4,32]
    const float* att_dst  = (const float*)d_in[5];
    const float* bias     = (const float*)d_in[6];   // [3,128]
    const float* bn_gamma = (const float*)d_in[7];
    const float* bn_beta  = (const float*)d_in[8];
    const float* bn_mean  = (const float*)d_in[9];
    const float* bn_var   = (const float*)d_in[10];
    const float* fc1w     = (const float*)d_in[11];  // [128,64]
    const float* fc1b     = (const float*)d_in[12];
    const float* fc2w     = (const float*)d_in[13];  // [64,10]
    const float* fc2b     = (const float*)d_in[14];
    float* out = (float*)d_out;

    const int* src = eidx;
    const int* dst = eidx + N_EDGES;

    // ---- workspace layout
    char* p = (char*)d_ws;
    size_t off = 0;
    auto alloc = [&](size_t bytes) {
        size_t o = off;
        off = align_up(off + bytes, 256);
        return (void*)(p + o);
    };
    float* H       = (float*)alloc((size_t)N_NODES * HIDDEN * 4);
    float* Xbuf    = (float*)alloc((size_t)N_NODES * HIDDEN * 4);
    float* as4     = (float*)alloc((size_t)N_NODES * HEADS * 4);
    float* ad4     = (float*)alloc((size_t)N_NODES * HEADS * 4);
    int*   degcur  = (int*)alloc((size_t)2 * N_NODES * 4);
    int*   rowoff  = (int*)alloc((size_t)(N_NODES + 1) * 4);
    int*   col     = (int*)alloc((size_t)E_TOTAL * 4);
    int* deg = degcur;
    int* cursor = degcur + N_NODES;
    (void)ws_size; (void)n_in; (void)in_sizes; (void)out_size;

    // ---- zero fill (deg+cursor)
    zero_kernel<<<(2 * N_NODES + 255) / 256, 256, 0, stream>>>((unsigned int*)degcur, 2 * N_NODES);

    // ---- CSR build (by destination), once per call
    hist_kernel<<<(E_TOTAL + 255) / 256, 256, 0, stream>>>(dst, deg);
    scan_kernel<<<1, 1024, 0, stream>>>(deg, rowoff, N_NODES);
    scatter_kernel<<<(E_TOTAL + 255) / 256, 256, 0, stream>>>(src, dst, rowoff, cursor, col);

    // ---- 3 GAT layers
    const float* xcur = x;
    for (int layer = 0; layer < NUM_LAYERS; ++layer) {
        const float* Wl  = W + (size_t)layer * HIDDEN * HIDDEN;
        const float* asl = att_src + (size_t)layer * HEADS * OUT_CH;
        const float* adl = att_dst + (size_t)layer * HEADS * OUT_CH;
        const float* bl  = bias + (size_t)layer * HIDDEN;
        const float* gl  = bn_gamma + (size_t)layer * HIDDEN;
        const float* btl = bn_beta + (size_t)layer * HIDDEN;
        const float* ml  = bn_mean + (size_t)layer * HIDDEN;
        const float* vl  = bn_var + (size_t)layer * HIDDEN;

        gemm_xw<<<(N_NODES + 31) / 32, 256, 0, stream>>>(xcur, Wl, asl, adl, H, as4, ad4, N_NODES);
        aggregate_kernel<<<(N_NODES * 64 + 255) / 256, 256, 0, stream>>>(
            H, as4, ad4, rowoff, col, bl, gl, btl, ml, vl, Xbuf, N_NODES);
        xcur = Xbuf;
    }

    // ---- fused pool + MLP (batch sorted -> contiguous ranges, no atomics)
    pool_fc_kernel<<<N_GRAPHS, 128, 0, stream>>>(xcur, batch, fc1w, fc1b, fc2w, fc2b, out);
}

// Round 7
// 574.431 us; speedup vs baseline: 1.5511x; 1.0956x over previous
//
#include <hip/hip_runtime.h>
#include <math.h>

#define N_NODES 50000
#define N_EDGES 800000
#define E_TOTAL (N_EDGES + N_NODES)   // self-loops appended
#define N_GRAPHS 256
#define HEADS 4
#define OUT_CH 32
#define HIDDEN 128
#define NUM_LAYERS 3
#define NEG_SLOPE 0.2f
#define BN_EPS 1e-5f
#define NBLK_SCAN ((N_NODES + 255) / 256)   // 196

// ---------------------------------------------------------------- utilities

__global__ void zero_kernel(unsigned int* __restrict__ p, int n) {
    int i = blockIdx.x * blockDim.x + threadIdx.x;
    if (i < n) p[i] = 0u;
}

// ---------------------------------------------------------------- CSR build

__global__ void hist_kernel(const int* __restrict__ dst, int* __restrict__ deg) {
    int e = blockIdx.x * blockDim.x + threadIdx.x;
    if (e >= E_TOTAL) return;
    int d = (e < N_EDGES) ? dst[e] : (e - N_EDGES);
    atomicAdd(&deg[d], 1);
}

// hierarchical scan: stage 1 — per-block inclusive scan (256 elems/block)
__global__ __launch_bounds__(256) void scan1_kernel(const int* __restrict__ deg,
                                                    int* __restrict__ rowoff,
                                                    int* __restrict__ bsum, int n) {
    int i = blockIdx.x * 256 + threadIdx.x;
    int v = (i < n) ? deg[i] : 0;
    int lane = threadIdx.x & 63, wv = threadIdx.x >> 6;
    int s = v;
    for (int off = 1; off < 64; off <<= 1) {
        int u = __shfl_up(s, off);
        if (lane >= off) s += u;
    }
    __shared__ int wtot[4];
    if (lane == 63) wtot[wv] = s;
    __syncthreads();
    int add = 0;
    for (int w = 0; w < wv; ++w) add += wtot[w];
    s += add;
    if (i < n) rowoff[i + 1] = s;
    if (threadIdx.x == 255) bsum[blockIdx.x] = s;
}

// stage 2 — single block: exclusive scan of block sums (in place)
__global__ __launch_bounds__(256) void scan2_kernel(int* __restrict__ bsum, int nb) {
    int t = threadIdx.x;
    int v = (t < nb) ? bsum[t] : 0;
    int lane = t & 63, wv = t >> 6;
    int s = v;
    for (int off = 1; off < 64; off <<= 1) {
        int u = __shfl_up(s, off);
        if (lane >= off) s += u;
    }
    __shared__ int wtot[4];
    if (lane == 63) wtot[wv] = s;
    __syncthreads();
    int add = 0;
    for (int w = 0; w < wv; ++w) add += wtot[w];
    s += add;
    if (t < nb) bsum[t] = s - v;   // exclusive
}

// stage 3 — add block prefix back
__global__ __launch_bounds__(256) void scan3_kernel(const int* __restrict__ bsum,
                                                    int* __restrict__ rowoff, int n) {
    int i = blockIdx.x * 256 + threadIdx.x;
    if (i == 0) rowoff[0] = 0;
    if (i < n) rowoff[i + 1] += bsum[blockIdx.x];
}

__global__ void scatter_kernel(const int* __restrict__ src, const int* __restrict__ dst,
                               const int* __restrict__ rowoff, int* __restrict__ cursor,
                               int* __restrict__ col, int* __restrict__ dstarr) {
    int e = blockIdx.x * blockDim.x + threadIdx.x;
    if (e >= E_TOTAL) return;
    int s, d;
    if (e < N_EDGES) { s = src[e]; d = dst[e]; }
    else             { s = e - N_EDGES; d = s; }
    int pos = rowoff[d] + atomicAdd(&cursor[d], 1);
    col[pos] = s;
    dstarr[pos] = d;
}

// ---------------------------------------------------------------- GEMM h = X @ W (n x 128 @ 128 x 128)
// X tile stored transposed in LDS so inner loop reads are 2x ds_read_b128.
// fused epilogue: alpha_src / alpha_dst per (node, head) via 8-lane butterfly

__global__ __launch_bounds__(256) void gemm_xw(const float* __restrict__ X,
                                               const float* __restrict__ W,
                                               const float* __restrict__ att_src,
                                               const float* __restrict__ att_dst,
                                               float* __restrict__ H,
                                               float* __restrict__ as4,
                                               float* __restrict__ ad4, int n) {
    __shared__ float xst[32][36];    // [kk][r], rows 16B-aligned (36*4=144)
    __shared__ float ws[32][128];    // 32 k x 128 cols
    const int row0 = blockIdx.x * 32;
    const int cg = threadIdx.x & 31;   // col group: cols cg*4..cg*4+3
    const int rg = threadIdx.x >> 5;   // row group: rows rg*4..rg*4+3
    float acc[4][4];
#pragma unroll
    for (int r = 0; r < 4; ++r)
#pragma unroll
        for (int j = 0; j < 4; ++j) acc[r][j] = 0.f;

    for (int k0 = 0; k0 < 128; k0 += 32) {
        {
            int r = threadIdx.x >> 3;
            int kk = (threadIdx.x & 7) * 4;
            int gr = row0 + r;
            float4 v = make_float4(0.f, 0.f, 0.f, 0.f);
            if (gr < n) v = *reinterpret_cast<const float4*>(&X[gr * 128 + k0 + kk]);
            xst[kk + 0][r] = v.x; xst[kk + 1][r] = v.y; xst[kk + 2][r] = v.z; xst[kk + 3][r] = v.w;
        }
        for (int i = threadIdx.x; i < 32 * 128 / 4; i += 256) {
            int p = i * 4;
            int kk = p >> 7, cc = p & 127;
            *reinterpret_cast<float4*>(&ws[kk][cc]) =
                *reinterpret_cast<const float4*>(&W[(k0 + kk) * 128 + cc]);
        }
        __syncthreads();
#pragma unroll
        for (int kk = 0; kk < 32; ++kk) {
            float4 wv = *reinterpret_cast<const float4*>(&ws[kk][cg * 4]);
            float4 xv = *reinterpret_cast<const float4*>(&xst[kk][rg * 4]);
            acc[0][0] += xv.x * wv.x; acc[0][1] += xv.x * wv.y; acc[0][2] += xv.x * wv.z; acc[0][3] += xv.x * wv.w;
            acc[1][0] += xv.y * wv.x; acc[1][1] += xv.y * wv.y; acc[1][2] += xv.y * wv.z; acc[1][3] += xv.y * wv.w;
            acc[2][0] += xv.z * wv.x; acc[2][1] += xv.z * wv.y; acc[2][2] += xv.z * wv.z; acc[2][3] += xv.z * wv.w;
            acc[3][0] += xv.w * wv.x; acc[3][1] += xv.w * wv.y; acc[3][2] += xv.w * wv.z; acc[3][3] += xv.w * wv.w;
        }
        __syncthreads();
    }

#pragma unroll
    for (int r = 0; r < 4; ++r) {
        int gr = row0 + rg * 4 + r;
        if (gr < n) {
            float4 v = make_float4(acc[r][0], acc[r][1], acc[r][2], acc[r][3]);
            *reinterpret_cast<float4*>(&H[gr * 128 + cg * 4]) = v;
        }
    }

    const int h = cg >> 3;
    const int co = (cg & 7) * 4;
    float4 asw = *reinterpret_cast<const float4*>(att_src + h * OUT_CH + co);
    float4 adw = *reinterpret_cast<const float4*>(att_dst + h * OUT_CH + co);
#pragma unroll
    for (int r = 0; r < 4; ++r) {
        float s = acc[r][0] * asw.x + acc[r][1] * asw.y + acc[r][2] * asw.z + acc[r][3] * asw.w;
        float d = acc[r][0] * adw.x + acc[r][1] * adw.y + acc[r][2] * adw.z + acc[r][3] * adw.w;
        s += __shfl_xor(s, 1); d += __shfl_xor(d, 1);
        s += __shfl_xor(s, 2); d += __shfl_xor(d, 2);
        s += __shfl_xor(s, 4); d += __shfl_xor(d, 4);
        if ((cg & 7) == 0) {
            int gr = row0 + rg * 4 + r;
            if (gr < n) {
                as4[gr * 4 + h] = s;
                ad4[gr * 4 + h] = d;
            }
        }
    }
}

// ---------------------------------------------------------------- per-edge exp-scores (all 4 heads), edge-parallel

__global__ __launch_bounds__(256) void escore_kernel(const int* __restrict__ col,
                                                     const int* __restrict__ dstarr,
                                                     const float* __restrict__ as4,
                                                     const float* __restrict__ ad4,
                                                     float* __restrict__ esc) {
    int j = blockIdx.x * blockDim.x + threadIdx.x;
    if (j >= E_TOTAL) return;
    int s = col[j], d = dstarr[j];
    float4 a = *reinterpret_cast<const float4*>(&as4[s * 4]);
    float4 b = *reinterpret_cast<const float4*>(&ad4[d * 4]);
    float x0 = a.x + b.x, x1 = a.y + b.y, x2 = a.z + b.z, x3 = a.w + b.w;
    x0 = x0 > 0.f ? x0 : x0 * NEG_SLOPE;
    x1 = x1 > 0.f ? x1 : x1 * NEG_SLOPE;
    x2 = x2 > 0.f ? x2 : x2 * NEG_SLOPE;
    x3 = x3 > 0.f ? x3 : x3 * NEG_SLOPE;
    float4 e = make_float4(__expf(x0), __expf(x1), __expf(x2), __expf(x3));
    *reinterpret_cast<float4*>(&esc[(size_t)j * 4]) = e;
}

// ---------------------------------------------------------------- fused aggregation: edge-softmax + message sum + bias + BN + ELU
// one wave per destination node; lane l owns channels 2l, 2l+1 (head = l>>4).
// USE_ESC: exp-scores precomputed per edge; else compute inline.

template <int USE_ESC>
__global__ __launch_bounds__(256) void aggregate_kernel(
    const float* __restrict__ H, const float* __restrict__ as4, const float* __restrict__ ad4,
    const float* __restrict__ esc,
    const int* __restrict__ rowoff, const int* __restrict__ col,
    const float* __restrict__ bias, const float* __restrict__ gamma, const float* __restrict__ beta,
    const float* __restrict__ mean, const float* __restrict__ var,
    float* __restrict__ Xout, int n) {
    int wid = (blockIdx.x * blockDim.x + threadIdx.x) >> 6;
    if (wid >= n) return;
    int lane = threadIdx.x & 63;
    int hd = lane >> 4;          // head 0..3
    int c = lane * 2;            // channels c, c+1 (same head)

    float adv = USE_ESC ? 0.f : ad4[wid * 4 + hd];

    int jbeg = rowoff[wid], jend = rowoff[wid + 1];

    float s = 0.f, ax = 0.f, ay = 0.f;

    for (int base = jbeg; base < jend; base += 64) {
        int myj = base + lane;
        int mysrc = (myj < jend) ? col[myj] : 0;
        int cnt = min(64, jend - base);
        for (int t = 0; t < cnt; ++t) {
            int src = __shfl(mysrc, t);
            float e;
            if (USE_ESC) {
                e = esc[(size_t)(base + t) * 4 + hd];
            } else {
                float sc = as4[src * 4 + hd] + adv;
                sc = sc > 0.f ? sc : sc * NEG_SLOPE;
                e = __expf(sc);
            }
            float2 hv = *reinterpret_cast<const float2*>(&H[(size_t)src * HIDDEN + c]);
            s += e;
            ax += e * hv.x;
            ay += e * hv.y;
        }
    }

    float inv = 1.f / s;
    float v0 = ax * inv + bias[c];
    float v1 = ay * inv + bias[c + 1];
    v0 = (v0 - mean[c])     * (gamma[c]     * rsqrtf(var[c]     + BN_EPS)) + beta[c];
    v1 = (v1 - mean[c + 1]) * (gamma[c + 1] * rsqrtf(var[c + 1] + BN_EPS)) + beta[c + 1];
    v0 = v0 > 0.f ? v0 : expm1f(v0);
    v1 = v1 > 0.f ? v1 : expm1f(v1);
    float2 o = make_float2(v0, v1);
    *reinterpret_cast<float2*>(&Xout[(size_t)wid * HIDDEN + c]) = o;
}

// ---------------------------------------------------------------- fused mean-pool + MLP: one block (128 threads) per graph
// batch is SORTED -> each graph is a contiguous node range; no atomics.

__global__ __launch_bounds__(128) void pool_fc_kernel(
    const float* __restrict__ X, const int* __restrict__ batch,
    const float* __restrict__ fc1w, const float* __restrict__ fc1b,
    const float* __restrict__ fc2w, const float* __restrict__ fc2b,
    float* __restrict__ out) {
    int g = blockIdx.x;
    int t = threadIdx.x;  // 0..127, one channel each
    int lo = 0, hi = N_NODES;
    while (lo < hi) { int mid = (lo + hi) >> 1; if (batch[mid] < g) lo = mid + 1; else hi = mid; }
    int lo2 = lo, hi2 = N_NODES;
    while (lo2 < hi2) { int mid = (lo2 + hi2) >> 1; if (batch[mid] < g + 1) lo2 = mid + 1; else hi2 = mid; }

    float s = 0.f;
    for (int i = lo; i < lo2; ++i) s += X[(size_t)i * HIDDEN + t];
    float cnt = fmaxf((float)(lo2 - lo), 1.0f);

    __shared__ float pooled[HIDDEN];
    __shared__ float hmid[64];
    pooled[t] = s / cnt;
    __syncthreads();
    if (t < 64) {
        float a = fc1b[t];
#pragma unroll 8
        for (int k = 0; k < 128; ++k) a += pooled[k] * fc1w[k * 64 + t];
        hmid[t] = fmaxf(a, 0.f);
    }
    __syncthreads();
    if (t < 10) {
        float a = fc2b[t];
#pragma unroll 8
        for (int k = 0; k < 64; ++k) a += hmid[k] * fc2w[k * 10 + t];
        out[g * 10 + t] = a;
    }
}

// ---------------------------------------------------------------- launch

static inline size_t align_up(size_t x, size_t a) { return (x + a - 1) & ~(a - 1); }

extern "C" void kernel_launch(void* const* d_in, const int* in_sizes, int n_in,
                              void* d_out, int out_size, void* d_ws, size_t ws_size,
                              hipStream_t stream) {
    const float* x        = (const float*)d_in[0];
    const int*   eidx     = (const int*)d_in[1];   // [2, N_EDGES]
    const int*   batch    = (const int*)d_in[2];
    const float* W        = (const float*)d_in[3];   // [3,128,128]
    const float* att_src  = (const float*)d_in[4];   // [3,4,32]
    const float* att_dst  = (const float*)d_in[5];
    const float* bias     = (const float*)d_in[6];   // [3,128]
    const float* bn_gamma = (const float*)d_in[7];
    const float* bn_beta  = (const float*)d_in[8];
    const float* bn_mean  = (const float*)d_in[9];
    const float* bn_var   = (const float*)d_in[10];
    const float* fc1w     = (const float*)d_in[11];  // [128,64]
    const float* fc1b     = (const float*)d_in[12];
    const float* fc2w     = (const float*)d_in[13];  // [64,10]
    const float* fc2b     = (const float*)d_in[14];
    float* out = (float*)d_out;

    const int* src = eidx;
    const int* dst = eidx + N_EDGES;

    // ---- workspace layout
    char* p = (char*)d_ws;
    size_t off = 0;
    auto alloc = [&](size_t bytes) {
        size_t o = off;
        off = align_up(off + bytes, 256);
        return (void*)(p + o);
    };
    float* H       = (float*)alloc((size_t)N_NODES * HIDDEN * 4);
    float* Xbuf    = (float*)alloc((size_t)N_NODES * HIDDEN * 4);
    float* as4     = (float*)alloc((size_t)N_NODES * HEADS * 4);
    float* ad4     = (float*)alloc((size_t)N_NODES * HEADS * 4);
    int*   degcur  = (int*)alloc((size_t)2 * N_NODES * 4);
    int*   rowoff  = (int*)alloc((size_t)(N_NODES + 1) * 4);
    int*   col     = (int*)alloc((size_t)E_TOTAL * 4);
    int*   bsum    = (int*)alloc((size_t)NBLK_SCAN * 4);
    int*   dstarr  = (int*)alloc((size_t)E_TOTAL * 4);
    float* esc     = (float*)alloc((size_t)E_TOTAL * HEADS * 4);
    const bool use_esc = (off <= ws_size);
    int* deg = degcur;
    int* cursor = degcur + N_NODES;
    (void)n_in; (void)in_sizes; (void)out_size;

    // ---- zero fill (deg+cursor)
    zero_kernel<<<(2 * N_NODES + 255) / 256, 256, 0, stream>>>((unsigned int*)degcur, 2 * N_NODES);

    // ---- CSR build (by destination), once per call
    hist_kernel<<<(E_TOTAL + 255) / 256, 256, 0, stream>>>(dst, deg);
    scan1_kernel<<<NBLK_SCAN, 256, 0, stream>>>(deg, rowoff, bsum, N_NODES);
    scan2_kernel<<<1, 256, 0, stream>>>(bsum, NBLK_SCAN);
    scan3_kernel<<<NBLK_SCAN, 256, 0, stream>>>(bsum, rowoff, N_NODES);
    scatter_kernel<<<(E_TOTAL + 255) / 256, 256, 0, stream>>>(src, dst, rowoff, cursor, col, dstarr);

    // ---- 3 GAT layers
    const float* xcur = x;
    for (int layer = 0; layer < NUM_LAYERS; ++layer) {
        const float* Wl  = W + (size_t)layer * HIDDEN * HIDDEN;
        const float* asl = att_src + (size_t)layer * HEADS * OUT_CH;
        const float* adl = att_dst + (size_t)layer * HEADS * OUT_CH;
        const float* bl  = bias + (size_t)layer * HIDDEN;
        const float* gl  = bn_gamma + (size_t)layer * HIDDEN;
        const float* btl = bn_beta + (size_t)layer * HIDDEN;
        const float* ml  = bn_mean + (size_t)layer * HIDDEN;
        const float* vl  = bn_var + (size_t)layer * HIDDEN;

        gemm_xw<<<(N_NODES + 31) / 32, 256, 0, stream>>>(xcur, Wl, asl, adl, H, as4, ad4, N_NODES);
        if (use_esc) {
            escore_kernel<<<(E_TOTAL + 255) / 256, 256, 0, stream>>>(col, dstarr, as4, ad4, esc);
            aggregate_kernel<1><<<(N_NODES * 64 + 255) / 256, 256, 0, stream>>>(
                H, as4, ad4, esc, rowoff, col, bl, gl, btl, ml, vl, Xbuf, N_NODES);
        } else {
            aggregate_kernel<0><<<(N_NODES * 64 + 255) / 256, 256, 0, stream>>>(
                H, as4, ad4, esc, rowoff, col, bl, gl, btl, ml, vl, Xbuf, N_NODES);
        }
        xcur = Xbuf;
    }

    // ---- fused pool + MLP (batch sorted -> contiguous ranges, no atomics)
    pool_fc_kernel<<<N_GRAPHS, 128, 0, stream>>>(xcur, batch, fc1w, fc1b, fc2w, fc2b, out);
}

// Round 8
// 545.810 us; speedup vs baseline: 1.6324x; 1.0524x over previous
//
#include <hip/hip_runtime.h>
#include <math.h>

#define N_NODES 50000
#define N_EDGES 800000
#define E_TOTAL (N_EDGES + N_NODES)   // self-loops appended
#define N_GRAPHS 256
#define HEADS 4
#define OUT_CH 32
#define HIDDEN 128
#define NUM_LAYERS 3
#define NEG_SLOPE 0.2f
#define BN_EPS 1e-5f
#define NBLK_SCAN ((N_NODES + 255) / 256)   // 196

// ---------------------------------------------------------------- utilities

__global__ void zero_kernel(unsigned int* __restrict__ p, int n) {
    int i = blockIdx.x * blockDim.x + threadIdx.x;
    if (i < n) p[i] = 0u;
}

// ---------------------------------------------------------------- CSR build

__global__ void hist_kernel(const int* __restrict__ dst, int* __restrict__ deg) {
    int e = blockIdx.x * blockDim.x + threadIdx.x;
    if (e >= E_TOTAL) return;
    int d = (e < N_EDGES) ? dst[e] : (e - N_EDGES);
    atomicAdd(&deg[d], 1);
}

// hierarchical scan: stage 1 — per-block inclusive scan (256 elems/block)
__global__ __launch_bounds__(256) void scan1_kernel(const int* __restrict__ deg,
                                                    int* __restrict__ rowoff,
                                                    int* __restrict__ bsum, int n) {
    int i = blockIdx.x * 256 + threadIdx.x;
    int v = (i < n) ? deg[i] : 0;
    int lane = threadIdx.x & 63, wv = threadIdx.x >> 6;
    int s = v;
    for (int off = 1; off < 64; off <<= 1) {
        int u = __shfl_up(s, off);
        if (lane >= off) s += u;
    }
    __shared__ int wtot[4];
    if (lane == 63) wtot[wv] = s;
    __syncthreads();
    int add = 0;
    for (int w = 0; w < wv; ++w) add += wtot[w];
    s += add;
    if (i < n) rowoff[i + 1] = s;
    if (threadIdx.x == 255) bsum[blockIdx.x] = s;
}

// stage 2 — single block: exclusive scan of block sums (in place)
__global__ __launch_bounds__(256) void scan2_kernel(int* __restrict__ bsum, int nb) {
    int t = threadIdx.x;
    int v = (t < nb) ? bsum[t] : 0;
    int lane = t & 63, wv = t >> 6;
    int s = v;
    for (int off = 1; off < 64; off <<= 1) {
        int u = __shfl_up(s, off);
        if (lane >= off) s += u;
    }
    __shared__ int wtot[4];
    if (lane == 63) wtot[wv] = s;
    __syncthreads();
    int add = 0;
    for (int w = 0; w < wv; ++w) add += wtot[w];
    s += add;
    if (t < nb) bsum[t] = s - v;   // exclusive
}

// stage 3 — add block prefix back
__global__ __launch_bounds__(256) void scan3_kernel(const int* __restrict__ bsum,
                                                    int* __restrict__ rowoff, int n) {
    int i = blockIdx.x * 256 + threadIdx.x;
    if (i == 0) rowoff[0] = 0;
    if (i < n) rowoff[i + 1] += bsum[blockIdx.x];
}

__global__ void scatter_kernel(const int* __restrict__ src, const int* __restrict__ dst,
                               const int* __restrict__ rowoff, int* __restrict__ cursor,
                               int* __restrict__ col, int* __restrict__ dstarr) {
    int e = blockIdx.x * blockDim.x + threadIdx.x;
    if (e >= E_TOTAL) return;
    int s, d;
    if (e < N_EDGES) { s = src[e]; d = dst[e]; }
    else             { s = e - N_EDGES; d = s; }
    int pos = rowoff[d] + atomicAdd(&cursor[d], 1);
    col[pos] = s;
    dstarr[pos] = d;
}

// ---------------------------------------------------------------- GEMM h = X @ W (n x 128 @ 128 x 128)
// X tile stored transposed in LDS (XOR-swizzled row groups: conflict-free staging
// writes, reads stay broadcast). Inner loop: 2x ds_read_b128 + 16 FMA.
// fused epilogue: alpha_src / alpha_dst per (node, head) via 8-lane butterfly

__global__ __launch_bounds__(256) void gemm_xw(const float* __restrict__ X,
                                               const float* __restrict__ W,
                                               const float* __restrict__ att_src,
                                               const float* __restrict__ att_dst,
                                               float* __restrict__ H,
                                               float* __restrict__ as4,
                                               float* __restrict__ ad4, int n) {
    __shared__ float xst[32][36];    // [kk][swizzled r]
    __shared__ float ws[32][128];    // 32 k x 128 cols
    const int row0 = blockIdx.x * 32;
    const int cg = threadIdx.x & 31;   // col group: cols cg*4..cg*4+3
    const int rg = threadIdx.x >> 5;   // row group: rows rg*4..rg*4+3
    float acc[4][4];
#pragma unroll
    for (int r = 0; r < 4; ++r)
#pragma unroll
        for (int j = 0; j < 4; ++j) acc[r][j] = 0.f;

    for (int k0 = 0; k0 < 128; k0 += 32) {
        {
            int r = threadIdx.x >> 3;          // 0..31
            int kk = (threadIdx.x & 7) * 4;    // 0,4,..,28
            int swz = (kk >> 2) & 7;           // uniform for kk..kk+3
            int cswz = (((r >> 2) ^ swz) << 2) | (r & 3);
            int gr = row0 + r;
            float4 v = make_float4(0.f, 0.f, 0.f, 0.f);
            if (gr < n) v = *reinterpret_cast<const float4*>(&X[gr * 128 + k0 + kk]);
            xst[kk + 0][cswz] = v.x; xst[kk + 1][cswz] = v.y;
            xst[kk + 2][cswz] = v.z; xst[kk + 3][cswz] = v.w;
        }
        for (int i = threadIdx.x; i < 32 * 128 / 4; i += 256) {
            int p = i * 4;
            int kk = p >> 7, cc = p & 127;
            *reinterpret_cast<float4*>(&ws[kk][cc]) =
                *reinterpret_cast<const float4*>(&W[(k0 + kk) * 128 + cc]);
        }
        __syncthreads();
#pragma unroll
        for (int kk = 0; kk < 32; ++kk) {
            const int swz = (kk >> 2) & 7;
            float4 wv = *reinterpret_cast<const float4*>(&ws[kk][cg * 4]);
            float4 xv = *reinterpret_cast<const float4*>(&xst[kk][((rg ^ swz) << 2)]);
            acc[0][0] += xv.x * wv.x; acc[0][1] += xv.x * wv.y; acc[0][2] += xv.x * wv.z; acc[0][3] += xv.x * wv.w;
            acc[1][0] += xv.y * wv.x; acc[1][1] += xv.y * wv.y; acc[1][2] += xv.y * wv.z; acc[1][3] += xv.y * wv.w;
            acc[2][0] += xv.z * wv.x; acc[2][1] += xv.z * wv.y; acc[2][2] += xv.z * wv.z; acc[2][3] += xv.z * wv.w;
            acc[3][0] += xv.w * wv.x; acc[3][1] += xv.w * wv.y; acc[3][2] += xv.w * wv.z; acc[3][3] += xv.w * wv.w;
        }
        __syncthreads();
    }

#pragma unroll
    for (int r = 0; r < 4; ++r) {
        int gr = row0 + rg * 4 + r;
        if (gr < n) {
            float4 v = make_float4(acc[r][0], acc[r][1], acc[r][2], acc[r][3]);
            *reinterpret_cast<float4*>(&H[gr * 128 + cg * 4]) = v;
        }
    }

    const int h = cg >> 3;
    const int co = (cg & 7) * 4;
    float4 asw = *reinterpret_cast<const float4*>(att_src + h * OUT_CH + co);
    float4 adw = *reinterpret_cast<const float4*>(att_dst + h * OUT_CH + co);
#pragma unroll
    for (int r = 0; r < 4; ++r) {
        float s = acc[r][0] * asw.x + acc[r][1] * asw.y + acc[r][2] * asw.z + acc[r][3] * asw.w;
        float d = acc[r][0] * adw.x + acc[r][1] * adw.y + acc[r][2] * adw.z + acc[r][3] * adw.w;
        s += __shfl_xor(s, 1); d += __shfl_xor(d, 1);
        s += __shfl_xor(s, 2); d += __shfl_xor(d, 2);
        s += __shfl_xor(s, 4); d += __shfl_xor(d, 4);
        if ((cg & 7) == 0) {
            int gr = row0 + rg * 4 + r;
            if (gr < n) {
                as4[gr * 4 + h] = s;
                ad4[gr * 4 + h] = d;
            }
        }
    }
}

// ---------------------------------------------------------------- per-edge exp-scores (all 4 heads), edge-parallel

__global__ __launch_bounds__(256) void escore_kernel(const int* __restrict__ col,
                                                     const int* __restrict__ dstarr,
                                                     const float* __restrict__ as4,
                                                     const float* __restrict__ ad4,
                                                     float* __restrict__ esc) {
    int j = blockIdx.x * blockDim.x + threadIdx.x;
    if (j >= E_TOTAL) return;
    int s = col[j], d = dstarr[j];
    float4 a = *reinterpret_cast<const float4*>(&as4[s * 4]);
    float4 b = *reinterpret_cast<const float4*>(&ad4[d * 4]);
    float x0 = a.x + b.x, x1 = a.y + b.y, x2 = a.z + b.z, x3 = a.w + b.w;
    x0 = x0 > 0.f ? x0 : x0 * NEG_SLOPE;
    x1 = x1 > 0.f ? x1 : x1 * NEG_SLOPE;
    x2 = x2 > 0.f ? x2 : x2 * NEG_SLOPE;
    x3 = x3 > 0.f ? x3 : x3 * NEG_SLOPE;
    float4 e = make_float4(__expf(x0), __expf(x1), __expf(x2), __expf(x3));
    *reinterpret_cast<float4*>(&esc[(size_t)j * 4]) = e;
}

// ---------------------------------------------------------------- fused aggregation: edge-softmax + message sum + bias + BN + ELU
// one wave per destination node; lane l owns channels 2l, 2l+1 (head = l>>4).
// 4-wide unrolled inner loop: batch shfls + esc + H loads before FMAs (MLP).

template <int USE_ESC>
__global__ __launch_bounds__(256) void aggregate_kernel(
    const float* __restrict__ H, const float* __restrict__ as4, const float* __restrict__ ad4,
    const float* __restrict__ esc,
    const int* __restrict__ rowoff, const int* __restrict__ col,
    const float* __restrict__ bias, const float* __restrict__ gamma, const float* __restrict__ beta,
    const float* __restrict__ mean, const float* __restrict__ var,
    float* __restrict__ Xout, int n) {
    int wid = (blockIdx.x * blockDim.x + threadIdx.x) >> 6;
    if (wid >= n) return;
    int lane = threadIdx.x & 63;
    int hd = lane >> 4;          // head 0..3
    int c = lane * 2;            // channels c, c+1 (same head)

    float adv = USE_ESC ? 0.f : ad4[wid * 4 + hd];

    int jbeg = rowoff[wid], jend = rowoff[wid + 1];

    float s = 0.f, ax = 0.f, ay = 0.f;

    for (int base = jbeg; base < jend; base += 64) {
        int myj = base + lane;
        int mysrc = (myj < jend) ? col[myj] : 0;
        int cnt = min(64, jend - base);
        int t = 0;
        if (USE_ESC) {
#pragma unroll 1
            for (; t + 4 <= cnt; t += 4) {
                int s0 = __shfl(mysrc, t + 0);
                int s1 = __shfl(mysrc, t + 1);
                int s2 = __shfl(mysrc, t + 2);
                int s3 = __shfl(mysrc, t + 3);
                float e0 = esc[(size_t)(base + t + 0) * 4 + hd];
                float e1 = esc[(size_t)(base + t + 1) * 4 + hd];
                float e2 = esc[(size_t)(base + t + 2) * 4 + hd];
                float e3 = esc[(size_t)(base + t + 3) * 4 + hd];
                float2 h0 = *reinterpret_cast<const float2*>(&H[(size_t)s0 * HIDDEN + c]);
                float2 h1 = *reinterpret_cast<const float2*>(&H[(size_t)s1 * HIDDEN + c]);
                float2 h2 = *reinterpret_cast<const float2*>(&H[(size_t)s2 * HIDDEN + c]);
                float2 h3 = *reinterpret_cast<const float2*>(&H[(size_t)s3 * HIDDEN + c]);
                s  += (e0 + e1) + (e2 + e3);
                ax += e0 * h0.x + e1 * h1.x + e2 * h2.x + e3 * h3.x;
                ay += e0 * h0.y + e1 * h1.y + e2 * h2.y + e3 * h3.y;
            }
        }
        for (; t < cnt; ++t) {
            int src = __shfl(mysrc, t);
            float e;
            if (USE_ESC) {
                e = esc[(size_t)(base + t) * 4 + hd];
            } else {
                float sc = as4[src * 4 + hd] + adv;
                sc = sc > 0.f ? sc : sc * NEG_SLOPE;
                e = __expf(sc);
            }
            float2 hv = *reinterpret_cast<const float2*>(&H[(size_t)src * HIDDEN + c]);
            s += e;
            ax += e * hv.x;
            ay += e * hv.y;
        }
    }

    float inv = 1.f / s;
    float v0 = ax * inv + bias[c];
    float v1 = ay * inv + bias[c + 1];
    v0 = (v0 - mean[c])     * (gamma[c]     * rsqrtf(var[c]     + BN_EPS)) + beta[c];
    v1 = (v1 - mean[c + 1]) * (gamma[c + 1] * rsqrtf(var[c + 1] + BN_EPS)) + beta[c + 1];
    v0 = v0 > 0.f ? v0 : expm1f(v0);
    v1 = v1 > 0.f ? v1 : expm1f(v1);
    float2 o = make_float2(v0, v1);
    *reinterpret_cast<float2*>(&Xout[(size_t)wid * HIDDEN + c]) = o;
}

// ---------------------------------------------------------------- fused mean-pool + MLP: one block (128 threads) per graph
// batch is SORTED -> each graph is a contiguous node range; no atomics.

__global__ __launch_bounds__(128) void pool_fc_kernel(
    const float* __restrict__ X, const int* __restrict__ batch,
    const float* __restrict__ fc1w, const float* __restrict__ fc1b,
    const float* __restrict__ fc2w, const float* __restrict__ fc2b,
    float* __restrict__ out) {
    int g = blockIdx.x;
    int t = threadIdx.x;  // 0..127, one channel each
    int lo = 0, hi = N_NODES;
    while (lo < hi) { int mid = (lo + hi) >> 1; if (batch[mid] < g) lo = mid + 1; else hi = mid; }
    int lo2 = lo, hi2 = N_NODES;
    while (lo2 < hi2) { int mid = (lo2 + hi2) >> 1; if (batch[mid] < g + 1) lo2 = mid + 1; else hi2 = mid; }

    float s = 0.f;
    for (int i = lo; i < lo2; ++i) s += X[(size_t)i * HIDDEN + t];
    float cnt = fmaxf((float)(lo2 - lo), 1.0f);

    __shared__ float pooled[HIDDEN];
    __shared__ float hmid[64];
    pooled[t] = s / cnt;
    __syncthreads();
    if (t < 64) {
        float a = fc1b[t];
#pragma unroll 8
        for (int k = 0; k < 128; ++k) a += pooled[k] * fc1w[k * 64 + t];
        hmid[t] = fmaxf(a, 0.f);
    }
    __syncthreads();
    if (t < 10) {
        float a = fc2b[t];
#pragma unroll 8
        for (int k = 0; k < 64; ++k) a += hmid[k] * fc2w[k * 10 + t];
        out[g * 10 + t] = a;
    }
}

// ---------------------------------------------------------------- launch

static inline size_t align_up(size_t x, size_t a) { return (x + a - 1) & ~(a - 1); }

extern "C" void kernel_launch(void* const* d_in, const int* in_sizes, int n_in,
                              void* d_out, int out_size, void* d_ws, size_t ws_size,
                              hipStream_t stream) {
    const float* x        = (const float*)d_in[0];
    const int*   eidx     = (const int*)d_in[1];   // [2, N_EDGES]
    const int*   batch    = (const int*)d_in[2];
    const float* W        = (const float*)d_in[3];   // [3,128,128]
    const float* att_src  = (const float*)d_in[4];   // [3,4,32]
    const float* att_dst  = (const float*)d_in[5];
    const float* bias     = (const float*)d_in[6];   // [3,128]
    const float* bn_gamma = (const float*)d_in[7];
    const float* bn_beta  = (const float*)d_in[8];
    const float* bn_mean  = (const float*)d_in[9];
    const float* bn_var   = (const float*)d_in[10];
    const float* fc1w     = (const float*)d_in[11];  // [128,64]
    const float* fc1b     = (const float*)d_in[12];
    const float* fc2w     = (const float*)d_in[13];  // [64,10]
    const float* fc2b     = (const float*)d_in[14];
    float* out = (float*)d_out;

    const int* src = eidx;
    const int* dst = eidx + N_EDGES;

    // ---- workspace layout
    char* p = (char*)d_ws;
    size_t off = 0;
    auto alloc = [&](size_t bytes) {
        size_t o = off;
        off = align_up(off + bytes, 256);
        return (void*)(p + o);
    };
    float* H       = (float*)alloc((size_t)N_NODES * HIDDEN * 4);
    float* Xbuf    = (float*)alloc((size_t)N_NODES * HIDDEN * 4);
    float* as4     = (float*)alloc((size_t)N_NODES * HEADS * 4);
    float* ad4     = (float*)alloc((size_t)N_NODES * HEADS * 4);
    int*   degcur  = (int*)alloc((size_t)2 * N_NODES * 4);
    int*   rowoff  = (int*)alloc((size_t)(N_NODES + 1) * 4);
    int*   col     = (int*)alloc((size_t)E_TOTAL * 4);
    int*   bsum    = (int*)alloc((size_t)NBLK_SCAN * 4);
    int*   dstarr  = (int*)alloc((size_t)E_TOTAL * 4);
    float* esc     = (float*)alloc((size_t)E_TOTAL * HEADS * 4);
    const bool use_esc = (off <= ws_size);
    int* deg = degcur;
    int* cursor = degcur + N_NODES;
    (void)n_in; (void)in_sizes; (void)out_size;

    // ---- zero fill (deg+cursor)
    zero_kernel<<<(2 * N_NODES + 255) / 256, 256, 0, stream>>>((unsigned int*)degcur, 2 * N_NODES);

    // ---- CSR build (by destination), once per call
    hist_kernel<<<(E_TOTAL + 255) / 256, 256, 0, stream>>>(dst, deg);
    scan1_kernel<<<NBLK_SCAN, 256, 0, stream>>>(deg, rowoff, bsum, N_NODES);
    scan2_kernel<<<1, 256, 0, stream>>>(bsum, NBLK_SCAN);
    scan3_kernel<<<NBLK_SCAN, 256, 0, stream>>>(bsum, rowoff, N_NODES);
    scatter_kernel<<<(E_TOTAL + 255) / 256, 256, 0, stream>>>(src, dst, rowoff, cursor, col, dstarr);

    // ---- 3 GAT layers
    const float* xcur = x;
    for (int layer = 0; layer < NUM_LAYERS; ++layer) {
        const float* Wl  = W + (size_t)layer * HIDDEN * HIDDEN;
        const float* asl = att_src + (size_t)layer * HEADS * OUT_CH;
        const float* adl = att_dst + (size_t)layer * HEADS * OUT_CH;
        const float* bl  = bias + (size_t)layer * HIDDEN;
        const float* gl  = bn_gamma + (size_t)layer * HIDDEN;
        const float* btl = bn_beta + (size_t)layer * HIDDEN;
        const float* ml  = bn_mean + (size_t)layer * HIDDEN;
        const float* vl  = bn_var + (size_t)layer * HIDDEN;

        gemm_xw<<<(N_NODES + 31) / 32, 256, 0, stream>>>(xcur, Wl, asl, adl, H, as4, ad4, N_NODES);
        if (use_esc) {
            escore_kernel<<<(E_TOTAL + 255) / 256, 256, 0, stream>>>(col, dstarr, as4, ad4, esc);
            aggregate_kernel<1><<<(N_NODES * 64 + 255) / 256, 256, 0, stream>>>(
                H, as4, ad4, esc, rowoff, col, bl, gl, btl, ml, vl, Xbuf, N_NODES);
        } else {
            aggregate_kernel<0><<<(N_NODES * 64 + 255) / 256, 256, 0, stream>>>(
                H, as4, ad4, esc, rowoff, col, bl, gl, btl, ml, vl, Xbuf, N_NODES);
        }
        xcur = Xbuf;
    }

    // ---- fused pool + MLP (batch sorted -> contiguous ranges, no atomics)
    pool_fc_kernel<<<N_GRAPHS, 128, 0, stream>>>(xcur, batch, fc1w, fc1b, fc2w, fc2b, out);
}

// Round 9
// 509.722 us; speedup vs baseline: 1.7480x; 1.0708x over previous
//
#include <hip/hip_runtime.h>
#include <math.h>

#define N_NODES 50000
#define N_EDGES 800000
#define E_TOTAL (N_EDGES + N_NODES)   // self-loops appended
#define N_GRAPHS 256
#define HEADS 4
#define OUT_CH 32
#define HIDDEN 128
#define NUM_LAYERS 3
#define NEG_SLOPE 0.2f
#define BN_EPS 1e-5f
#define NBLK_SCAN ((N_NODES + 255) / 256)   // 196

// ---------------------------------------------------------------- utilities

__global__ void zero_kernel(unsigned int* __restrict__ p, int n) {
    int i = blockIdx.x * blockDim.x + threadIdx.x;
    if (i < n) p[i] = 0u;
}

// ---------------------------------------------------------------- CSR build

__global__ void hist_kernel(const int* __restrict__ dst, int* __restrict__ deg) {
    int e = blockIdx.x * blockDim.x + threadIdx.x;
    if (e >= E_TOTAL) return;
    int d = (e < N_EDGES) ? dst[e] : (e - N_EDGES);
    atomicAdd(&deg[d], 1);
}

// hierarchical scan: stage 1 — per-block inclusive scan (256 elems/block)
__global__ __launch_bounds__(256) void scan1_kernel(const int* __restrict__ deg,
                                                    int* __restrict__ rowoff,
                                                    int* __restrict__ bsum, int n) {
    int i = blockIdx.x * 256 + threadIdx.x;
    int v = (i < n) ? deg[i] : 0;
    int lane = threadIdx.x & 63, wv = threadIdx.x >> 6;
    int s = v;
    for (int off = 1; off < 64; off <<= 1) {
        int u = __shfl_up(s, off);
        if (lane >= off) s += u;
    }
    __shared__ int wtot[4];
    if (lane == 63) wtot[wv] = s;
    __syncthreads();
    int add = 0;
    for (int w = 0; w < wv; ++w) add += wtot[w];
    s += add;
    if (i < n) rowoff[i + 1] = s;
    if (threadIdx.x == 255) bsum[blockIdx.x] = s;
}

// stage 2 — single block: exclusive scan of block sums (in place)
__global__ __launch_bounds__(256) void scan2_kernel(int* __restrict__ bsum, int nb) {
    int t = threadIdx.x;
    int v = (t < nb) ? bsum[t] : 0;
    int lane = t & 63, wv = t >> 6;
    int s = v;
    for (int off = 1; off < 64; off <<= 1) {
        int u = __shfl_up(s, off);
        if (lane >= off) s += u;
    }
    __shared__ int wtot[4];
    if (lane == 63) wtot[wv] = s;
    __syncthreads();
    int add = 0;
    for (int w = 0; w < wv; ++w) add += wtot[w];
    s += add;
    if (t < nb) bsum[t] = s - v;   // exclusive
}

// stage 3 — add block prefix back
__global__ __launch_bounds__(256) void scan3_kernel(const int* __restrict__ bsum,
                                                    int* __restrict__ rowoff, int n) {
    int i = blockIdx.x * 256 + threadIdx.x;
    if (i == 0) rowoff[0] = 0;
    if (i < n) rowoff[i + 1] += bsum[blockIdx.x];
}

__global__ void scatter_kernel(const int* __restrict__ src, const int* __restrict__ dst,
                               const int* __restrict__ rowoff, int* __restrict__ cursor,
                               int* __restrict__ col, int* __restrict__ dstarr) {
    int e = blockIdx.x * blockDim.x + threadIdx.x;
    if (e >= E_TOTAL) return;
    int s, d;
    if (e < N_EDGES) { s = src[e]; d = dst[e]; }
    else             { s = e - N_EDGES; d = s; }
    int pos = rowoff[d] + atomicAdd(&cursor[d], 1);
    col[pos] = s;
    dstarr[pos] = d;
}

// ---------------------------------------------------------------- GEMM h = X @ W (n x 128 @ 128 x 128)
// X tile stored transposed in LDS (XOR-swizzled row groups: conflict-free staging
// writes, reads stay broadcast). Inner loop: 2x ds_read_b128 + 16 FMA.
// fused epilogue: alpha_src / alpha_dst per (node, head) via 8-lane butterfly

__global__ __launch_bounds__(256) void gemm_xw(const float* __restrict__ X,
                                               const float* __restrict__ W,
                                               const float* __restrict__ att_src,
                                               const float* __restrict__ att_dst,
                                               float* __restrict__ H,
                                               float* __restrict__ as4,
                                               float* __restrict__ ad4, int n) {
    __shared__ float xst[32][36];    // [kk][swizzled r]
    __shared__ float ws[32][128];    // 32 k x 128 cols
    const int row0 = blockIdx.x * 32;
    const int cg = threadIdx.x & 31;   // col group: cols cg*4..cg*4+3
    const int rg = threadIdx.x >> 5;   // row group: rows rg*4..rg*4+3
    float acc[4][4];
#pragma unroll
    for (int r = 0; r < 4; ++r)
#pragma unroll
        for (int j = 0; j < 4; ++j) acc[r][j] = 0.f;

    for (int k0 = 0; k0 < 128; k0 += 32) {
        {
            int r = threadIdx.x >> 3;          // 0..31
            int kk = (threadIdx.x & 7) * 4;    // 0,4,..,28
            int swz = (kk >> 2) & 7;           // uniform for kk..kk+3
            int cswz = (((r >> 2) ^ swz) << 2) | (r & 3);
            int gr = row0 + r;
            float4 v = make_float4(0.f, 0.f, 0.f, 0.f);
            if (gr < n) v = *reinterpret_cast<const float4*>(&X[gr * 128 + k0 + kk]);
            xst[kk + 0][cswz] = v.x; xst[kk + 1][cswz] = v.y;
            xst[kk + 2][cswz] = v.z; xst[kk + 3][cswz] = v.w;
        }
        for (int i = threadIdx.x; i < 32 * 128 / 4; i += 256) {
            int p = i * 4;
            int kk = p >> 7, cc = p & 127;
            *reinterpret_cast<float4*>(&ws[kk][cc]) =
                *reinterpret_cast<const float4*>(&W[(k0 + kk) * 128 + cc]);
        }
        __syncthreads();
#pragma unroll
        for (int kk = 0; kk < 32; ++kk) {
            const int swz = (kk >> 2) & 7;
            float4 wv = *reinterpret_cast<const float4*>(&ws[kk][cg * 4]);
            float4 xv = *reinterpret_cast<const float4*>(&xst[kk][((rg ^ swz) << 2)]);
            acc[0][0] += xv.x * wv.x; acc[0][1] += xv.x * wv.y; acc[0][2] += xv.x * wv.z; acc[0][3] += xv.x * wv.w;
            acc[1][0] += xv.y * wv.x; acc[1][1] += xv.y * wv.y; acc[1][2] += xv.y * wv.z; acc[1][3] += xv.y * wv.w;
            acc[2][0] += xv.z * wv.x; acc[2][1] += xv.z * wv.y; acc[2][2] += xv.z * wv.z; acc[2][3] += xv.z * wv.w;
            acc[3][0] += xv.w * wv.x; acc[3][1] += xv.w * wv.y; acc[3][2] += xv.w * wv.z; acc[3][3] += xv.w * wv.w;
        }
        __syncthreads();
    }

#pragma unroll
    for (int r = 0; r < 4; ++r) {
        int gr = row0 + rg * 4 + r;
        if (gr < n) {
            float4 v = make_float4(acc[r][0], acc[r][1], acc[r][2], acc[r][3]);
            *reinterpret_cast<float4*>(&H[gr * 128 + cg * 4]) = v;
        }
    }

    const int h = cg >> 3;
    const int co = (cg & 7) * 4;
    float4 asw = *reinterpret_cast<const float4*>(att_src + h * OUT_CH + co);
    float4 adw = *reinterpret_cast<const float4*>(att_dst + h * OUT_CH + co);
#pragma unroll
    for (int r = 0; r < 4; ++r) {
        float s = acc[r][0] * asw.x + acc[r][1] * asw.y + acc[r][2] * asw.z + acc[r][3] * asw.w;
        float d = acc[r][0] * adw.x + acc[r][1] * adw.y + acc[r][2] * adw.z + acc[r][3] * adw.w;
        s += __shfl_xor(s, 1); d += __shfl_xor(d, 1);
        s += __shfl_xor(s, 2); d += __shfl_xor(d, 2);
        s += __shfl_xor(s, 4); d += __shfl_xor(d, 4);
        if ((cg & 7) == 0) {
            int gr = row0 + rg * 4 + r;
            if (gr < n) {
                as4[gr * 4 + h] = s;
                ad4[gr * 4 + h] = d;
            }
        }
    }
}

// ---------------------------------------------------------------- per-edge exp-scores (all 4 heads), edge-parallel

__global__ __launch_bounds__(256) void escore_kernel(const int* __restrict__ col,
                                                     const int* __restrict__ dstarr,
                                                     const float* __restrict__ as4,
                                                     const float* __restrict__ ad4,
                                                     float* __restrict__ esc) {
    int j = blockIdx.x * blockDim.x + threadIdx.x;
    if (j >= E_TOTAL) return;
    int s = col[j], d = dstarr[j];
    float4 a = *reinterpret_cast<const float4*>(&as4[s * 4]);
    float4 b = *reinterpret_cast<const float4*>(&ad4[d * 4]);
    float x0 = a.x + b.x, x1 = a.y + b.y, x2 = a.z + b.z, x3 = a.w + b.w;
    x0 = x0 > 0.f ? x0 : x0 * NEG_SLOPE;
    x1 = x1 > 0.f ? x1 : x1 * NEG_SLOPE;
    x2 = x2 > 0.f ? x2 : x2 * NEG_SLOPE;
    x3 = x3 > 0.f ? x3 : x3 * NEG_SLOPE;
    float4 e = make_float4(__expf(x0), __expf(x1), __expf(x2), __expf(x3));
    *reinterpret_cast<float4*>(&esc[(size_t)j * 4]) = e;
}

// ---------------------------------------------------------------- fused aggregation: edge-softmax + message sum + bias + BN + ELU
// one wave per destination node; lane l owns channels 2l, 2l+1 (head = l>>4).
// 8-wide unrolled inner loop: batch shfls + esc + H loads before FMAs (MLP).

template <int USE_ESC>
__global__ __launch_bounds__(256) void aggregate_kernel(
    const float* __restrict__ H, const float* __restrict__ as4, const float* __restrict__ ad4,
    const float* __restrict__ esc,
    const int* __restrict__ rowoff, const int* __restrict__ col,
    const float* __restrict__ bias, const float* __restrict__ gamma, const float* __restrict__ beta,
    const float* __restrict__ mean, const float* __restrict__ var,
    float* __restrict__ Xout, int n) {
    int wid = (blockIdx.x * blockDim.x + threadIdx.x) >> 6;
    if (wid >= n) return;
    int lane = threadIdx.x & 63;
    int hd = lane >> 4;          // head 0..3
    int c = lane * 2;            // channels c, c+1 (same head)

    float adv = USE_ESC ? 0.f : ad4[wid * 4 + hd];

    int jbeg = rowoff[wid], jend = rowoff[wid + 1];

    float s = 0.f, ax = 0.f, ay = 0.f;

    for (int base = jbeg; base < jend; base += 64) {
        int myj = base + lane;
        int mysrc = (myj < jend) ? col[myj] : 0;
        int cnt = min(64, jend - base);
        int t = 0;
        if (USE_ESC) {
#pragma unroll 1
            for (; t + 8 <= cnt; t += 8) {
                int s0 = __shfl(mysrc, t + 0);
                int s1 = __shfl(mysrc, t + 1);
                int s2 = __shfl(mysrc, t + 2);
                int s3 = __shfl(mysrc, t + 3);
                int s4 = __shfl(mysrc, t + 4);
                int s5 = __shfl(mysrc, t + 5);
                int s6 = __shfl(mysrc, t + 6);
                int s7 = __shfl(mysrc, t + 7);
                float e0 = esc[(size_t)(base + t + 0) * 4 + hd];
                float e1 = esc[(size_t)(base + t + 1) * 4 + hd];
                float e2 = esc[(size_t)(base + t + 2) * 4 + hd];
                float e3 = esc[(size_t)(base + t + 3) * 4 + hd];
                float e4 = esc[(size_t)(base + t + 4) * 4 + hd];
                float e5 = esc[(size_t)(base + t + 5) * 4 + hd];
                float e6 = esc[(size_t)(base + t + 6) * 4 + hd];
                float e7 = esc[(size_t)(base + t + 7) * 4 + hd];
                float2 h0 = *reinterpret_cast<const float2*>(&H[(size_t)s0 * HIDDEN + c]);
                float2 h1 = *reinterpret_cast<const float2*>(&H[(size_t)s1 * HIDDEN + c]);
                float2 h2 = *reinterpret_cast<const float2*>(&H[(size_t)s2 * HIDDEN + c]);
                float2 h3 = *reinterpret_cast<const float2*>(&H[(size_t)s3 * HIDDEN + c]);
                float2 h4 = *reinterpret_cast<const float2*>(&H[(size_t)s4 * HIDDEN + c]);
                float2 h5 = *reinterpret_cast<const float2*>(&H[(size_t)s5 * HIDDEN + c]);
                float2 h6 = *reinterpret_cast<const float2*>(&H[(size_t)s6 * HIDDEN + c]);
                float2 h7 = *reinterpret_cast<const float2*>(&H[(size_t)s7 * HIDDEN + c]);
                s  += ((e0 + e1) + (e2 + e3)) + ((e4 + e5) + (e6 + e7));
                ax += e0 * h0.x + e1 * h1.x + e2 * h2.x + e3 * h3.x
                    + e4 * h4.x + e5 * h5.x + e6 * h6.x + e7 * h7.x;
                ay += e0 * h0.y + e1 * h1.y + e2 * h2.y + e3 * h3.y
                    + e4 * h4.y + e5 * h5.y + e6 * h6.y + e7 * h7.y;
            }
        }
        for (; t < cnt; ++t) {
            int src = __shfl(mysrc, t);
            float e;
            if (USE_ESC) {
                e = esc[(size_t)(base + t) * 4 + hd];
            } else {
                float sc = as4[src * 4 + hd] + adv;
                sc = sc > 0.f ? sc : sc * NEG_SLOPE;
                e = __expf(sc);
            }
            float2 hv = *reinterpret_cast<const float2*>(&H[(size_t)src * HIDDEN + c]);
            s += e;
            ax += e * hv.x;
            ay += e * hv.y;
        }
    }

    float inv = 1.f / s;
    float v0 = ax * inv + bias[c];
    float v1 = ay * inv + bias[c + 1];
    v0 = (v0 - mean[c])     * (gamma[c]     * rsqrtf(var[c]     + BN_EPS)) + beta[c];
    v1 = (v1 - mean[c + 1]) * (gamma[c + 1] * rsqrtf(var[c + 1] + BN_EPS)) + beta[c + 1];
    v0 = v0 > 0.f ? v0 : expm1f(v0);
    v1 = v1 > 0.f ? v1 : expm1f(v1);
    float2 o = make_float2(v0, v1);
    *reinterpret_cast<float2*>(&Xout[(size_t)wid * HIDDEN + c]) = o;
}

// ---------------------------------------------------------------- fused mean-pool + MLP: one block (1024 threads) per graph
// batch is SORTED -> contiguous node range. 32 row-groups x 32 float4 channel
// groups; LDS tree reduce; fc1+fc2 in-block.

__global__ __launch_bounds__(1024) void pool_fc_kernel(
    const float* __restrict__ X, const int* __restrict__ batch,
    const float* __restrict__ fc1w, const float* __restrict__ fc1b,
    const float* __restrict__ fc2w, const float* __restrict__ fc2b,
    float* __restrict__ out) {
    int g = blockIdx.x;
    int tid = threadIdx.x;       // 0..1023
    int cg = (tid & 31) * 4;     // channel group: 0,4,...,124
    int rg = tid >> 5;           // row group: 0..31

    int lo = 0, hi = N_NODES;
    while (lo < hi) { int mid = (lo + hi) >> 1; if (batch[mid] < g) lo = mid + 1; else hi = mid; }
    int lo2 = lo, hi2 = N_NODES;
    while (lo2 < hi2) { int mid = (lo2 + hi2) >> 1; if (batch[mid] < g + 1) lo2 = mid + 1; else hi2 = mid; }

    float ax = 0.f, ay = 0.f, az = 0.f, aw = 0.f;
    for (int i = lo + rg; i < lo2; i += 32) {
        float4 v = *reinterpret_cast<const float4*>(&X[(size_t)i * HIDDEN + cg]);
        ax += v.x; ay += v.y; az += v.z; aw += v.w;
    }

    __shared__ float red[32][132];   // [rg][channel]
    red[rg][cg + 0] = ax; red[rg][cg + 1] = ay;
    red[rg][cg + 2] = az; red[rg][cg + 3] = aw;
    __syncthreads();
#pragma unroll
    for (int step = 16; step >= 1; step >>= 1) {
        if (rg < step) {
            red[rg][cg + 0] += red[rg + step][cg + 0];
            red[rg][cg + 1] += red[rg + step][cg + 1];
            red[rg][cg + 2] += red[rg + step][cg + 2];
            red[rg][cg + 3] += red[rg + step][cg + 3];
        }
        __syncthreads();
    }

    __shared__ float pooled[HIDDEN];
    __shared__ float hmid[64];
    if (rg == 0) {
        float inv = 1.f / fmaxf((float)(lo2 - lo), 1.0f);
        pooled[cg + 0] = red[0][cg + 0] * inv;
        pooled[cg + 1] = red[0][cg + 1] * inv;
        pooled[cg + 2] = red[0][cg + 2] * inv;
        pooled[cg + 3] = red[0][cg + 3] * inv;
    }
    __syncthreads();
    if (tid < 64) {
        float a = fc1b[tid];
#pragma unroll 8
        for (int k = 0; k < 128; ++k) a += pooled[k] * fc1w[k * 64 + tid];
        hmid[tid] = fmaxf(a, 0.f);
    }
    __syncthreads();
    if (tid < 10) {
        float a = fc2b[tid];
#pragma unroll 8
        for (int k = 0; k < 64; ++k) a += hmid[k] * fc2w[k * 10 + tid];
        out[g * 10 + tid] = a;
    }
}

// ---------------------------------------------------------------- launch

static inline size_t align_up(size_t x, size_t a) { return (x + a - 1) & ~(a - 1); }

extern "C" void kernel_launch(void* const* d_in, const int* in_sizes, int n_in,
                              void* d_out, int out_size, void* d_ws, size_t ws_size,
                              hipStream_t stream) {
    const float* x        = (const float*)d_in[0];
    const int*   eidx     = (const int*)d_in[1];   // [2, N_EDGES]
    const int*   batch    = (const int*)d_in[2];
    const float* W        = (const float*)d_in[3];   // [3,128,128]
    const float* att_src  = (const float*)d_in[4];   // [3,4,32]
    const float* att_dst  = (const float*)d_in[5];
    const float* bias     = (const float*)d_in[6];   // [3,128]
    const float* bn_gamma = (const float*)d_in[7];
    const float* bn_beta  = (const float*)d_in[8];
    const float* bn_mean  = (const float*)d_in[9];
    const float* bn_var   = (const float*)d_in[10];
    const float* fc1w     = (const float*)d_in[11];  // [128,64]
    const float* fc1b     = (const float*)d_in[12];
    const float* fc2w     = (const float*)d_in[13];  // [64,10]
    const float* fc2b     = (const float*)d_in[14];
    float* out = (float*)d_out;

    const int* src = eidx;
    const int* dst = eidx + N_EDGES;

    // ---- workspace layout
    char* p = (char*)d_ws;
    size_t off = 0;
    auto alloc = [&](size_t bytes) {
        size_t o = off;
        off = align_up(off + bytes, 256);
        return (void*)(p + o);
    };
    float* H       = (float*)alloc((size_t)N_NODES * HIDDEN * 4);
    float* Xbuf    = (float*)alloc((size_t)N_NODES * HIDDEN * 4);
    float* as4     = (float*)alloc((size_t)N_NODES * HEADS * 4);
    float* ad4     = (float*)alloc((size_t)N_NODES * HEADS * 4);
    int*   degcur  = (int*)alloc((size_t)2 * N_NODES * 4);
    int*   rowoff  = (int*)alloc((size_t)(N_NODES + 1) * 4);
    int*   col     = (int*)alloc((size_t)E_TOTAL * 4);
    int*   bsum    = (int*)alloc((size_t)NBLK_SCAN * 4);
    int*   dstarr  = (int*)alloc((size_t)E_TOTAL * 4);
    float* esc     = (float*)alloc((size_t)E_TOTAL * HEADS * 4);
    const bool use_esc = (off <= ws_size);
    int* deg = degcur;
    int* cursor = degcur + N_NODES;
    (void)n_in; (void)in_sizes; (void)out_size;

    // ---- zero fill (deg+cursor)
    zero_kernel<<<(2 * N_NODES + 255) / 256, 256, 0, stream>>>((unsigned int*)degcur, 2 * N_NODES);

    // ---- CSR build (by destination), once per call
    hist_kernel<<<(E_TOTAL + 255) / 256, 256, 0, stream>>>(dst, deg);
    scan1_kernel<<<NBLK_SCAN, 256, 0, stream>>>(deg, rowoff, bsum, N_NODES);
    scan2_kernel<<<1, 256, 0, stream>>>(bsum, NBLK_SCAN);
    scan3_kernel<<<NBLK_SCAN, 256, 0, stream>>>(bsum, rowoff, N_NODES);
    scatter_kernel<<<(E_TOTAL + 255) / 256, 256, 0, stream>>>(src, dst, rowoff, cursor, col, dstarr);

    // ---- 3 GAT layers
    const float* xcur = x;
    for (int layer = 0; layer < NUM_LAYERS; ++layer) {
        const float* Wl  = W + (size_t)layer * HIDDEN * HIDDEN;
        const float* asl = att_src + (size_t)layer * HEADS * OUT_CH;
        const float* adl = att_dst + (size_t)layer * HEADS * OUT_CH;
        const float* bl  = bias + (size_t)layer * HIDDEN;
        const float* gl  = bn_gamma + (size_t)layer * HIDDEN;
        const float* btl = bn_beta + (size_t)layer * HIDDEN;
        const float* ml  = bn_mean + (size_t)layer * HIDDEN;
        const float* vl  = bn_var + (size_t)layer * HIDDEN;

        gemm_xw<<<(N_NODES + 31) / 32, 256, 0, stream>>>(xcur, Wl, asl, adl, H, as4, ad4, N_NODES);
        if (use_esc) {
            escore_kernel<<<(E_TOTAL + 255) / 256, 256, 0, stream>>>(col, dstarr, as4, ad4, esc);
            aggregate_kernel<1><<<(N_NODES * 64 + 255) / 256, 256, 0, stream>>>(
                H, as4, ad4, esc, rowoff, col, bl, gl, btl, ml, vl, Xbuf, N_NODES);
        } else {
            aggregate_kernel<0><<<(N_NODES * 64 + 255) / 256, 256, 0, stream>>>(
                H, as4, ad4, esc, rowoff, col, bl, gl, btl, ml, vl, Xbuf, N_NODES);
        }
        xcur = Xbuf;
    }

    // ---- fused pool + MLP (batch sorted -> contiguous ranges, no atomics)
    pool_fc_kernel<<<N_GRAPHS, 1024, 0, stream>>>(xcur, batch, fc1w, fc1b, fc2w, fc2b, out);
}

// Round 10
// 466.245 us; speedup vs baseline: 1.9110x; 1.0932x over previous
//
#include <hip/hip_runtime.h>
#include <math.h>

#define N_NODES 50000
#define N_EDGES 800000
#define E_TOTAL (N_EDGES + N_NODES)   // self-loops appended
#define N_GRAPHS 256
#define HEADS 4
#define OUT_CH 32
#define HIDDEN 128
#define NUM_LAYERS 3
#define NEG_SLOPE 0.2f
#define BN_EPS 1e-5f
#define NBLK_SCAN ((N_NODES + 255) / 256)   // 196

// ---------------------------------------------------------------- utilities

__global__ void zero_kernel(unsigned int* __restrict__ p, int n) {
    int i = blockIdx.x * blockDim.x + threadIdx.x;
    if (i < n) p[i] = 0u;
}

// ---------------------------------------------------------------- CSR build
// hist also assigns each edge its within-row rank (old deg value) so the
// scatter pass needs no atomic.

__global__ void hist_kernel(const int* __restrict__ dst, int* __restrict__ deg,
                            int* __restrict__ rank) {
    int e = blockIdx.x * blockDim.x + threadIdx.x;
    if (e >= E_TOTAL) return;
    int d = (e < N_EDGES) ? dst[e] : (e - N_EDGES);
    rank[e] = atomicAdd(&deg[d], 1);
}

// hierarchical scan: stage 1 — per-block inclusive scan (256 elems/block)
__global__ __launch_bounds__(256) void scan1_kernel(const int* __restrict__ deg,
                                                    int* __restrict__ rowoff,
                                                    int* __restrict__ bsum, int n) {
    int i = blockIdx.x * 256 + threadIdx.x;
    int v = (i < n) ? deg[i] : 0;
    int lane = threadIdx.x & 63, wv = threadIdx.x >> 6;
    int s = v;
    for (int off = 1; off < 64; off <<= 1) {
        int u = __shfl_up(s, off);
        if (lane >= off) s += u;
    }
    __shared__ int wtot[4];
    if (lane == 63) wtot[wv] = s;
    __syncthreads();
    int add = 0;
    for (int w = 0; w < wv; ++w) add += wtot[w];
    s += add;
    if (i < n) rowoff[i + 1] = s;
    if (threadIdx.x == 255) bsum[blockIdx.x] = s;
}

// stage 2 — single block: exclusive scan of block sums (in place)
__global__ __launch_bounds__(256) void scan2_kernel(int* __restrict__ bsum, int nb) {
    int t = threadIdx.x;
    int v = (t < nb) ? bsum[t] : 0;
    int lane = t & 63, wv = t >> 6;
    int s = v;
    for (int off = 1; off < 64; off <<= 1) {
        int u = __shfl_up(s, off);
        if (lane >= off) s += u;
    }
    __shared__ int wtot[4];
    if (lane == 63) wtot[wv] = s;
    __syncthreads();
    int add = 0;
    for (int w = 0; w < wv; ++w) add += wtot[w];
    s += add;
    if (t < nb) bsum[t] = s - v;   // exclusive
}

// stage 3 — add block prefix back
__global__ __launch_bounds__(256) void scan3_kernel(const int* __restrict__ bsum,
                                                    int* __restrict__ rowoff, int n) {
    int i = blockIdx.x * 256 + threadIdx.x;
    if (i == 0) rowoff[0] = 0;
    if (i < n) rowoff[i + 1] += bsum[blockIdx.x];
}

// no atomic: pos = rowoff[d] + rank[e]; single 8B packed write per edge
__global__ void scatter_kernel(const int* __restrict__ src, const int* __restrict__ dst,
                               const int* __restrict__ rowoff, const int* __restrict__ rank,
                               int2* __restrict__ edgebuf) {
    int e = blockIdx.x * blockDim.x + threadIdx.x;
    if (e >= E_TOTAL) return;
    int s, d;
    if (e < N_EDGES) { s = src[e]; d = dst[e]; }
    else             { s = e - N_EDGES; d = s; }
    int pos = rowoff[d] + rank[e];
    edgebuf[pos] = make_int2(s, d);
}

// ---------------------------------------------------------------- GEMM h = X @ W (n x 128 @ 128 x 128)
// X tile stored transposed in LDS (XOR-swizzled row groups: conflict-free staging
// writes, reads stay broadcast). Inner loop: 2x ds_read_b128 + 16 FMA.
// fused epilogue: alpha_src / alpha_dst per (node, head) via 8-lane butterfly

__global__ __launch_bounds__(256) void gemm_xw(const float* __restrict__ X,
                                               const float* __restrict__ W,
                                               const float* __restrict__ att_src,
                                               const float* __restrict__ att_dst,
                                               float* __restrict__ H,
                                               float* __restrict__ as4,
                                               float* __restrict__ ad4, int n) {
    __shared__ float xst[32][36];    // [kk][swizzled r]
    __shared__ float ws[32][128];    // 32 k x 128 cols
    const int row0 = blockIdx.x * 32;
    const int cg = threadIdx.x & 31;   // col group: cols cg*4..cg*4+3
    const int rg = threadIdx.x >> 5;   // row group: rows rg*4..rg*4+3
    float acc[4][4];
#pragma unroll
    for (int r = 0; r < 4; ++r)
#pragma unroll
        for (int j = 0; j < 4; ++j) acc[r][j] = 0.f;

    for (int k0 = 0; k0 < 128; k0 += 32) {
        {
            int r = threadIdx.x >> 3;          // 0..31
            int kk = (threadIdx.x & 7) * 4;    // 0,4,..,28
            int swz = (kk >> 2) & 7;           // uniform for kk..kk+3
            int cswz = (((r >> 2) ^ swz) << 2) | (r & 3);
            int gr = row0 + r;
            float4 v = make_float4(0.f, 0.f, 0.f, 0.f);
            if (gr < n) v = *reinterpret_cast<const float4*>(&X[gr * 128 + k0 + kk]);
            xst[kk + 0][cswz] = v.x; xst[kk + 1][cswz] = v.y;
            xst[kk + 2][cswz] = v.z; xst[kk + 3][cswz] = v.w;
        }
        for (int i = threadIdx.x; i < 32 * 128 / 4; i += 256) {
            int p = i * 4;
            int kk = p >> 7, cc = p & 127;
            *reinterpret_cast<float4*>(&ws[kk][cc]) =
                *reinterpret_cast<const float4*>(&W[(k0 + kk) * 128 + cc]);
        }
        __syncthreads();
#pragma unroll
        for (int kk = 0; kk < 32; ++kk) {
            const int swz = (kk >> 2) & 7;
            float4 wv = *reinterpret_cast<const float4*>(&ws[kk][cg * 4]);
            float4 xv = *reinterpret_cast<const float4*>(&xst[kk][((rg ^ swz) << 2)]);
            acc[0][0] += xv.x * wv.x; acc[0][1] += xv.x * wv.y; acc[0][2] += xv.x * wv.z; acc[0][3] += xv.x * wv.w;
            acc[1][0] += xv.y * wv.x; acc[1][1] += xv.y * wv.y; acc[1][2] += xv.y * wv.z; acc[1][3] += xv.y * wv.w;
            acc[2][0] += xv.z * wv.x; acc[2][1] += xv.z * wv.y; acc[2][2] += xv.z * wv.z; acc[2][3] += xv.z * wv.w;
            acc[3][0] += xv.w * wv.x; acc[3][1] += xv.w * wv.y; acc[3][2] += xv.w * wv.z; acc[3][3] += xv.w * wv.w;
        }
        __syncthreads();
    }

#pragma unroll
    for (int r = 0; r < 4; ++r) {
        int gr = row0 + rg * 4 + r;
        if (gr < n) {
            float4 v = make_float4(acc[r][0], acc[r][1], acc[r][2], acc[r][3]);
            *reinterpret_cast<float4*>(&H[gr * 128 + cg * 4]) = v;
        }
    }

    const int h = cg >> 3;
    const int co = (cg & 7) * 4;
    float4 asw = *reinterpret_cast<const float4*>(att_src + h * OUT_CH + co);
    float4 adw = *reinterpret_cast<const float4*>(att_dst + h * OUT_CH + co);
#pragma unroll
    for (int r = 0; r < 4; ++r) {
        float s = acc[r][0] * asw.x + acc[r][1] * asw.y + acc[r][2] * asw.z + acc[r][3] * asw.w;
        float d = acc[r][0] * adw.x + acc[r][1] * adw.y + acc[r][2] * adw.z + acc[r][3] * adw.w;
        s += __shfl_xor(s, 1); d += __shfl_xor(d, 1);
        s += __shfl_xor(s, 2); d += __shfl_xor(d, 2);
        s += __shfl_xor(s, 4); d += __shfl_xor(d, 4);
        if ((cg & 7) == 0) {
            int gr = row0 + rg * 4 + r;
            if (gr < n) {
                as4[gr * 4 + h] = s;
                ad4[gr * 4 + h] = d;
            }
        }
    }
}

// ---------------------------------------------------------------- per-edge exp-scores (all 4 heads), edge-parallel

__global__ __launch_bounds__(256) void escore_kernel(const int2* __restrict__ edgebuf,
                                                     const float* __restrict__ as4,
                                                     const float* __restrict__ ad4,
                                                     float* __restrict__ esc) {
    int j = blockIdx.x * blockDim.x + threadIdx.x;
    if (j >= E_TOTAL) return;
    int2 ed = edgebuf[j];
    float4 a = *reinterpret_cast<const float4*>(&as4[ed.x * 4]);
    float4 b = *reinterpret_cast<const float4*>(&ad4[ed.y * 4]);
    float x0 = a.x + b.x, x1 = a.y + b.y, x2 = a.z + b.z, x3 = a.w + b.w;
    x0 = x0 > 0.f ? x0 : x0 * NEG_SLOPE;
    x1 = x1 > 0.f ? x1 : x1 * NEG_SLOPE;
    x2 = x2 > 0.f ? x2 : x2 * NEG_SLOPE;
    x3 = x3 > 0.f ? x3 : x3 * NEG_SLOPE;
    float4 e = make_float4(__expf(x0), __expf(x1), __expf(x2), __expf(x3));
    *reinterpret_cast<float4*>(&esc[(size_t)j * 4]) = e;
}

// ---------------------------------------------------------------- fused aggregation: edge-softmax + message sum + bias + BN + ELU
// one wave per destination node; lane l owns channels 2l, 2l+1 (head = l>>4).
// 8-wide unrolled inner loop: batch shfls + esc + H loads before FMAs (MLP).

template <int USE_ESC>
__global__ __launch_bounds__(256) void aggregate_kernel(
    const float* __restrict__ H, const float* __restrict__ as4, const float* __restrict__ ad4,
    const float* __restrict__ esc,
    const int* __restrict__ rowoff, const int2* __restrict__ edgebuf,
    const float* __restrict__ bias, const float* __restrict__ gamma, const float* __restrict__ beta,
    const float* __restrict__ mean, const float* __restrict__ var,
    float* __restrict__ Xout, int n) {
    int wid = (blockIdx.x * blockDim.x + threadIdx.x) >> 6;
    if (wid >= n) return;
    int lane = threadIdx.x & 63;
    int hd = lane >> 4;          // head 0..3
    int c = lane * 2;            // channels c, c+1 (same head)

    float adv = USE_ESC ? 0.f : ad4[wid * 4 + hd];

    int jbeg = rowoff[wid], jend = rowoff[wid + 1];

    float s = 0.f, ax = 0.f, ay = 0.f;

    for (int base = jbeg; base < jend; base += 64) {
        int myj = base + lane;
        int mysrc = (myj < jend) ? edgebuf[myj].x : 0;
        int cnt = min(64, jend - base);
        int t = 0;
        if (USE_ESC) {
#pragma unroll 1
            for (; t + 8 <= cnt; t += 8) {
                int s0 = __shfl(mysrc, t + 0);
                int s1 = __shfl(mysrc, t + 1);
                int s2 = __shfl(mysrc, t + 2);
                int s3 = __shfl(mysrc, t + 3);
                int s4 = __shfl(mysrc, t + 4);
                int s5 = __shfl(mysrc, t + 5);
                int s6 = __shfl(mysrc, t + 6);
                int s7 = __shfl(mysrc, t + 7);
                float e0 = esc[(size_t)(base + t + 0) * 4 + hd];
                float e1 = esc[(size_t)(base + t + 1) * 4 + hd];
                float e2 = esc[(size_t)(base + t + 2) * 4 + hd];
                float e3 = esc[(size_t)(base + t + 3) * 4 + hd];
                float e4 = esc[(size_t)(base + t + 4) * 4 + hd];
                float e5 = esc[(size_t)(base + t + 5) * 4 + hd];
                float e6 = esc[(size_t)(base + t + 6) * 4 + hd];
                float e7 = esc[(size_t)(base + t + 7) * 4 + hd];
                float2 h0 = *reinterpret_cast<const float2*>(&H[(size_t)s0 * HIDDEN + c]);
                float2 h1 = *reinterpret_cast<const float2*>(&H[(size_t)s1 * HIDDEN + c]);
                float2 h2 = *reinterpret_cast<const float2*>(&H[(size_t)s2 * HIDDEN + c]);
                float2 h3 = *reinterpret_cast<const float2*>(&H[(size_t)s3 * HIDDEN + c]);
                float2 h4 = *reinterpret_cast<const float2*>(&H[(size_t)s4 * HIDDEN + c]);
                float2 h5 = *reinterpret_cast<const float2*>(&H[(size_t)s5 * HIDDEN + c]);
                float2 h6 = *reinterpret_cast<const float2*>(&H[(size_t)s6 * HIDDEN + c]);
                float2 h7 = *reinterpret_cast<const float2*>(&H[(size_t)s7 * HIDDEN + c]);
                s  += ((e0 + e1) + (e2 + e3)) + ((e4 + e5) + (e6 + e7));
                ax += e0 * h0.x + e1 * h1.x + e2 * h2.x + e3 * h3.x
                    + e4 * h4.x + e5 * h5.x + e6 * h6.x + e7 * h7.x;
                ay += e0 * h0.y + e1 * h1.y + e2 * h2.y + e3 * h3.y
                    + e4 * h4.y + e5 * h5.y + e6 * h6.y + e7 * h7.y;
            }
        }
        for (; t < cnt; ++t) {
            int src = __shfl(mysrc, t);
            float e;
            if (USE_ESC) {
                e = esc[(size_t)(base + t) * 4 + hd];
            } else {
                float sc = as4[src * 4 + hd] + adv;
                sc = sc > 0.f ? sc : sc * NEG_SLOPE;
                e = __expf(sc);
            }
            float2 hv = *reinterpret_cast<const float2*>(&H[(size_t)src * HIDDEN + c]);
            s += e;
            ax += e * hv.x;
            ay += e * hv.y;
        }
    }

    float inv = 1.f / s;
    float v0 = ax * inv + bias[c];
    float v1 = ay * inv + bias[c + 1];
    v0 = (v0 - mean[c])     * (gamma[c]     * rsqrtf(var[c]     + BN_EPS)) + beta[c];
    v1 = (v1 - mean[c + 1]) * (gamma[c + 1] * rsqrtf(var[c + 1] + BN_EPS)) + beta[c + 1];
    v0 = v0 > 0.f ? v0 : expm1f(v0);
    v1 = v1 > 0.f ? v1 : expm1f(v1);
    float2 o = make_float2(v0, v1);
    *reinterpret_cast<float2*>(&Xout[(size_t)wid * HIDDEN + c]) = o;
}

// ---------------------------------------------------------------- fused mean-pool + MLP: one block (1024 threads) per graph
// batch is SORTED -> contiguous node range. 32 row-groups x 32 float4 channel
// groups; LDS tree reduce; fc1+fc2 in-block.

__global__ __launch_bounds__(1024) void pool_fc_kernel(
    const float* __restrict__ X, const int* __restrict__ batch,
    const float* __restrict__ fc1w, const float* __restrict__ fc1b,
    const float* __restrict__ fc2w, const float* __restrict__ fc2b,
    float* __restrict__ out) {
    int g = blockIdx.x;
    int tid = threadIdx.x;       // 0..1023
    int cg = (tid & 31) * 4;     // channel group: 0,4,...,124
    int rg = tid >> 5;           // row group: 0..31

    int lo = 0, hi = N_NODES;
    while (lo < hi) { int mid = (lo + hi) >> 1; if (batch[mid] < g) lo = mid + 1; else hi = mid; }
    int lo2 = lo, hi2 = N_NODES;
    while (lo2 < hi2) { int mid = (lo2 + hi2) >> 1; if (batch[mid] < g + 1) lo2 = mid + 1; else hi2 = mid; }

    float ax = 0.f, ay = 0.f, az = 0.f, aw = 0.f;
    for (int i = lo + rg; i < lo2; i += 32) {
        float4 v = *reinterpret_cast<const float4*>(&X[(size_t)i * HIDDEN + cg]);
        ax += v.x; ay += v.y; az += v.z; aw += v.w;
    }

    __shared__ float red[32][132];   // [rg][channel]
    red[rg][cg + 0] = ax; red[rg][cg + 1] = ay;
    red[rg][cg + 2] = az; red[rg][cg + 3] = aw;
    __syncthreads();
#pragma unroll
    for (int step = 16; step >= 1; step >>= 1) {
        if (rg < step) {
            red[rg][cg + 0] += red[rg + step][cg + 0];
            red[rg][cg + 1] += red[rg + step][cg + 1];
            red[rg][cg + 2] += red[rg + step][cg + 2];
            red[rg][cg + 3] += red[rg + step][cg + 3];
        }
        __syncthreads();
    }

    __shared__ float pooled[HIDDEN];
    __shared__ float hmid[64];
    if (rg == 0) {
        float inv = 1.f / fmaxf((float)(lo2 - lo), 1.0f);
        pooled[cg + 0] = red[0][cg + 0] * inv;
        pooled[cg + 1] = red[0][cg + 1] * inv;
        pooled[cg + 2] = red[0][cg + 2] * inv;
        pooled[cg + 3] = red[0][cg + 3] * inv;
    }
    __syncthreads();
    if (tid < 64) {
        float a = fc1b[tid];
#pragma unroll 8
        for (int k = 0; k < 128; ++k) a += pooled[k] * fc1w[k * 64 + tid];
        hmid[tid] = fmaxf(a, 0.f);
    }
    __syncthreads();
    if (tid < 10) {
        float a = fc2b[tid];
#pragma unroll 8
        for (int k = 0; k < 64; ++k) a += hmid[k] * fc2w[k * 10 + tid];
        out[g * 10 + tid] = a;
    }
}

// ---------------------------------------------------------------- launch

static inline size_t align_up(size_t x, size_t a) { return (x + a - 1) & ~(a - 1); }

extern "C" void kernel_launch(void* const* d_in, const int* in_sizes, int n_in,
                              void* d_out, int out_size, void* d_ws, size_t ws_size,
                              hipStream_t stream) {
    const float* x        = (const float*)d_in[0];
    const int*   eidx     = (const int*)d_in[1];   // [2, N_EDGES]
    const int*   batch    = (const int*)d_in[2];
    const float* W        = (const float*)d_in[3];   // [3,128,128]
    const float* att_src  = (const float*)d_in[4];   // [3,4,32]
    const float* att_dst  = (const float*)d_in[5];
    const float* bias     = (const float*)d_in[6];   // [3,128]
    const float* bn_gamma = (const float*)d_in[7];
    const float* bn_beta  = (const float*)d_in[8];
    const float* bn_mean  = (const float*)d_in[9];
    const float* bn_var   = (const float*)d_in[10];
    const float* fc1w     = (const float*)d_in[11];  // [128,64]
    const float* fc1b     = (const float*)d_in[12];
    const float* fc2w     = (const float*)d_in[13];  // [64,10]
    const float* fc2b     = (const float*)d_in[14];
    float* out = (float*)d_out;

    const int* src = eidx;
    const int* dst = eidx + N_EDGES;

    // ---- workspace layout
    char* p = (char*)d_ws;
    size_t off = 0;
    auto alloc = [&](size_t bytes) {
        size_t o = off;
        off = align_up(off + bytes, 256);
        return (void*)(p + o);
    };
    float* H       = (float*)alloc((size_t)N_NODES * HIDDEN * 4);
    float* Xbuf    = (float*)alloc((size_t)N_NODES * HIDDEN * 4);
    float* as4     = (float*)alloc((size_t)N_NODES * HEADS * 4);
    float* ad4     = (float*)alloc((size_t)N_NODES * HEADS * 4);
    int*   deg     = (int*)alloc((size_t)N_NODES * 4);
    int*   rowoff  = (int*)alloc((size_t)(N_NODES + 1) * 4);
    int*   rank    = (int*)alloc((size_t)E_TOTAL * 4);
    int*   bsum    = (int*)alloc((size_t)NBLK_SCAN * 4);
    int2*  edgebuf = (int2*)alloc((size_t)E_TOTAL * 8);
    float* esc     = (float*)alloc((size_t)E_TOTAL * HEADS * 4);
    const bool use_esc = (off <= ws_size);
    (void)n_in; (void)in_sizes; (void)out_size;

    // ---- zero fill (deg only)
    zero_kernel<<<(N_NODES + 255) / 256, 256, 0, stream>>>((unsigned int*)deg, N_NODES);

    // ---- CSR build (by destination), once per call
    hist_kernel<<<(E_TOTAL + 255) / 256, 256, 0, stream>>>(dst, deg, rank);
    scan1_kernel<<<NBLK_SCAN, 256, 0, stream>>>(deg, rowoff, bsum, N_NODES);
    scan2_kernel<<<1, 256, 0, stream>>>(bsum, NBLK_SCAN);
    scan3_kernel<<<NBLK_SCAN, 256, 0, stream>>>(bsum, rowoff, N_NODES);
    scatter_kernel<<<(E_TOTAL + 255) / 256, 256, 0, stream>>>(src, dst, rowoff, rank, edgebuf);

    // ---- 3 GAT layers
    const float* xcur = x;
    for (int layer = 0; layer < NUM_LAYERS; ++layer) {
        const float* Wl  = W + (size_t)layer * HIDDEN * HIDDEN;
        const float* asl = att_src + (size_t)layer * HEADS * OUT_CH;
        const float* adl = att_dst + (size_t)layer * HEADS * OUT_CH;
        const float* bl  = bias + (size_t)layer * HIDDEN;
        const float* gl  = bn_gamma + (size_t)layer * HIDDEN;
        const float* btl = bn_beta + (size_t)layer * HIDDEN;
        const float* ml  = bn_mean + (size_t)layer * HIDDEN;
        const float* vl  = bn_var + (size_t)layer * HIDDEN;

        gemm_xw<<<(N_NODES + 31) / 32, 256, 0, stream>>>(xcur, Wl, asl, adl, H, as4, ad4, N_NODES);
        if (use_esc) {
            escore_kernel<<<(E_TOTAL + 255) / 256, 256, 0, stream>>>(edgebuf, as4, ad4, esc);
            aggregate_kernel<1><<<(N_NODES * 64 + 255) / 256, 256, 0, stream>>>(
                H, as4, ad4, esc, rowoff, edgebuf, bl, gl, btl, ml, vl, Xbuf, N_NODES);
        } else {
            aggregate_kernel<0><<<(N_NODES * 64 + 255) / 256, 256, 0, stream>>>(
                H, as4, ad4, esc, rowoff, edgebuf, bl, gl, btl, ml, vl, Xbuf, N_NODES);
        }
        xcur = Xbuf;
    }

    // ---- fused pool + MLP (batch sorted -> contiguous ranges, no atomics)
    pool_fc_kernel<<<N_GRAPHS, 1024, 0, stream>>>(xcur, batch, fc1w, fc1b, fc2w, fc2b, out);
}

// Round 12
// 402.283 us; speedup vs baseline: 2.2148x; 1.1590x over previous
//
#include <hip/hip_runtime.h>
#include <hip/hip_fp16.h>
#include <math.h>

#define N_NODES 50000
#define N_EDGES 800000
#define E_TOTAL (N_EDGES + N_NODES)   // self-loops appended
#define N_GRAPHS 256
#define HEADS 4
#define OUT_CH 32
#define HIDDEN 128
#define NUM_LAYERS 3
#define NEG_SLOPE 0.2f
#define BN_EPS 1e-5f
#define NBLK_SCAN ((N_NODES + 255) / 256)   // 196

// ---------------------------------------------------------------- utilities

__global__ void zero_kernel(unsigned int* __restrict__ p, int n) {
    int i = blockIdx.x * blockDim.x + threadIdx.x;
    if (i < n) p[i] = 0u;
}

// ---------------------------------------------------------------- CSR build
// hist also assigns each edge its within-row rank (old deg value) so the
// scatter pass needs no atomic.

__global__ void hist_kernel(const int* __restrict__ dst, int* __restrict__ deg,
                            int* __restrict__ rank) {
    int e = blockIdx.x * blockDim.x + threadIdx.x;
    if (e >= E_TOTAL) return;
    int d = (e < N_EDGES) ? dst[e] : (e - N_EDGES);
    rank[e] = atomicAdd(&deg[d], 1);
}

// hierarchical scan: stage 1 — per-block inclusive scan (256 elems/block)
__global__ __launch_bounds__(256) void scan1_kernel(const int* __restrict__ deg,
                                                    int* __restrict__ rowoff,
                                                    int* __restrict__ bsum, int n) {
    int i = blockIdx.x * 256 + threadIdx.x;
    int v = (i < n) ? deg[i] : 0;
    int lane = threadIdx.x & 63, wv = threadIdx.x >> 6;
    int s = v;
    for (int off = 1; off < 64; off <<= 1) {
        int u = __shfl_up(s, off);
        if (lane >= off) s += u;
    }
    __shared__ int wtot[4];
    if (lane == 63) wtot[wv] = s;
    __syncthreads();
    int add = 0;
    for (int w = 0; w < wv; ++w) add += wtot[w];
    s += add;
    if (i < n) rowoff[i + 1] = s;
    if (threadIdx.x == 255) bsum[blockIdx.x] = s;
}

// stage 2 — single block: exclusive scan of block sums (in place)
__global__ __launch_bounds__(256) void scan2_kernel(int* __restrict__ bsum, int nb) {
    int t = threadIdx.x;
    int v = (t < nb) ? bsum[t] : 0;
    int lane = t & 63, wv = t >> 6;
    int s = v;
    for (int off = 1; off < 64; off <<= 1) {
        int u = __shfl_up(s, off);
        if (lane >= off) s += u;
    }
    __shared__ int wtot[4];
    if (lane == 63) wtot[wv] = s;
    __syncthreads();
    int add = 0;
    for (int w = 0; w < wv; ++w) add += wtot[w];
    s += add;
    if (t < nb) bsum[t] = s - v;   // exclusive
}

// stage 3 — add block prefix back
__global__ __launch_bounds__(256) void scan3_kernel(const int* __restrict__ bsum,
                                                    int* __restrict__ rowoff, int n) {
    int i = blockIdx.x * 256 + threadIdx.x;
    if (i == 0) rowoff[0] = 0;
    if (i < n) rowoff[i + 1] += bsum[blockIdx.x];
}

// no atomic: pos = rowoff[d] + rank[e]; single 8B packed write per edge
__global__ void scatter_kernel(const int* __restrict__ src, const int* __restrict__ dst,
                               const int* __restrict__ rowoff, const int* __restrict__ rank,
                               int2* __restrict__ edgebuf) {
    int e = blockIdx.x * blockDim.x + threadIdx.x;
    if (e >= E_TOTAL) return;
    int s, d;
    if (e < N_EDGES) { s = src[e]; d = dst[e]; }
    else             { s = e - N_EDGES; d = s; }
    int pos = rowoff[d] + rank[e];
    edgebuf[pos] = make_int2(s, d);
}

// ---------------------------------------------------------------- GEMM h = X @ W (n x 128 @ 128 x 128)
// X tile stored transposed in LDS (XOR-swizzled row groups). Inner loop:
// 2x ds_read_b128 + 16 FMA. Epilogue: fp32 attention dots (as4/ad4) via 8-lane
// butterfly, then H written as FP16 (halves the aggregate gather bytes).

__global__ __launch_bounds__(256) void gemm_xw(const float* __restrict__ X,
                                               const float* __restrict__ W,
                                               const float* __restrict__ att_src,
                                               const float* __restrict__ att_dst,
                                               __half* __restrict__ Hh,
                                               float* __restrict__ as4,
                                               float* __restrict__ ad4, int n) {
    __shared__ float xst[32][36];    // [kk][swizzled r]
    __shared__ float ws[32][128];    // 32 k x 128 cols
    const int row0 = blockIdx.x * 32;
    const int cg = threadIdx.x & 31;   // col group: cols cg*4..cg*4+3
    const int rg = threadIdx.x >> 5;   // row group: rows rg*4..rg*4+3
    float acc[4][4];
#pragma unroll
    for (int r = 0; r < 4; ++r)
#pragma unroll
        for (int j = 0; j < 4; ++j) acc[r][j] = 0.f;

    for (int k0 = 0; k0 < 128; k0 += 32) {
        {
            int r = threadIdx.x >> 3;          // 0..31
            int kk = (threadIdx.x & 7) * 4;    // 0,4,..,28
            int swz = (kk >> 2) & 7;           // uniform for kk..kk+3
            int cswz = (((r >> 2) ^ swz) << 2) | (r & 3);
            int gr = row0 + r;
            float4 v = make_float4(0.f, 0.f, 0.f, 0.f);
            if (gr < n) v = *reinterpret_cast<const float4*>(&X[gr * 128 + k0 + kk]);
            xst[kk + 0][cswz] = v.x; xst[kk + 1][cswz] = v.y;
            xst[kk + 2][cswz] = v.z; xst[kk + 3][cswz] = v.w;
        }
        for (int i = threadIdx.x; i < 32 * 128 / 4; i += 256) {
            int p = i * 4;
            int kk = p >> 7, cc = p & 127;
            *reinterpret_cast<float4*>(&ws[kk][cc]) =
                *reinterpret_cast<const float4*>(&W[(k0 + kk) * 128 + cc]);
        }
        __syncthreads();
#pragma unroll
        for (int kk = 0; kk < 32; ++kk) {
            const int swz = (kk >> 2) & 7;
            float4 wv = *reinterpret_cast<const float4*>(&ws[kk][cg * 4]);
            float4 xv = *reinterpret_cast<const float4*>(&xst[kk][((rg ^ swz) << 2)]);
            acc[0][0] += xv.x * wv.x; acc[0][1] += xv.x * wv.y; acc[0][2] += xv.x * wv.z; acc[0][3] += xv.x * wv.w;
            acc[1][0] += xv.y * wv.x; acc[1][1] += xv.y * wv.y; acc[1][2] += xv.y * wv.z; acc[1][3] += xv.y * wv.w;
            acc[2][0] += xv.z * wv.x; acc[2][1] += xv.z * wv.y; acc[2][2] += xv.z * wv.z; acc[2][3] += xv.z * wv.w;
            acc[3][0] += xv.w * wv.x; acc[3][1] += xv.w * wv.y; acc[3][2] += xv.w * wv.z; acc[3][3] += xv.w * wv.w;
        }
        __syncthreads();
    }

    // write H tile as fp16 (8B per row-fragment)
#pragma unroll
    for (int r = 0; r < 4; ++r) {
        int gr = row0 + rg * 4 + r;
        if (gr < n) {
            __half2 ab = __floats2half2_rn(acc[r][0], acc[r][1]);
            __half2 cd = __floats2half2_rn(acc[r][2], acc[r][3]);
            uint2 u;
            u.x = *reinterpret_cast<unsigned*>(&ab);
            u.y = *reinterpret_cast<unsigned*>(&cd);
            *reinterpret_cast<uint2*>(&Hh[(size_t)gr * 128 + cg * 4]) = u;
        }
    }

    // fp32 attention coefficients from the fp32 accumulators
    const int h = cg >> 3;
    const int co = (cg & 7) * 4;
    float4 asw = *reinterpret_cast<const float4*>(att_src + h * OUT_CH + co);
    float4 adw = *reinterpret_cast<const float4*>(att_dst + h * OUT_CH + co);
#pragma unroll
    for (int r = 0; r < 4; ++r) {
        float s = acc[r][0] * asw.x + acc[r][1] * asw.y + acc[r][2] * asw.z + acc[r][3] * asw.w;
        float d = acc[r][0] * adw.x + acc[r][1] * adw.y + acc[r][2] * adw.z + acc[r][3] * adw.w;
        s += __shfl_xor(s, 1); d += __shfl_xor(d, 1);
        s += __shfl_xor(s, 2); d += __shfl_xor(d, 2);
        s += __shfl_xor(s, 4); d += __shfl_xor(d, 4);
        if ((cg & 7) == 0) {
            int gr = row0 + rg * 4 + r;
            if (gr < n) {
                as4[gr * 4 + h] = s;
                ad4[gr * 4 + h] = d;
            }
        }
    }
}

// ---------------------------------------------------------------- per-edge exp-scores (all 4 heads), edge-parallel

__global__ __launch_bounds__(256) void escore_kernel(const int2* __restrict__ edgebuf,
                                                     const float* __restrict__ as4,
                                                     const float* __restrict__ ad4,
                                                     float* __restrict__ esc) {
    int j = blockIdx.x * blockDim.x + threadIdx.x;
    if (j >= E_TOTAL) return;
    int2 ed = edgebuf[j];
    float4 a = *reinterpret_cast<const float4*>(&as4[ed.x * 4]);
    float4 b = *reinterpret_cast<const float4*>(&ad4[ed.y * 4]);
    float x0 = a.x + b.x, x1 = a.y + b.y, x2 = a.z + b.z, x3 = a.w + b.w;
    x0 = x0 > 0.f ? x0 : x0 * NEG_SLOPE;
    x1 = x1 > 0.f ? x1 : x1 * NEG_SLOPE;
    x2 = x2 > 0.f ? x2 : x2 * NEG_SLOPE;
    x3 = x3 > 0.f ? x3 : x3 * NEG_SLOPE;
    float4 e = make_float4(__expf(x0), __expf(x1), __expf(x2), __expf(x3));
    *reinterpret_cast<float4*>(&esc[(size_t)j * 4]) = e;
}

// ---------------------------------------------------------------- fused aggregation: edge-softmax + message sum + bias + BN + ELU
// one wave per destination node; lane l owns channels 2l, 2l+1 (head = l>>4).
// H gathered as half2 (4B/lane/edge); fp32 accumulation.

template <int USE_ESC>
__global__ __launch_bounds__(256) void aggregate_kernel(
    const __half2* __restrict__ Hh2, const float* __restrict__ as4, const float* __restrict__ ad4,
    const float* __restrict__ esc,
    const int* __restrict__ rowoff, const int2* __restrict__ edgebuf,
    const float* __restrict__ bias, const float* __restrict__ gamma, const float* __restrict__ beta,
    const float* __restrict__ mean, const float* __restrict__ var,
    float* __restrict__ Xout, int n) {
    int wid = (blockIdx.x * blockDim.x + threadIdx.x) >> 6;
    if (wid >= n) return;
    int lane = threadIdx.x & 63;
    int hd = lane >> 4;          // head 0..3
    int c = lane * 2;            // channels c, c+1 (same head)

    float adv = USE_ESC ? 0.f : ad4[wid * 4 + hd];

    int jbeg = rowoff[wid], jend = rowoff[wid + 1];

    float s = 0.f, ax = 0.f, ay = 0.f;

    for (int base = jbeg; base < jend; base += 64) {
        int myj = base + lane;
        int mysrc = (myj < jend) ? edgebuf[myj].x : 0;
        int cnt = min(64, jend - base);
        int t = 0;
        if (USE_ESC) {
#pragma unroll 1
            for (; t + 8 <= cnt; t += 8) {
                int s0 = __shfl(mysrc, t + 0);
                int s1 = __shfl(mysrc, t + 1);
                int s2 = __shfl(mysrc, t + 2);
                int s3 = __shfl(mysrc, t + 3);
                int s4 = __shfl(mysrc, t + 4);
                int s5 = __shfl(mysrc, t + 5);
                int s6 = __shfl(mysrc, t + 6);
                int s7 = __shfl(mysrc, t + 7);
                float e0 = esc[(size_t)(base + t + 0) * 4 + hd];
                float e1 = esc[(size_t)(base + t + 1) * 4 + hd];
                float e2 = esc[(size_t)(base + t + 2) * 4 + hd];
                float e3 = esc[(size_t)(base + t + 3) * 4 + hd];
                float e4 = esc[(size_t)(base + t + 4) * 4 + hd];
                float e5 = esc[(size_t)(base + t + 5) * 4 + hd];
                float e6 = esc[(size_t)(base + t + 6) * 4 + hd];
                float e7 = esc[(size_t)(base + t + 7) * 4 + hd];
                float2 h0 = __half22float2(Hh2[(size_t)s0 * 64 + lane]);
                float2 h1 = __half22float2(Hh2[(size_t)s1 * 64 + lane]);
                float2 h2 = __half22float2(Hh2[(size_t)s2 * 64 + lane]);
                float2 h3 = __half22float2(Hh2[(size_t)s3 * 64 + lane]);
                float2 h4 = __half22float2(Hh2[(size_t)s4 * 64 + lane]);
                float2 h5 = __half22float2(Hh2[(size_t)s5 * 64 + lane]);
                float2 h6 = __half22float2(Hh2[(size_t)s6 * 64 + lane]);
                float2 h7 = __half22float2(Hh2[(size_t)s7 * 64 + lane]);
                s  += ((e0 + e1) + (e2 + e3)) + ((e4 + e5) + (e6 + e7));
                ax += e0 * h0.x + e1 * h1.x + e2 * h2.x + e3 * h3.x
                    + e4 * h4.x + e5 * h5.x + e6 * h6.x + e7 * h7.x;
                ay += e0 * h0.y + e1 * h1.y + e2 * h2.y + e3 * h3.y
                    + e4 * h4.y + e5 * h5.y + e6 * h6.y + e7 * h7.y;
            }
        }
        for (; t < cnt; ++t) {
            int src = __shfl(mysrc, t);
            float e;
            if (USE_ESC) {
                e = esc[(size_t)(base + t) * 4 + hd];
            } else {
                float sc = as4[src * 4 + hd] + adv;
                sc = sc > 0.f ? sc : sc * NEG_SLOPE;
                e = __expf(sc);
            }
            float2 hv = __half22float2(Hh2[(size_t)src * 64 + lane]);
            s += e;
            ax += e * hv.x;
            ay += e * hv.y;
        }
    }

    float inv = 1.f / s;
    float v0 = ax * inv + bias[c];
    float v1 = ay * inv + bias[c + 1];
    v0 = (v0 - mean[c])     * (gamma[c]     * rsqrtf(var[c]     + BN_EPS)) + beta[c];
    v1 = (v1 - mean[c + 1]) * (gamma[c + 1] * rsqrtf(var[c + 1] + BN_EPS)) + beta[c + 1];
    v0 = v0 > 0.f ? v0 : expm1f(v0);
    v1 = v1 > 0.f ? v1 : expm1f(v1);
    float2 o = make_float2(v0, v1);
    *reinterpret_cast<float2*>(&Xout[(size_t)wid * HIDDEN + c]) = o;
}

// ---------------------------------------------------------------- fused mean-pool + MLP: one block (1024 threads) per graph
// batch is SORTED -> contiguous node range. 32 row-groups x 32 float4 channel
// groups; LDS tree reduce; fc1+fc2 in-block.

__global__ __launch_bounds__(1024) void pool_fc_kernel(
    const float* __restrict__ X, const int* __restrict__ batch,
    const float* __restrict__ fc1w, const float* __restrict__ fc1b,
    const float* __restrict__ fc2w, const float* __restrict__ fc2b,
    float* __restrict__ out) {
    int g = blockIdx.x;
    int tid = threadIdx.x;       // 0..1023
    int cg = (tid & 31) * 4;     // channel group: 0,4,...,124
    int rg = tid >> 5;           // row group: 0..31

    int lo = 0, hi = N_NODES;
    while (lo < hi) { int mid = (lo + hi) >> 1; if (batch[mid] < g) lo = mid + 1; else hi = mid; }
    int lo2 = lo, hi2 = N_NODES;
    while (lo2 < hi2) { int mid = (lo2 + hi2) >> 1; if (batch[mid] < g + 1) lo2 = mid + 1; else hi2 = mid; }

    float ax = 0.f, ay = 0.f, az = 0.f, aw = 0.f;
    for (int i = lo + rg; i < lo2; i += 32) {
        float4 v = *reinterpret_cast<const float4*>(&X[(size_t)i * HIDDEN + cg]);
        ax += v.x; ay += v.y; az += v.z; aw += v.w;
    }

    __shared__ float red[32][132];   // [rg][channel]
    red[rg][cg + 0] = ax; red[rg][cg + 1] = ay;
    red[rg][cg + 2] = az; red[rg][cg + 3] = aw;
    __syncthreads();
#pragma unroll
    for (int step = 16; step >= 1; step >>= 1) {
        if (rg < step) {
            red[rg][cg + 0] += red[rg + step][cg + 0];
            red[rg][cg + 1] += red[rg + step][cg + 1];
            red[rg][cg + 2] += red[rg + step][cg + 2];
            red[rg][cg + 3] += red[rg + step][cg + 3];
        }
        __syncthreads();
    }

    __shared__ float pooled[HIDDEN];
    __shared__ float hmid[64];
    if (rg == 0) {
        float inv = 1.f / fmaxf((float)(lo2 - lo), 1.0f);
        pooled[cg + 0] = red[0][cg + 0] * inv;
        pooled[cg + 1] = red[0][cg + 1] * inv;
        pooled[cg + 2] = red[0][cg + 2] * inv;
        pooled[cg + 3] = red[0][cg + 3] * inv;
    }
    __syncthreads();
    if (tid < 64) {
        float a = fc1b[tid];
#pragma unroll 8
        for (int k = 0; k < 128; ++k) a += pooled[k] * fc1w[k * 64 + tid];
        hmid[tid] = fmaxf(a, 0.f);
    }
    __syncthreads();
    if (tid < 10) {
        float a = fc2b[tid];
#pragma unroll 8
        for (int k = 0; k < 64; ++k) a += hmid[k] * fc2w[k * 10 + tid];
        out[g * 10 + tid] = a;
    }
}

// ---------------------------------------------------------------- launch

static inline size_t align_up(size_t x, size_t a) { return (x + a - 1) & ~(a - 1); }

extern "C" void kernel_launch(void* const* d_in, const int* in_sizes, int n_in,
                              void* d_out, int out_size, void* d_ws, size_t ws_size,
                              hipStream_t stream) {
    const float* x        = (const float*)d_in[0];
    const int*   eidx     = (const int*)d_in[1];   // [2, N_EDGES]
    const int*   batch    = (const int*)d_in[2];
    const float* W        = (const float*)d_in[3];   // [3,128,128]
    const float* att_src  = (const float*)d_in[4];   // [3,4,32]
    const float* att_dst  = (const float*)d_in[5];
    const float* bias     = (const float*)d_in[6];   // [3,128]
    const float* bn_gamma = (const float*)d_in[7];
    const float* bn_beta  = (const float*)d_in[8];
    const float* bn_mean  = (const float*)d_in[9];
    const float* bn_var   = (const float*)d_in[10];
    const float* fc1w     = (const float*)d_in[11];  // [128,64]
    const float* fc1b     = (const float*)d_in[12];
    const float* fc2w     = (const float*)d_in[13];  // [64,10]
    const float* fc2b     = (const float*)d_in[14];
    float* out = (float*)d_out;

    const int* src = eidx;
    const int* dst = eidx + N_EDGES;

    // ---- workspace layout
    char* p = (char*)d_ws;
    size_t off = 0;
    auto alloc = [&](size_t bytes) {
        size_t o = off;
        off = align_up(off + bytes, 256);
        return (void*)(p + o);
    };
    __half* Hh     = (__half*)alloc((size_t)N_NODES * HIDDEN * 2);
    float* Xbuf    = (float*)alloc((size_t)N_NODES * HIDDEN * 4);
    float* as4     = (float*)alloc((size_t)N_NODES * HEADS * 4);
    float* ad4     = (float*)alloc((size_t)N_NODES * HEADS * 4);
    int*   deg     = (int*)alloc((size_t)N_NODES * 4);
    int*   rowoff  = (int*)alloc((size_t)(N_NODES + 1) * 4);
    int*   rank    = (int*)alloc((size_t)E_TOTAL * 4);
    int*   bsum    = (int*)alloc((size_t)NBLK_SCAN * 4);
    int2*  edgebuf = (int2*)alloc((size_t)E_TOTAL * 8);
    float* esc     = (float*)alloc((size_t)E_TOTAL * HEADS * 4);
    const bool use_esc = (off <= ws_size);
    (void)n_in; (void)in_sizes; (void)out_size;

    // ---- zero fill (deg only)
    zero_kernel<<<(N_NODES + 255) / 256, 256, 0, stream>>>((unsigned int*)deg, N_NODES);

    // ---- CSR build (by destination), once per call
    hist_kernel<<<(E_TOTAL + 255) / 256, 256, 0, stream>>>(dst, deg, rank);
    scan1_kernel<<<NBLK_SCAN, 256, 0, stream>>>(deg, rowoff, bsum, N_NODES);
    scan2_kernel<<<1, 256, 0, stream>>>(bsum, NBLK_SCAN);
    scan3_kernel<<<NBLK_SCAN, 256, 0, stream>>>(bsum, rowoff, N_NODES);
    scatter_kernel<<<(E_TOTAL + 255) / 256, 256, 0, stream>>>(src, dst, rowoff, rank, edgebuf);

    // ---- 3 GAT layers
    const float* xcur = x;
    for (int layer = 0; layer < NUM_LAYERS; ++layer) {
        const float* Wl  = W + (size_t)layer * HIDDEN * HIDDEN;
        const float* asl = att_src + (size_t)layer * HEADS * OUT_CH;
        const float* adl = att_dst + (size_t)layer * HEADS * OUT_CH;
        const float* bl  = bias + (size_t)layer * HIDDEN;
        const float* gl  = bn_gamma + (size_t)layer * HIDDEN;
        const float* btl = bn_beta + (size_t)layer * HIDDEN;
        const float* ml  = bn_mean + (size_t)layer * HIDDEN;
        const float* vl  = bn_var + (size_t)layer * HIDDEN;

        gemm_xw<<<(N_NODES + 31) / 32, 256, 0, stream>>>(xcur, Wl, asl, adl, Hh, as4, ad4, N_NODES);
        if (use_esc) {
            escore_kernel<<<(E_TOTAL + 255) / 256, 256, 0, stream>>>(edgebuf, as4, ad4, esc);
            aggregate_kernel<1><<<(N_NODES * 64 + 255) / 256, 256, 0, stream>>>(
                (const __half2*)Hh, as4, ad4, esc, rowoff, edgebuf, bl, gl, btl, ml, vl, Xbuf, N_NODES);
        } else {
            aggregate_kernel<0><<<(N_NODES * 64 + 255) / 256, 256, 0, stream>>>(
                (const __half2*)Hh, as4, ad4, esc, rowoff, edgebuf, bl, gl, btl, ml, vl, Xbuf, N_NODES);
        }
        xcur = Xbuf;
    }

    // ---- fused pool + MLP (batch sorted -> contiguous ranges, no atomics)
    pool_fc_kernel<<<N_GRAPHS, 1024, 0, stream>>>(xcur, batch, fc1w, fc1b, fc2w, fc2b, out);
}

// Round 13
// 383.761 us; speedup vs baseline: 2.3217x; 1.0483x over previous
//
#include <hip/hip_runtime.h>
#include <hip/hip_fp16.h>
#include <math.h>

#define N_NODES 50000
#define N_EDGES 800000
#define E_TOTAL (N_EDGES + N_NODES)   // self-loops appended
#define N_GRAPHS 256
#define HEADS 4
#define OUT_CH 32
#define HIDDEN 128
#define NUM_LAYERS 3
#define NEG_SLOPE 0.2f
#define BN_EPS 1e-5f
#define NBLK_SCAN ((N_NODES + 255) / 256)   // 196

// ---------------------------------------------------------------- utilities

__global__ void zero_kernel(unsigned int* __restrict__ p, int n) {
    int i = blockIdx.x * blockDim.x + threadIdx.x;
    if (i < n) p[i] = 0u;
}

// ---------------------------------------------------------------- CSR build
// hist also assigns each edge its within-row rank (old deg value) so the
// scatter pass needs no atomic.

__global__ void hist_kernel(const int* __restrict__ dst, int* __restrict__ deg,
                            int* __restrict__ rank) {
    int e = blockIdx.x * blockDim.x + threadIdx.x;
    if (e >= E_TOTAL) return;
    int d = (e < N_EDGES) ? dst[e] : (e - N_EDGES);
    rank[e] = atomicAdd(&deg[d], 1);
}

// hierarchical scan: stage 1 — per-block inclusive scan (256 elems/block)
__global__ __launch_bounds__(256) void scan1_kernel(const int* __restrict__ deg,
                                                    int* __restrict__ rowoff,
                                                    int* __restrict__ bsum, int n) {
    int i = blockIdx.x * 256 + threadIdx.x;
    int v = (i < n) ? deg[i] : 0;
    int lane = threadIdx.x & 63, wv = threadIdx.x >> 6;
    int s = v;
    for (int off = 1; off < 64; off <<= 1) {
        int u = __shfl_up(s, off);
        if (lane >= off) s += u;
    }
    __shared__ int wtot[4];
    if (lane == 63) wtot[wv] = s;
    __syncthreads();
    int add = 0;
    for (int w = 0; w < wv; ++w) add += wtot[w];
    s += add;
    if (i < n) rowoff[i + 1] = s;
    if (threadIdx.x == 255) bsum[blockIdx.x] = s;
}

// stage 2 — single block: exclusive scan of block sums (in place)
__global__ __launch_bounds__(256) void scan2_kernel(int* __restrict__ bsum, int nb) {
    int t = threadIdx.x;
    int v = (t < nb) ? bsum[t] : 0;
    int lane = t & 63, wv = t >> 6;
    int s = v;
    for (int off = 1; off < 64; off <<= 1) {
        int u = __shfl_up(s, off);
        if (lane >= off) s += u;
    }
    __shared__ int wtot[4];
    if (lane == 63) wtot[wv] = s;
    __syncthreads();
    int add = 0;
    for (int w = 0; w < wv; ++w) add += wtot[w];
    s += add;
    if (t < nb) bsum[t] = s - v;   // exclusive
}

// stage 3 — add block prefix back
__global__ __launch_bounds__(256) void scan3_kernel(const int* __restrict__ bsum,
                                                    int* __restrict__ rowoff, int n) {
    int i = blockIdx.x * 256 + threadIdx.x;
    if (i == 0) rowoff[0] = 0;
    if (i < n) rowoff[i + 1] += bsum[blockIdx.x];
}

// no atomic: pos = rowoff[d] + rank[e]; single 4B write per edge
__global__ void scatter_kernel(const int* __restrict__ src, const int* __restrict__ dst,
                               const int* __restrict__ rowoff, const int* __restrict__ rank,
                               int* __restrict__ col) {
    int e = blockIdx.x * blockDim.x + threadIdx.x;
    if (e >= E_TOTAL) return;
    int s, d;
    if (e < N_EDGES) { s = src[e]; d = dst[e]; }
    else             { s = e - N_EDGES; d = s; }
    int pos = rowoff[d] + rank[e];
    col[pos] = s;
}

// ---------------------------------------------------------------- GEMM h = X @ W (n x 128 @ 128 x 128)
// X tile stored transposed in LDS (XOR-swizzled row groups). Inner loop:
// 2x ds_read_b128 + 16 FMA. Epilogue: fp32 attention dots (as4/ad4) via 8-lane
// butterfly, then H written as FP16 (halves the aggregate gather bytes).

__global__ __launch_bounds__(256) void gemm_xw(const float* __restrict__ X,
                                               const float* __restrict__ W,
                                               const float* __restrict__ att_src,
                                               const float* __restrict__ att_dst,
                                               __half* __restrict__ Hh,
                                               float* __restrict__ as4,
                                               float* __restrict__ ad4, int n) {
    __shared__ float xst[32][36];    // [kk][swizzled r]
    __shared__ float ws[32][128];    // 32 k x 128 cols
    const int row0 = blockIdx.x * 32;
    const int cg = threadIdx.x & 31;   // col group: cols cg*4..cg*4+3
    const int rg = threadIdx.x >> 5;   // row group: rows rg*4..rg*4+3
    float acc[4][4];
#pragma unroll
    for (int r = 0; r < 4; ++r)
#pragma unroll
        for (int j = 0; j < 4; ++j) acc[r][j] = 0.f;

    for (int k0 = 0; k0 < 128; k0 += 32) {
        {
            int r = threadIdx.x >> 3;          // 0..31
            int kk = (threadIdx.x & 7) * 4;    // 0,4,..,28
            int swz = (kk >> 2) & 7;           // uniform for kk..kk+3
            int cswz = (((r >> 2) ^ swz) << 2) | (r & 3);
            int gr = row0 + r;
            float4 v = make_float4(0.f, 0.f, 0.f, 0.f);
            if (gr < n) v = *reinterpret_cast<const float4*>(&X[gr * 128 + k0 + kk]);
            xst[kk + 0][cswz] = v.x; xst[kk + 1][cswz] = v.y;
            xst[kk + 2][cswz] = v.z; xst[kk + 3][cswz] = v.w;
        }
        for (int i = threadIdx.x; i < 32 * 128 / 4; i += 256) {
            int p = i * 4;
            int kk = p >> 7, cc = p & 127;
            *reinterpret_cast<float4*>(&ws[kk][cc]) =
                *reinterpret_cast<const float4*>(&W[(k0 + kk) * 128 + cc]);
        }
        __syncthreads();
#pragma unroll
        for (int kk = 0; kk < 32; ++kk) {
            const int swz = (kk >> 2) & 7;
            float4 wv = *reinterpret_cast<const float4*>(&ws[kk][cg * 4]);
            float4 xv = *reinterpret_cast<const float4*>(&xst[kk][((rg ^ swz) << 2)]);
            acc[0][0] += xv.x * wv.x; acc[0][1] += xv.x * wv.y; acc[0][2] += xv.x * wv.z; acc[0][3] += xv.x * wv.w;
            acc[1][0] += xv.y * wv.x; acc[1][1] += xv.y * wv.y; acc[1][2] += xv.y * wv.z; acc[1][3] += xv.y * wv.w;
            acc[2][0] += xv.z * wv.x; acc[2][1] += xv.z * wv.y; acc[2][2] += xv.z * wv.z; acc[2][3] += xv.z * wv.w;
            acc[3][0] += xv.w * wv.x; acc[3][1] += xv.w * wv.y; acc[3][2] += xv.w * wv.z; acc[3][3] += xv.w * wv.w;
        }
        __syncthreads();
    }

    // write H tile as fp16 (8B per row-fragment)
#pragma unroll
    for (int r = 0; r < 4; ++r) {
        int gr = row0 + rg * 4 + r;
        if (gr < n) {
            __half2 ab = __floats2half2_rn(acc[r][0], acc[r][1]);
            __half2 cd = __floats2half2_rn(acc[r][2], acc[r][3]);
            uint2 u;
            u.x = *reinterpret_cast<unsigned*>(&ab);
            u.y = *reinterpret_cast<unsigned*>(&cd);
            *reinterpret_cast<uint2*>(&Hh[(size_t)gr * 128 + cg * 4]) = u;
        }
    }

    // fp32 attention coefficients from the fp32 accumulators
    const int h = cg >> 3;
    const int co = (cg & 7) * 4;
    float4 asw = *reinterpret_cast<const float4*>(att_src + h * OUT_CH + co);
    float4 adw = *reinterpret_cast<const float4*>(att_dst + h * OUT_CH + co);
#pragma unroll
    for (int r = 0; r < 4; ++r) {
        float s = acc[r][0] * asw.x + acc[r][1] * asw.y + acc[r][2] * asw.z + acc[r][3] * asw.w;
        float d = acc[r][0] * adw.x + acc[r][1] * adw.y + acc[r][2] * adw.z + acc[r][3] * adw.w;
        s += __shfl_xor(s, 1); d += __shfl_xor(d, 1);
        s += __shfl_xor(s, 2); d += __shfl_xor(d, 2);
        s += __shfl_xor(s, 4); d += __shfl_xor(d, 4);
        if ((cg & 7) == 0) {
            int gr = row0 + rg * 4 + r;
            if (gr < n) {
                as4[gr * 4 + h] = s;
                ad4[gr * 4 + h] = d;
            }
        }
    }
}

// ---------------------------------------------------------------- fused aggregation: edge-softmax + message sum + bias + BN + ELU
// one wave per destination node; lane l owns channels 2l, 2l+1 (head = l>>4).
// Inline scores: all 16 lanes of a head group read the SAME as4[src*4+hd]
// address (one 16B broadcast line per edge, L2-resident 800 KB table) + one
// quarter-rate exp. 8-wide unroll keeps >=8 H gathers in flight.

__global__ __launch_bounds__(256) void aggregate_kernel(
    const __half2* __restrict__ Hh2, const float* __restrict__ as4, const float* __restrict__ ad4,
    const int* __restrict__ rowoff, const int* __restrict__ col,
    const float* __restrict__ bias, const float* __restrict__ gamma, const float* __restrict__ beta,
    const float* __restrict__ mean, const float* __restrict__ var,
    float* __restrict__ Xout, int n) {
    int wid = (blockIdx.x * blockDim.x + threadIdx.x) >> 6;
    if (wid >= n) return;
    int lane = threadIdx.x & 63;
    int hd = lane >> 4;          // head 0..3
    int c = lane * 2;            // channels c, c+1 (same head)

    float adv = ad4[wid * 4 + hd];

    int jbeg = rowoff[wid], jend = rowoff[wid + 1];

    float s = 0.f, ax = 0.f, ay = 0.f;

    for (int base = jbeg; base < jend; base += 64) {
        int myj = base + lane;
        int mysrc = (myj < jend) ? col[myj] : 0;
        int cnt = min(64, jend - base);
        int t = 0;
#pragma unroll 1
        for (; t + 8 <= cnt; t += 8) {
            int s0 = __shfl(mysrc, t + 0);
            int s1 = __shfl(mysrc, t + 1);
            int s2 = __shfl(mysrc, t + 2);
            int s3 = __shfl(mysrc, t + 3);
            int s4 = __shfl(mysrc, t + 4);
            int s5 = __shfl(mysrc, t + 5);
            int s6 = __shfl(mysrc, t + 6);
            int s7 = __shfl(mysrc, t + 7);
            float a0 = as4[s0 * 4 + hd];
            float a1 = as4[s1 * 4 + hd];
            float a2 = as4[s2 * 4 + hd];
            float a3 = as4[s3 * 4 + hd];
            float a4 = as4[s4 * 4 + hd];
            float a5 = as4[s5 * 4 + hd];
            float a6 = as4[s6 * 4 + hd];
            float a7 = as4[s7 * 4 + hd];
            float2 h0 = __half22float2(Hh2[(size_t)s0 * 64 + lane]);
            float2 h1 = __half22float2(Hh2[(size_t)s1 * 64 + lane]);
            float2 h2 = __half22float2(Hh2[(size_t)s2 * 64 + lane]);
            float2 h3 = __half22float2(Hh2[(size_t)s3 * 64 + lane]);
            float2 h4 = __half22float2(Hh2[(size_t)s4 * 64 + lane]);
            float2 h5 = __half22float2(Hh2[(size_t)s5 * 64 + lane]);
            float2 h6 = __half22float2(Hh2[(size_t)s6 * 64 + lane]);
            float2 h7 = __half22float2(Hh2[(size_t)s7 * 64 + lane]);
            float x0 = a0 + adv; x0 = x0 > 0.f ? x0 : x0 * NEG_SLOPE;
            float x1 = a1 + adv; x1 = x1 > 0.f ? x1 : x1 * NEG_SLOPE;
            float x2 = a2 + adv; x2 = x2 > 0.f ? x2 : x2 * NEG_SLOPE;
            float x3 = a3 + adv; x3 = x3 > 0.f ? x3 : x3 * NEG_SLOPE;
            float x4 = a4 + adv; x4 = x4 > 0.f ? x4 : x4 * NEG_SLOPE;
            float x5 = a5 + adv; x5 = x5 > 0.f ? x5 : x5 * NEG_SLOPE;
            float x6 = a6 + adv; x6 = x6 > 0.f ? x6 : x6 * NEG_SLOPE;
            float x7 = a7 + adv; x7 = x7 > 0.f ? x7 : x7 * NEG_SLOPE;
            float e0 = __expf(x0);
            float e1 = __expf(x1);
            float e2 = __expf(x2);
            float e3 = __expf(x3);
            float e4 = __expf(x4);
            float e5 = __expf(x5);
            float e6 = __expf(x6);
            float e7 = __expf(x7);
            s  += ((e0 + e1) + (e2 + e3)) + ((e4 + e5) + (e6 + e7));
            ax += e0 * h0.x + e1 * h1.x + e2 * h2.x + e3 * h3.x
                + e4 * h4.x + e5 * h5.x + e6 * h6.x + e7 * h7.x;
            ay += e0 * h0.y + e1 * h1.y + e2 * h2.y + e3 * h3.y
                + e4 * h4.y + e5 * h5.y + e6 * h6.y + e7 * h7.y;
        }
        for (; t < cnt; ++t) {
            int src = __shfl(mysrc, t);
            float sc = as4[src * 4 + hd] + adv;
            sc = sc > 0.f ? sc : sc * NEG_SLOPE;
            float e = __expf(sc);
            float2 hv = __half22float2(Hh2[(size_t)src * 64 + lane]);
            s += e;
            ax += e * hv.x;
            ay += e * hv.y;
        }
    }

    float inv = 1.f / s;
    float v0 = ax * inv + bias[c];
    float v1 = ay * inv + bias[c + 1];
    v0 = (v0 - mean[c])     * (gamma[c]     * rsqrtf(var[c]     + BN_EPS)) + beta[c];
    v1 = (v1 - mean[c + 1]) * (gamma[c + 1] * rsqrtf(var[c + 1] + BN_EPS)) + beta[c + 1];
    v0 = v0 > 0.f ? v0 : expm1f(v0);
    v1 = v1 > 0.f ? v1 : expm1f(v1);
    float2 o = make_float2(v0, v1);
    *reinterpret_cast<float2*>(&Xout[(size_t)wid * HIDDEN + c]) = o;
}

// ---------------------------------------------------------------- fused mean-pool + MLP: one block (1024 threads) per graph
// batch is SORTED -> contiguous node range. 32 row-groups x 32 float4 channel
// groups; LDS tree reduce; fc1+fc2 in-block.

__global__ __launch_bounds__(1024) void pool_fc_kernel(
    const float* __restrict__ X, const int* __restrict__ batch,
    const float* __restrict__ fc1w, const float* __restrict__ fc1b,
    const float* __restrict__ fc2w, const float* __restrict__ fc2b,
    float* __restrict__ out) {
    int g = blockIdx.x;
    int tid = threadIdx.x;       // 0..1023
    int cg = (tid & 31) * 4;     // channel group: 0,4,...,124
    int rg = tid >> 5;           // row group: 0..31

    int lo = 0, hi = N_NODES;
    while (lo < hi) { int mid = (lo + hi) >> 1; if (batch[mid] < g) lo = mid + 1; else hi = mid; }
    int lo2 = lo, hi2 = N_NODES;
    while (lo2 < hi2) { int mid = (lo2 + hi2) >> 1; if (batch[mid] < g + 1) lo2 = mid + 1; else hi2 = mid; }

    float ax = 0.f, ay = 0.f, az = 0.f, aw = 0.f;
    for (int i = lo + rg; i < lo2; i += 32) {
        float4 v = *reinterpret_cast<const float4*>(&X[(size_t)i * HIDDEN + cg]);
        ax += v.x; ay += v.y; az += v.z; aw += v.w;
    }

    __shared__ float red[32][132];   // [rg][channel]
    red[rg][cg + 0] = ax; red[rg][cg + 1] = ay;
    red[rg][cg + 2] = az; red[rg][cg + 3] = aw;
    __syncthreads();
#pragma unroll
    for (int step = 16; step >= 1; step >>= 1) {
        if (rg < step) {
            red[rg][cg + 0] += red[rg + step][cg + 0];
            red[rg][cg + 1] += red[rg + step][cg + 1];
            red[rg][cg + 2] += red[rg + step][cg + 2];
            red[rg][cg + 3] += red[rg + step][cg + 3];
        }
        __syncthreads();
    }

    __shared__ float pooled[HIDDEN];
    __shared__ float hmid[64];
    if (rg == 0) {
        float inv = 1.f / fmaxf((float)(lo2 - lo), 1.0f);
        pooled[cg + 0] = red[0][cg + 0] * inv;
        pooled[cg + 1] = red[0][cg + 1] * inv;
        pooled[cg + 2] = red[0][cg + 2] * inv;
        pooled[cg + 3] = red[0][cg + 3] * inv;
    }
    __syncthreads();
    if (tid < 64) {
        float a = fc1b[tid];
#pragma unroll 8
        for (int k = 0; k < 128; ++k) a += pooled[k] * fc1w[k * 64 + tid];
        hmid[tid] = fmaxf(a, 0.f);
    }
    __syncthreads();
    if (tid < 10) {
        float a = fc2b[tid];
#pragma unroll 8
        for (int k = 0; k < 64; ++k) a += hmid[k] * fc2w[k * 10 + tid];
        out[g * 10 + tid] = a;
    }
}

// ---------------------------------------------------------------- launch

static inline size_t align_up(size_t x, size_t a) { return (x + a - 1) & ~(a - 1); }

extern "C" void kernel_launch(void* const* d_in, const int* in_sizes, int n_in,
                              void* d_out, int out_size, void* d_ws, size_t ws_size,
                              hipStream_t stream) {
    const float* x        = (const float*)d_in[0];
    const int*   eidx     = (const int*)d_in[1];   // [2, N_EDGES]
    const int*   batch    = (const int*)d_in[2];
    const float* W        = (const float*)d_in[3];   // [3,128,128]
    const float* att_src  = (const float*)d_in[4];   // [3,4,32]
    const float* att_dst  = (const float*)d_in[5];
    const float* bias     = (const float*)d_in[6];   // [3,128]
    const float* bn_gamma = (const float*)d_in[7];
    const float* bn_beta  = (const float*)d_in[8];
    const float* bn_mean  = (const float*)d_in[9];
    const float* bn_var   = (const float*)d_in[10];
    const float* fc1w     = (const float*)d_in[11];  // [128,64]
    const float* fc1b     = (const float*)d_in[12];
    const float* fc2w     = (const float*)d_in[13];  // [64,10]
    const float* fc2b     = (const float*)d_in[14];
    float* out = (float*)d_out;

    const int* src = eidx;
    const int* dst = eidx + N_EDGES;

    // ---- workspace layout
    char* p = (char*)d_ws;
    size_t off = 0;
    auto alloc = [&](size_t bytes) {
        size_t o = off;
        off = align_up(off + bytes, 256);
        return (void*)(p + o);
    };
    __half* Hh     = (__half*)alloc((size_t)N_NODES * HIDDEN * 2);
    float* Xbuf    = (float*)alloc((size_t)N_NODES * HIDDEN * 4);
    float* as4     = (float*)alloc((size_t)N_NODES * HEADS * 4);
    float* ad4     = (float*)alloc((size_t)N_NODES * HEADS * 4);
    int*   deg     = (int*)alloc((size_t)N_NODES * 4);
    int*   rowoff  = (int*)alloc((size_t)(N_NODES + 1) * 4);
    int*   rank    = (int*)alloc((size_t)E_TOTAL * 4);
    int*   bsum    = (int*)alloc((size_t)NBLK_SCAN * 4);
    int*   col     = (int*)alloc((size_t)E_TOTAL * 4);
    (void)n_in; (void)in_sizes; (void)out_size; (void)ws_size;

    // ---- zero fill (deg only)
    zero_kernel<<<(N_NODES + 255) / 256, 256, 0, stream>>>((unsigned int*)deg, N_NODES);

    // ---- CSR build (by destination), once per call
    hist_kernel<<<(E_TOTAL + 255) / 256, 256, 0, stream>>>(dst, deg, rank);
    scan1_kernel<<<NBLK_SCAN, 256, 0, stream>>>(deg, rowoff, bsum, N_NODES);
    scan2_kernel<<<1, 256, 0, stream>>>(bsum, NBLK_SCAN);
    scan3_kernel<<<NBLK_SCAN, 256, 0, stream>>>(bsum, rowoff, N_NODES);
    scatter_kernel<<<(E_TOTAL + 255) / 256, 256, 0, stream>>>(src, dst, rowoff, rank, col);

    // ---- 3 GAT layers
    const float* xcur = x;
    for (int layer = 0; layer < NUM_LAYERS; ++layer) {
        const float* Wl  = W + (size_t)layer * HIDDEN * HIDDEN;
        const float* asl = att_src + (size_t)layer * HEADS * OUT_CH;
        const float* adl = att_dst + (size_t)layer * HEADS * OUT_CH;
        const float* bl  = bias + (size_t)layer * HIDDEN;
        const float* gl  = bn_gamma + (size_t)layer * HIDDEN;
        const float* btl = bn_beta + (size_t)layer * HIDDEN;
        const float* ml  = bn_mean + (size_t)layer * HIDDEN;
        const float* vl  = bn_var + (size_t)layer * HIDDEN;

        gemm_xw<<<(N_NODES + 31) / 32, 256, 0, stream>>>(xcur, Wl, asl, adl, Hh, as4, ad4, N_NODES);
        aggregate_kernel<<<(N_NODES * 64 + 255) / 256, 256, 0, stream>>>(
            (const __half2*)Hh, as4, ad4, rowoff, col, bl, gl, btl, ml, vl, Xbuf, N_NODES);
        xcur = Xbuf;
    }

    // ---- fused pool + MLP (batch sorted -> contiguous ranges, no atomics)
    pool_fc_kernel<<<N_GRAPHS, 1024, 0, stream>>>(xcur, batch, fc1w, fc1b, fc2w, fc2b, out);
}

// Round 14
// 383.664 us; speedup vs baseline: 2.3223x; 1.0003x over previous
//
#include <hip/hip_runtime.h>
#include <hip/hip_fp16.h>
#include <math.h>

#define N_NODES 50000
#define N_EDGES 800000
#define E_TOTAL (N_EDGES + N_NODES)   // self-loops appended
#define N_GRAPHS 256
#define HEADS 4
#define OUT_CH 32
#define HIDDEN 128
#define NUM_LAYERS 3
#define NEG_SLOPE 0.2f
#define BN_EPS 1e-5f
#define NBLK_SCAN ((N_NODES + 255) / 256)   // 196

// ---------------------------------------------------------------- utilities

__global__ void zero_kernel(unsigned int* __restrict__ p, int n) {
    int i = blockIdx.x * blockDim.x + threadIdx.x;
    if (i < n) p[i] = 0u;
}

// ---------------------------------------------------------------- CSR build
// hist also assigns each edge its within-row rank (old deg value) so the
// scatter pass needs no atomic.

__global__ void hist_kernel(const int* __restrict__ dst, int* __restrict__ deg,
                            int* __restrict__ rank) {
    int e = blockIdx.x * blockDim.x + threadIdx.x;
    if (e >= E_TOTAL) return;
    int d = (e < N_EDGES) ? dst[e] : (e - N_EDGES);
    rank[e] = atomicAdd(&deg[d], 1);
}

// hierarchical scan: stage 1 — per-block inclusive scan (256 elems/block)
__global__ __launch_bounds__(256) void scan1_kernel(const int* __restrict__ deg,
                                                    int* __restrict__ rowoff,
                                                    int* __restrict__ bsum, int n) {
    int i = blockIdx.x * 256 + threadIdx.x;
    int v = (i < n) ? deg[i] : 0;
    int lane = threadIdx.x & 63, wv = threadIdx.x >> 6;
    int s = v;
    for (int off = 1; off < 64; off <<= 1) {
        int u = __shfl_up(s, off);
        if (lane >= off) s += u;
    }
    __shared__ int wtot[4];
    if (lane == 63) wtot[wv] = s;
    __syncthreads();
    int add = 0;
    for (int w = 0; w < wv; ++w) add += wtot[w];
    s += add;
    if (i < n) rowoff[i + 1] = s;
    if (threadIdx.x == 255) bsum[blockIdx.x] = s;
}

// stage 2 — single block: exclusive scan of block sums (in place)
__global__ __launch_bounds__(256) void scan2_kernel(int* __restrict__ bsum, int nb) {
    int t = threadIdx.x;
    int v = (t < nb) ? bsum[t] : 0;
    int lane = t & 63, wv = t >> 6;
    int s = v;
    for (int off = 1; off < 64; off <<= 1) {
        int u = __shfl_up(s, off);
        if (lane >= off) s += u;
    }
    __shared__ int wtot[4];
    if (lane == 63) wtot[wv] = s;
    __syncthreads();
    int add = 0;
    for (int w = 0; w < wv; ++w) add += wtot[w];
    s += add;
    if (t < nb) bsum[t] = s - v;   // exclusive
}

// stage 3 — add block prefix back
__global__ __launch_bounds__(256) void scan3_kernel(const int* __restrict__ bsum,
                                                    int* __restrict__ rowoff, int n) {
    int i = blockIdx.x * 256 + threadIdx.x;
    if (i == 0) rowoff[0] = 0;
    if (i < n) rowoff[i + 1] += bsum[blockIdx.x];
}

// no atomic: pos = rowoff[d] + rank[e]; single 4B write per edge
__global__ void scatter_kernel(const int* __restrict__ src, const int* __restrict__ dst,
                               const int* __restrict__ rowoff, const int* __restrict__ rank,
                               int* __restrict__ col) {
    int e = blockIdx.x * blockDim.x + threadIdx.x;
    if (e >= E_TOTAL) return;
    int s, d;
    if (e < N_EDGES) { s = src[e]; d = dst[e]; }
    else             { s = e - N_EDGES; d = s; }
    int pos = rowoff[d] + rank[e];
    col[pos] = s;
}

// ---------------------------------------------------------------- GEMM h = X @ W (n x 128 @ 128 x 128)
// X tile stored transposed in LDS (XOR-swizzled row groups). Inner loop:
// 2x ds_read_b128 + 16 FMA. Epilogue: fp32 attention dots (as4/ad4) via 8-lane
// butterfly, then H written as FP16 (halves the aggregate gather bytes).

__global__ __launch_bounds__(256) void gemm_xw(const float* __restrict__ X,
                                               const float* __restrict__ W,
                                               const float* __restrict__ att_src,
                                               const float* __restrict__ att_dst,
                                               __half* __restrict__ Hh,
                                               float* __restrict__ as4,
                                               float* __restrict__ ad4, int n) {
    __shared__ float xst[32][36];    // [kk][swizzled r]
    __shared__ float ws[32][128];    // 32 k x 128 cols
    const int row0 = blockIdx.x * 32;
    const int cg = threadIdx.x & 31;   // col group: cols cg*4..cg*4+3
    const int rg = threadIdx.x >> 5;   // row group: rows rg*4..rg*4+3
    float acc[4][4];
#pragma unroll
    for (int r = 0; r < 4; ++r)
#pragma unroll
        for (int j = 0; j < 4; ++j) acc[r][j] = 0.f;

    for (int k0 = 0; k0 < 128; k0 += 32) {
        {
            int r = threadIdx.x >> 3;          // 0..31
            int kk = (threadIdx.x & 7) * 4;    // 0,4,..,28
            int swz = (kk >> 2) & 7;           // uniform for kk..kk+3
            int cswz = (((r >> 2) ^ swz) << 2) | (r & 3);
            int gr = row0 + r;
            float4 v = make_float4(0.f, 0.f, 0.f, 0.f);
            if (gr < n) v = *reinterpret_cast<const float4*>(&X[gr * 128 + k0 + kk]);
            xst[kk + 0][cswz] = v.x; xst[kk + 1][cswz] = v.y;
            xst[kk + 2][cswz] = v.z; xst[kk + 3][cswz] = v.w;
        }
        for (int i = threadIdx.x; i < 32 * 128 / 4; i += 256) {
            int p = i * 4;
            int kk = p >> 7, cc = p & 127;
            *reinterpret_cast<float4*>(&ws[kk][cc]) =
                *reinterpret_cast<const float4*>(&W[(k0 + kk) * 128 + cc]);
        }
        __syncthreads();
#pragma unroll
        for (int kk = 0; kk < 32; ++kk) {
            const int swz = (kk >> 2) & 7;
            float4 wv = *reinterpret_cast<const float4*>(&ws[kk][cg * 4]);
            float4 xv = *reinterpret_cast<const float4*>(&xst[kk][((rg ^ swz) << 2)]);
            acc[0][0] += xv.x * wv.x; acc[0][1] += xv.x * wv.y; acc[0][2] += xv.x * wv.z; acc[0][3] += xv.x * wv.w;
            acc[1][0] += xv.y * wv.x; acc[1][1] += xv.y * wv.y; acc[1][2] += xv.y * wv.z; acc[1][3] += xv.y * wv.w;
            acc[2][0] += xv.z * wv.x; acc[2][1] += xv.z * wv.y; acc[2][2] += xv.z * wv.z; acc[2][3] += xv.z * wv.w;
            acc[3][0] += xv.w * wv.x; acc[3][1] += xv.w * wv.y; acc[3][2] += xv.w * wv.z; acc[3][3] += xv.w * wv.w;
        }
        __syncthreads();
    }

    // write H tile as fp16 (8B per row-fragment)
#pragma unroll
    for (int r = 0; r < 4; ++r) {
        int gr = row0 + rg * 4 + r;
        if (gr < n) {
            __half2 ab = __floats2half2_rn(acc[r][0], acc[r][1]);
            __half2 cd = __floats2half2_rn(acc[r][2], acc[r][3]);
            uint2 u;
            u.x = *reinterpret_cast<unsigned*>(&ab);
            u.y = *reinterpret_cast<unsigned*>(&cd);
            *reinterpret_cast<uint2*>(&Hh[(size_t)gr * 128 + cg * 4]) = u;
        }
    }

    // fp32 attention coefficients from the fp32 accumulators
    const int h = cg >> 3;
    const int co = (cg & 7) * 4;
    float4 asw = *reinterpret_cast<const float4*>(att_src + h * OUT_CH + co);
    float4 adw = *reinterpret_cast<const float4*>(att_dst + h * OUT_CH + co);
#pragma unroll
    for (int r = 0; r < 4; ++r) {
        float s = acc[r][0] * asw.x + acc[r][1] * asw.y + acc[r][2] * asw.z + acc[r][3] * asw.w;
        float d = acc[r][0] * adw.x + acc[r][1] * adw.y + acc[r][2] * adw.z + acc[r][3] * adw.w;
        s += __shfl_xor(s, 1); d += __shfl_xor(d, 1);
        s += __shfl_xor(s, 2); d += __shfl_xor(d, 2);
        s += __shfl_xor(s, 4); d += __shfl_xor(d, 4);
        if ((cg & 7) == 0) {
            int gr = row0 + rg * 4 + r;
            if (gr < n) {
                as4[gr * 4 + h] = s;
                ad4[gr * 4 + h] = d;
            }
        }
    }
}

// ---------------------------------------------------------------- fused aggregation: edge-softmax + message sum + bias + BN + ELU
// one wave per destination node; lane l owns channels 2l, 2l+1 (head = l>>4).
// Cooperative scoring: at each 64-edge chunk, lane l computes the 4 head
// exp-scores of ITS edge (1 float4 load + 4 exp) into LDS; the inner loop
// reads esc_s[wv][t][hd] as a broadcast ds_read. 16x fewer transcendentals
// than inline-per-lane. Same-wave ds_write->ds_read is ordered (LDS FIFO),
// no block barrier (waves run divergent trip counts).

__global__ __launch_bounds__(256) void aggregate_kernel(
    const __half2* __restrict__ Hh2, const float* __restrict__ as4, const float* __restrict__ ad4,
    const int* __restrict__ rowoff, const int* __restrict__ col,
    const float* __restrict__ bias, const float* __restrict__ gamma, const float* __restrict__ beta,
    const float* __restrict__ mean, const float* __restrict__ var,
    float* __restrict__ Xout, int n) {
    __shared__ float4 esc_s[4][64];   // [wave][edge-in-chunk] -> 4 head exp-scores
    int wid = (blockIdx.x * blockDim.x + threadIdx.x) >> 6;
    if (wid >= n) return;
    int lane = threadIdx.x & 63;
    int wv = (threadIdx.x >> 6) & 3;
    int hd = lane >> 4;          // head 0..3
    int c = lane * 2;            // channels c, c+1 (same head)

    float4 adv4 = *reinterpret_cast<const float4*>(&ad4[wid * 4]);
    const float* escp = reinterpret_cast<const float*>(&esc_s[wv][0]);

    int jbeg = rowoff[wid], jend = rowoff[wid + 1];

    float s = 0.f, ax = 0.f, ay = 0.f;

    for (int base = jbeg; base < jend; base += 64) {
        int myj = base + lane;
        int mysrc = (myj < jend) ? col[myj] : 0;
        int cnt = min(64, jend - base);

        // cooperative scoring for this chunk: my edge, all 4 heads
        {
            float4 a = *reinterpret_cast<const float4*>(&as4[mysrc * 4]);
            float x0 = a.x + adv4.x; x0 = x0 > 0.f ? x0 : x0 * NEG_SLOPE;
            float x1 = a.y + adv4.y; x1 = x1 > 0.f ? x1 : x1 * NEG_SLOPE;
            float x2 = a.z + adv4.z; x2 = x2 > 0.f ? x2 : x2 * NEG_SLOPE;
            float x3 = a.w + adv4.w; x3 = x3 > 0.f ? x3 : x3 * NEG_SLOPE;
            esc_s[wv][lane] = make_float4(__expf(x0), __expf(x1), __expf(x2), __expf(x3));
        }

        int t = 0;
#pragma unroll 1
        for (; t + 8 <= cnt; t += 8) {
            int s0 = __shfl(mysrc, t + 0);
            int s1 = __shfl(mysrc, t + 1);
            int s2 = __shfl(mysrc, t + 2);
            int s3 = __shfl(mysrc, t + 3);
            int s4 = __shfl(mysrc, t + 4);
            int s5 = __shfl(mysrc, t + 5);
            int s6 = __shfl(mysrc, t + 6);
            int s7 = __shfl(mysrc, t + 7);
            float e0 = escp[(t + 0) * 4 + hd];
            float e1 = escp[(t + 1) * 4 + hd];
            float e2 = escp[(t + 2) * 4 + hd];
            float e3 = escp[(t + 3) * 4 + hd];
            float e4 = escp[(t + 4) * 4 + hd];
            float e5 = escp[(t + 5) * 4 + hd];
            float e6 = escp[(t + 6) * 4 + hd];
            float e7 = escp[(t + 7) * 4 + hd];
            float2 h0 = __half22float2(Hh2[(size_t)s0 * 64 + lane]);
            float2 h1 = __half22float2(Hh2[(size_t)s1 * 64 + lane]);
            float2 h2 = __half22float2(Hh2[(size_t)s2 * 64 + lane]);
            float2 h3 = __half22float2(Hh2[(size_t)s3 * 64 + lane]);
            float2 h4 = __half22float2(Hh2[(size_t)s4 * 64 + lane]);
            float2 h5 = __half22float2(Hh2[(size_t)s5 * 64 + lane]);
            float2 h6 = __half22float2(Hh2[(size_t)s6 * 64 + lane]);
            float2 h7 = __half22float2(Hh2[(size_t)s7 * 64 + lane]);
            s  += ((e0 + e1) + (e2 + e3)) + ((e4 + e5) + (e6 + e7));
            ax += e0 * h0.x + e1 * h1.x + e2 * h2.x + e3 * h3.x
                + e4 * h4.x + e5 * h5.x + e6 * h6.x + e7 * h7.x;
            ay += e0 * h0.y + e1 * h1.y + e2 * h2.y + e3 * h3.y
                + e4 * h4.y + e5 * h5.y + e6 * h6.y + e7 * h7.y;
        }
        for (; t < cnt; ++t) {
            int src = __shfl(mysrc, t);
            float e = escp[t * 4 + hd];
            float2 hv = __half22float2(Hh2[(size_t)src * 64 + lane]);
            s += e;
            ax += e * hv.x;
            ay += e * hv.y;
        }
    }

    float inv = 1.f / s;
    float v0 = ax * inv + bias[c];
    float v1 = ay * inv + bias[c + 1];
    v0 = (v0 - mean[c])     * (gamma[c]     * rsqrtf(var[c]     + BN_EPS)) + beta[c];
    v1 = (v1 - mean[c + 1]) * (gamma[c + 1] * rsqrtf(var[c + 1] + BN_EPS)) + beta[c + 1];
    v0 = v0 > 0.f ? v0 : expm1f(v0);
    v1 = v1 > 0.f ? v1 : expm1f(v1);
    float2 o = make_float2(v0, v1);
    *reinterpret_cast<float2*>(&Xout[(size_t)wid * HIDDEN + c]) = o;
}

// ---------------------------------------------------------------- fused mean-pool + MLP: one block (1024 threads) per graph
// batch is SORTED -> contiguous node range. 32 row-groups x 32 float4 channel
// groups; LDS tree reduce; fc1+fc2 in-block.

__global__ __launch_bounds__(1024) void pool_fc_kernel(
    const float* __restrict__ X, const int* __restrict__ batch,
    const float* __restrict__ fc1w, const float* __restrict__ fc1b,
    const float* __restrict__ fc2w, const float* __restrict__ fc2b,
    float* __restrict__ out) {
    int g = blockIdx.x;
    int tid = threadIdx.x;       // 0..1023
    int cg = (tid & 31) * 4;     // channel group: 0,4,...,124
    int rg = tid >> 5;           // row group: 0..31

    int lo = 0, hi = N_NODES;
    while (lo < hi) { int mid = (lo + hi) >> 1; if (batch[mid] < g) lo = mid + 1; else hi = mid; }
    int lo2 = lo, hi2 = N_NODES;
    while (lo2 < hi2) { int mid = (lo2 + hi2) >> 1; if (batch[mid] < g + 1) lo2 = mid + 1; else hi2 = mid; }

    float ax = 0.f, ay = 0.f, az = 0.f, aw = 0.f;
    for (int i = lo + rg; i < lo2; i += 32) {
        float4 v = *reinterpret_cast<const float4*>(&X[(size_t)i * HIDDEN + cg]);
        ax += v.x; ay += v.y; az += v.z; aw += v.w;
    }

    __shared__ float red[32][132];   // [rg][channel]
    red[rg][cg + 0] = ax; red[rg][cg + 1] = ay;
    red[rg][cg + 2] = az; red[rg][cg + 3] = aw;
    __syncthreads();
#pragma unroll
    for (int step = 16; step >= 1; step >>= 1) {
        if (rg < step) {
            red[rg][cg + 0] += red[rg + step][cg + 0];
            red[rg][cg + 1] += red[rg + step][cg + 1];
            red[rg][cg + 2] += red[rg + step][cg + 2];
            red[rg][cg + 3] += red[rg + step][cg + 3];
        }
        __syncthreads();
    }

    __shared__ float pooled[HIDDEN];
    __shared__ float hmid[64];
    if (rg == 0) {
        float inv = 1.f / fmaxf((float)(lo2 - lo), 1.0f);
        pooled[cg + 0] = red[0][cg + 0] * inv;
        pooled[cg + 1] = red[0][cg + 1] * inv;
        pooled[cg + 2] = red[0][cg + 2] * inv;
        pooled[cg + 3] = red[0][cg + 3] * inv;
    }
    __syncthreads();
    if (tid < 64) {
        float a = fc1b[tid];
#pragma unroll 8
        for (int k = 0; k < 128; ++k) a += pooled[k] * fc1w[k * 64 + tid];
        hmid[tid] = fmaxf(a, 0.f);
    }
    __syncthreads();
    if (tid < 10) {
        float a = fc2b[tid];
#pragma unroll 8
        for (int k = 0; k < 64; ++k) a += hmid[k] * fc2w[k * 10 + tid];
        out[g * 10 + tid] = a;
    }
}

// ---------------------------------------------------------------- launch

static inline size_t align_up(size_t x, size_t a) { return (x + a - 1) & ~(a - 1); }

extern "C" void kernel_launch(void* const* d_in, const int* in_sizes, int n_in,
                              void* d_out, int out_size, void* d_ws, size_t ws_size,
                              hipStream_t stream) {
    const float* x        = (const float*)d_in[0];
    const int*   eidx     = (const int*)d_in[1];   // [2, N_EDGES]
    const int*   batch    = (const int*)d_in[2];
    const float* W        = (const float*)d_in[3];   // [3,128,128]
    const float* att_src  = (const float*)d_in[4];   // [3,4,32]
    const float* att_dst  = (const float*)d_in[5];
    const float* bias     = (const float*)d_in[6];   // [3,128]
    const float* bn_gamma = (const float*)d_in[7];
    const float* bn_beta  = (const float*)d_in[8];
    const float* bn_mean  = (const float*)d_in[9];
    const float* bn_var   = (const float*)d_in[10];
    const float* fc1w     = (const float*)d_in[11];  // [128,64]
    const float* fc1b     = (const float*)d_in[12];
    const float* fc2w     = (const float*)d_in[13];  // [64,10]
    const float* fc2b     = (const float*)d_in[14];
    float* out = (float*)d_out;

    const int* src = eidx;
    const int* dst = eidx + N_EDGES;

    // ---- workspace layout
    char* p = (char*)d_ws;
    size_t off = 0;
    auto alloc = [&](size_t bytes) {
        size_t o = off;
        off = align_up(off + bytes, 256);
        return (void*)(p + o);
    };
    __half* Hh     = (__half*)alloc((size_t)N_NODES * HIDDEN * 2);
    float* Xbuf    = (float*)alloc((size_t)N_NODES * HIDDEN * 4);
    float* as4     = (float*)alloc((size_t)N_NODES * HEADS * 4);
    float* ad4     = (float*)alloc((size_t)N_NODES * HEADS * 4);
    int*   deg     = (int*)alloc((size_t)N_NODES * 4);
    int*   rowoff  = (int*)alloc((size_t)(N_NODES + 1) * 4);
    int*   rank    = (int*)alloc((size_t)E_TOTAL * 4);
    int*   bsum    = (int*)alloc((size_t)NBLK_SCAN * 4);
    int*   col     = (int*)alloc((size_t)E_TOTAL * 4);
    (void)n_in; (void)in_sizes; (void)out_size; (void)ws_size;

    // ---- zero fill (deg only)
    zero_kernel<<<(N_NODES + 255) / 256, 256, 0, stream>>>((unsigned int*)deg, N_NODES);

    // ---- CSR build (by destination), once per call
    hist_kernel<<<(E_TOTAL + 255) / 256, 256, 0, stream>>>(dst, deg, rank);
    scan1_kernel<<<NBLK_SCAN, 256, 0, stream>>>(deg, rowoff, bsum, N_NODES);
    scan2_kernel<<<1, 256, 0, stream>>>(bsum, NBLK_SCAN);
    scan3_kernel<<<NBLK_SCAN, 256, 0, stream>>>(bsum, rowoff, N_NODES);
    scatter_kernel<<<(E_TOTAL + 255) / 256, 256, 0, stream>>>(src, dst, rowoff, rank, col);

    // ---- 3 GAT layers
    const float* xcur = x;
    for (int layer = 0; layer < NUM_LAYERS; ++layer) {
        const float* Wl  = W + (size_t)layer * HIDDEN * HIDDEN;
        const float* asl = att_src + (size_t)layer * HEADS * OUT_CH;
        const float* adl = att_dst + (size_t)layer * HEADS * OUT_CH;
        const float* bl  = bias + (size_t)layer * HIDDEN;
        const float* gl  = bn_gamma + (size_t)layer * HIDDEN;
        const float* btl = bn_beta + (size_t)layer * HIDDEN;
        const float* ml  = bn_mean + (size_t)layer * HIDDEN;
        const float* vl  = bn_var + (size_t)layer * HIDDEN;

        gemm_xw<<<(N_NODES + 31) / 32, 256, 0, stream>>>(xcur, Wl, asl, adl, Hh, as4, ad4, N_NODES);
        aggregate_kernel<<<(N_NODES * 64 + 255) / 256, 256, 0, stream>>>(
            (const __half2*)Hh, as4, ad4, rowoff, col, bl, gl, btl, ml, vl, Xbuf, N_NODES);
        xcur = Xbuf;
    }

    // ---- fused pool + MLP (batch sorted -> contiguous ranges, no atomics)
    pool_fc_kernel<<<N_GRAPHS, 1024, 0, stream>>>(xcur, batch, fc1w, fc1b, fc2w, fc2b, out);
}

// Round 15
// 372.760 us; speedup vs baseline: 2.3902x; 1.0293x over previous
//
#include <hip/hip_runtime.h>
#include <hip/hip_fp16.h>
#include <math.h>

#define N_NODES 50000
#define N_EDGES 800000
#define E_TOTAL (N_EDGES + N_NODES)   // self-loops appended
#define N_GRAPHS 256
#define HEADS 4
#define OUT_CH 32
#define HIDDEN 128
#define NUM_LAYERS 3
#define NEG_SLOPE 0.2f
#define BN_EPS 1e-5f
#define NBLK_SCAN ((N_NODES + 255) / 256)   // 196

typedef _Float16 half8v __attribute__((ext_vector_type(8)));
typedef float float4v __attribute__((ext_vector_type(4)));

// ---------------------------------------------------------------- utilities

__global__ void zero_kernel(unsigned int* __restrict__ p, int n) {
    int i = blockIdx.x * blockDim.x + threadIdx.x;
    if (i < n) p[i] = 0u;
}

// ---------------------------------------------------------------- CSR build

__global__ void hist_kernel(const int* __restrict__ dst, int* __restrict__ deg,
                            int* __restrict__ rank) {
    int e = blockIdx.x * blockDim.x + threadIdx.x;
    if (e >= E_TOTAL) return;
    int d = (e < N_EDGES) ? dst[e] : (e - N_EDGES);
    rank[e] = atomicAdd(&deg[d], 1);
}

__global__ __launch_bounds__(256) void scan1_kernel(const int* __restrict__ deg,
                                                    int* __restrict__ rowoff,
                                                    int* __restrict__ bsum, int n) {
    int i = blockIdx.x * 256 + threadIdx.x;
    int v = (i < n) ? deg[i] : 0;
    int lane = threadIdx.x & 63, wv = threadIdx.x >> 6;
    int s = v;
    for (int off = 1; off < 64; off <<= 1) {
        int u = __shfl_up(s, off);
        if (lane >= off) s += u;
    }
    __shared__ int wtot[4];
    if (lane == 63) wtot[wv] = s;
    __syncthreads();
    int add = 0;
    for (int w = 0; w < wv; ++w) add += wtot[w];
    s += add;
    if (i < n) rowoff[i + 1] = s;
    if (threadIdx.x == 255) bsum[blockIdx.x] = s;
}

__global__ __launch_bounds__(256) void scan2_kernel(int* __restrict__ bsum, int nb) {
    int t = threadIdx.x;
    int v = (t < nb) ? bsum[t] : 0;
    int lane = t & 63, wv = t >> 6;
    int s = v;
    for (int off = 1; off < 64; off <<= 1) {
        int u = __shfl_up(s, off);
        if (lane >= off) s += u;
    }
    __shared__ int wtot[4];
    if (lane == 63) wtot[wv] = s;
    __syncthreads();
    int add = 0;
    for (int w = 0; w < wv; ++w) add += wtot[w];
    s += add;
    if (t < nb) bsum[t] = s - v;   // exclusive
}

__global__ __launch_bounds__(256) void scan3_kernel(const int* __restrict__ bsum,
                                                    int* __restrict__ rowoff, int n) {
    int i = blockIdx.x * 256 + threadIdx.x;
    if (i == 0) rowoff[0] = 0;
    if (i < n) rowoff[i + 1] += bsum[blockIdx.x];
}

__global__ void scatter_kernel(const int* __restrict__ src, const int* __restrict__ dst,
                               const int* __restrict__ rowoff, const int* __restrict__ rank,
                               int* __restrict__ col) {
    int e = blockIdx.x * blockDim.x + threadIdx.x;
    if (e >= E_TOTAL) return;
    int s, d;
    if (e < N_EDGES) { s = src[e]; d = dst[e]; }
    else             { s = e - N_EDGES; d = s; }
    int pos = rowoff[d] + rank[e];
    col[pos] = s;
}

// ---------------------------------------------------------------- GEMM h = X @ W via fp16 MFMA (fp32 accum), no LDS.
// Block: 256 threads = 4 waves, 32 output rows x 128 cols. Wave w = head w,
// cols [32w, 32w+32): 2 m-tiles x 2 c-tiles, mfma_f32_16x16x32_f16 x 4 per
// k-chunk, K=128 in 4 chunks. A-frag: row=lane&15, k=(lane>>4)*8+j (32B
// contiguous global read). B-frag: col=lane&15, k=(lane>>4)*8+j (16-lane
// rows coalesce to 64B segments; W is L2-resident). C/D: col=lane&15,
// row=(lane>>4)*4+i (verified layout). Epilogue: H as fp16; alpha dots
// reduced over the 16-lane col group via shfl_xor 1/2/4/8.

__global__ __launch_bounds__(256) void gemm_xw(const float* __restrict__ X,
                                               const float* __restrict__ W,
                                               const float* __restrict__ att_src,
                                               const float* __restrict__ att_dst,
                                               __half* __restrict__ Hh,
                                               float* __restrict__ as4,
                                               float* __restrict__ ad4, int n) {
    const int row0 = blockIdx.x * 32;
    const int lane = threadIdx.x & 63;
    const int w = threadIdx.x >> 6;      // wave id == head id
    const int cw = w * 32;               // wave's col base
    const int r16 = lane & 15;
    const int g = lane >> 4;             // 0..3

    float4v acc[2][2];
#pragma unroll
    for (int m = 0; m < 2; ++m)
#pragma unroll
        for (int ct = 0; ct < 2; ++ct)
#pragma unroll
            for (int i = 0; i < 4; ++i) acc[m][ct][i] = 0.f;

#pragma unroll
    for (int k0 = 0; k0 < 128; k0 += 32) {
        const int kk = k0 + g * 8;
        half8v a[2], b[2];
        // A fragments (2 m-tiles): 8 consecutive fp32 -> fp16
#pragma unroll
        for (int m = 0; m < 2; ++m) {
            int gr = row0 + m * 16 + r16;
            float4 x0 = make_float4(0.f, 0.f, 0.f, 0.f);
            float4 x1 = make_float4(0.f, 0.f, 0.f, 0.f);
            if (gr < n) {
                const float* xp = &X[(size_t)gr * 128 + kk];
                x0 = *reinterpret_cast<const float4*>(xp);
                x1 = *reinterpret_cast<const float4*>(xp + 4);
            }
            a[m][0] = (_Float16)x0.x; a[m][1] = (_Float16)x0.y;
            a[m][2] = (_Float16)x0.z; a[m][3] = (_Float16)x0.w;
            a[m][4] = (_Float16)x1.x; a[m][5] = (_Float16)x1.y;
            a[m][6] = (_Float16)x1.z; a[m][7] = (_Float16)x1.w;
        }
        // B fragments (2 c-tiles): 8 strided fp32 rows of W
#pragma unroll
        for (int ct = 0; ct < 2; ++ct) {
            const float* wp = &W[(size_t)kk * 128 + cw + ct * 16 + r16];
#pragma unroll
            for (int j = 0; j < 8; ++j) b[ct][j] = (_Float16)wp[(size_t)j * 128];
        }
#pragma unroll
        for (int m = 0; m < 2; ++m)
#pragma unroll
            for (int ct = 0; ct < 2; ++ct)
                acc[m][ct] = __builtin_amdgcn_mfma_f32_16x16x32_f16(a[m], b[ct], acc[m][ct], 0, 0, 0);
    }

    // H write (fp16): row = row0 + m*16 + g*4 + i, col = cw + ct*16 + r16
#pragma unroll
    for (int m = 0; m < 2; ++m)
#pragma unroll
        for (int i = 0; i < 4; ++i) {
            int gr = row0 + m * 16 + g * 4 + i;
            if (gr < n) {
#pragma unroll
                for (int ct = 0; ct < 2; ++ct)
                    Hh[(size_t)gr * 128 + cw + ct * 16 + r16] = (__half)acc[m][ct][i];
            }
        }

    // attention coefficients for head w: dot over this wave's 32 cols
    float asw0 = att_src[cw + r16];
    float asw1 = att_src[cw + 16 + r16];
    float adw0 = att_dst[cw + r16];
    float adw1 = att_dst[cw + 16 + r16];
#pragma unroll
    for (int m = 0; m < 2; ++m)
#pragma unroll
        for (int i = 0; i < 4; ++i) {
            float s = acc[m][0][i] * asw0 + acc[m][1][i] * asw1;
            float d = acc[m][0][i] * adw0 + acc[m][1][i] * adw1;
            s += __shfl_xor(s, 1); d += __shfl_xor(d, 1);
            s += __shfl_xor(s, 2); d += __shfl_xor(d, 2);
            s += __shfl_xor(s, 4); d += __shfl_xor(d, 4);
            s += __shfl_xor(s, 8); d += __shfl_xor(d, 8);
            if (r16 == 0) {
                int gr = row0 + m * 16 + g * 4 + i;
                if (gr < n) {
                    as4[gr * 4 + w] = s;
                    ad4[gr * 4 + w] = d;
                }
            }
        }
}

// ---------------------------------------------------------------- fused aggregation: edge-softmax + message sum + bias + BN + ELU
// one wave per destination node; lane l owns channels 2l, 2l+1 (head = l>>4).
// Cooperative scoring (LDS, 1 float4 + 4 exp per lane per chunk) + wave-
// uniform col[] reads (readfirstlane base -> scalar-pipe loads, no shfl).

__global__ __launch_bounds__(256) void aggregate_kernel(
    const __half2* __restrict__ Hh2, const float* __restrict__ as4, const float* __restrict__ ad4,
    const int* __restrict__ rowoff, const int* __restrict__ col,
    const float* __restrict__ bias, const float* __restrict__ gamma, const float* __restrict__ beta,
    const float* __restrict__ mean, const float* __restrict__ var,
    float* __restrict__ Xout, int n) {
    __shared__ float4 esc_s[4][64];   // [wave][edge-in-chunk] -> 4 head exp-scores
    int wid = (blockIdx.x * blockDim.x + threadIdx.x) >> 6;
    if (wid >= n) return;
    int lane = threadIdx.x & 63;
    int wv = (threadIdx.x >> 6) & 3;
    int hd = lane >> 4;          // head 0..3
    int c = lane * 2;            // channels c, c+1 (same head)

    float4 adv4 = *reinterpret_cast<const float4*>(&ad4[wid * 4]);
    const float* escp = reinterpret_cast<const float*>(&esc_s[wv][0]);

    int jbeg = rowoff[wid], jend = rowoff[wid + 1];

    float s = 0.f, ax = 0.f, ay = 0.f;

    for (int base = jbeg; base < jend; base += 64) {
        int myj = base + lane;
        int mysrc = (myj < jend) ? col[myj] : 0;
        int cnt = min(64, jend - base);
        int bu = __builtin_amdgcn_readfirstlane(base);
        const int* cu = col + bu;

        // cooperative scoring for this chunk: my edge, all 4 heads
        {
            float4 a = *reinterpret_cast<const float4*>(&as4[mysrc * 4]);
            float x0 = a.x + adv4.x; x0 = x0 > 0.f ? x0 : x0 * NEG_SLOPE;
            float x1 = a.y + adv4.y; x1 = x1 > 0.f ? x1 : x1 * NEG_SLOPE;
            float x2 = a.z + adv4.z; x2 = x2 > 0.f ? x2 : x2 * NEG_SLOPE;
            float x3 = a.w + adv4.w; x3 = x3 > 0.f ? x3 : x3 * NEG_SLOPE;
            esc_s[wv][lane] = make_float4(__expf(x0), __expf(x1), __expf(x2), __expf(x3));
        }

        int t = 0;
#pragma unroll 1
        for (; t + 8 <= cnt; t += 8) {
            int s0 = cu[t + 0];
            int s1 = cu[t + 1];
            int s2 = cu[t + 2];
            int s3 = cu[t + 3];
            int s4 = cu[t + 4];
            int s5 = cu[t + 5];
            int s6 = cu[t + 6];
            int s7 = cu[t + 7];
            float e0 = escp[(t + 0) * 4 + hd];
            float e1 = escp[(t + 1) * 4 + hd];
            float e2 = escp[(t + 2) * 4 + hd];
            float e3 = escp[(t + 3) * 4 + hd];
            float e4 = escp[(t + 4) * 4 + hd];
            float e5 = escp[(t + 5) * 4 + hd];
            float e6 = escp[(t + 6) * 4 + hd];
            float e7 = escp[(t + 7) * 4 + hd];
            float2 h0 = __half22float2(Hh2[(size_t)s0 * 64 + lane]);
            float2 h1 = __half22float2(Hh2[(size_t)s1 * 64 + lane]);
            float2 h2 = __half22float2(Hh2[(size_t)s2 * 64 + lane]);
            float2 h3 = __half22float2(Hh2[(size_t)s3 * 64 + lane]);
            float2 h4 = __half22float2(Hh2[(size_t)s4 * 64 + lane]);
            float2 h5 = __half22float2(Hh2[(size_t)s5 * 64 + lane]);
            float2 h6 = __half22float2(Hh2[(size_t)s6 * 64 + lane]);
            float2 h7 = __half22float2(Hh2[(size_t)s7 * 64 + lane]);
            s  += ((e0 + e1) + (e2 + e3)) + ((e4 + e5) + (e6 + e7));
            ax += e0 * h0.x + e1 * h1.x + e2 * h2.x + e3 * h3.x
                + e4 * h4.x + e5 * h5.x + e6 * h6.x + e7 * h7.x;
            ay += e0 * h0.y + e1 * h1.y + e2 * h2.y + e3 * h3.y
                + e4 * h4.y + e5 * h5.y + e6 * h6.y + e7 * h7.y;
        }
        for (; t < cnt; ++t) {
            int src = cu[t];
            float e = escp[t * 4 + hd];
            float2 hv = __half22float2(Hh2[(size_t)src * 64 + lane]);
            s += e;
            ax += e * hv.x;
            ay += e * hv.y;
        }
    }

    float inv = 1.f / s;
    float v0 = ax * inv + bias[c];
    float v1 = ay * inv + bias[c + 1];
    v0 = (v0 - mean[c])     * (gamma[c]     * rsqrtf(var[c]     + BN_EPS)) + beta[c];
    v1 = (v1 - mean[c + 1]) * (gamma[c + 1] * rsqrtf(var[c + 1] + BN_EPS)) + beta[c + 1];
    v0 = v0 > 0.f ? v0 : expm1f(v0);
    v1 = v1 > 0.f ? v1 : expm1f(v1);
    float2 o = make_float2(v0, v1);
    *reinterpret_cast<float2*>(&Xout[(size_t)wid * HIDDEN + c]) = o;
}

// ---------------------------------------------------------------- fused mean-pool + MLP: one block (1024 threads) per graph

__global__ __launch_bounds__(1024) void pool_fc_kernel(
    const float* __restrict__ X, const int* __restrict__ batch,
    const float* __restrict__ fc1w, const float* __restrict__ fc1b,
    const float* __restrict__ fc2w, const float* __restrict__ fc2b,
    float* __restrict__ out) {
    int g = blockIdx.x;
    int tid = threadIdx.x;       // 0..1023
    int cg = (tid & 31) * 4;     // channel group: 0,4,...,124
    int rg = tid >> 5;           // row group: 0..31

    int lo = 0, hi = N_NODES;
    while (lo < hi) { int mid = (lo + hi) >> 1; if (batch[mid] < g) lo = mid + 1; else hi = mid; }
    int lo2 = lo, hi2 = N_NODES;
    while (lo2 < hi2) { int mid = (lo2 + hi2) >> 1; if (batch[mid] < g + 1) lo2 = mid + 1; else hi2 = mid; }

    float ax = 0.f, ay = 0.f, az = 0.f, aw = 0.f;
    for (int i = lo + rg; i < lo2; i += 32) {
        float4 v = *reinterpret_cast<const float4*>(&X[(size_t)i * HIDDEN + cg]);
        ax += v.x; ay += v.y; az += v.z; aw += v.w;
    }

    __shared__ float red[32][132];   // [rg][channel]
    red[rg][cg + 0] = ax; red[rg][cg + 1] = ay;
    red[rg][cg + 2] = az; red[rg][cg + 3] = aw;
    __syncthreads();
#pragma unroll
    for (int step = 16; step >= 1; step >>= 1) {
        if (rg < step) {
            red[rg][cg + 0] += red[rg + step][cg + 0];
            red[rg][cg + 1] += red[rg + step][cg + 1];
            red[rg][cg + 2] += red[rg + step][cg + 2];
            red[rg][cg + 3] += red[rg + step][cg + 3];
        }
        __syncthreads();
    }

    __shared__ float pooled[HIDDEN];
    __shared__ float hmid[64];
    if (rg == 0) {
        float inv = 1.f / fmaxf((float)(lo2 - lo), 1.0f);
        pooled[cg + 0] = red[0][cg + 0] * inv;
        pooled[cg + 1] = red[0][cg + 1] * inv;
        pooled[cg + 2] = red[0][cg + 2] * inv;
        pooled[cg + 3] = red[0][cg + 3] * inv;
    }
    __syncthreads();
    if (tid < 64) {
        float a = fc1b[tid];
#pragma unroll 8
        for (int k = 0; k < 128; ++k) a += pooled[k] * fc1w[k * 64 + tid];
        hmid[tid] = fmaxf(a, 0.f);
    }
    __syncthreads();
    if (tid < 10) {
        float a = fc2b[tid];
#pragma unroll 8
        for (int k = 0; k < 64; ++k) a += hmid[k] * fc2w[k * 10 + tid];
        out[g * 10 + tid] = a;
    }
}

// ---------------------------------------------------------------- launch

static inline size_t align_up(size_t x, size_t a) { return (x + a - 1) & ~(a - 1); }

extern "C" void kernel_launch(void* const* d_in, const int* in_sizes, int n_in,
                              void* d_out, int out_size, void* d_ws, size_t ws_size,
                              hipStream_t stream) {
    const float* x        = (const float*)d_in[0];
    const int*   eidx     = (const int*)d_in[1];   // [2, N_EDGES]
    const int*   batch    = (const int*)d_in[2];
    const float* W        = (const float*)d_in[3];   // [3,128,128]
    const float* att_src  = (const float*)d_in[4];   // [3,4,32]
    const float* att_dst  = (const float*)d_in[5];
    const float* bias     = (const float*)d_in[6];   // [3,128]
    const float* bn_gamma = (const float*)d_in[7];
    const float* bn_beta  = (const float*)d_in[8];
    const float* bn_mean  = (const float*)d_in[9];
    const float* bn_var   = (const float*)d_in[10];
    const float* fc1w     = (const float*)d_in[11];  // [128,64]
    const float* fc1b     = (const float*)d_in[12];
    const float* fc2w     = (const float*)d_in[13];  // [64,10]
    const float* fc2b     = (const float*)d_in[14];
    float* out = (float*)d_out;

    const int* src = eidx;
    const int* dst = eidx + N_EDGES;

    // ---- workspace layout
    char* p = (char*)d_ws;
    size_t off = 0;
    auto alloc = [&](size_t bytes) {
        size_t o = off;
        off = align_up(off + bytes, 256);
        return (void*)(p + o);
    };
    __half* Hh     = (__half*)alloc((size_t)N_NODES * HIDDEN * 2);
    float* Xbuf    = (float*)alloc((size_t)N_NODES * HIDDEN * 4);
    float* as4     = (float*)alloc((size_t)N_NODES * HEADS * 4);
    float* ad4     = (float*)alloc((size_t)N_NODES * HEADS * 4);
    int*   deg     = (int*)alloc((size_t)N_NODES * 4);
    int*   rowoff  = (int*)alloc((size_t)(N_NODES + 1) * 4);
    int*   rank    = (int*)alloc((size_t)E_TOTAL * 4);
    int*   bsum    = (int*)alloc((size_t)NBLK_SCAN * 4);
    int*   col     = (int*)alloc((size_t)E_TOTAL * 4);
    (void)n_in; (void)in_sizes; (void)out_size; (void)ws_size;

    // ---- zero fill (deg only)
    zero_kernel<<<(N_NODES + 255) / 256, 256, 0, stream>>>((unsigned int*)deg, N_NODES);

    // ---- CSR build (by destination), once per call
    hist_kernel<<<(E_TOTAL + 255) / 256, 256, 0, stream>>>(dst, deg, rank);
    scan1_kernel<<<NBLK_SCAN, 256, 0, stream>>>(deg, rowoff, bsum, N_NODES);
    scan2_kernel<<<1, 256, 0, stream>>>(bsum, NBLK_SCAN);
    scan3_kernel<<<NBLK_SCAN, 256, 0, stream>>>(bsum, rowoff, N_NODES);
    scatter_kernel<<<(E_TOTAL + 255) / 256, 256, 0, stream>>>(src, dst, rowoff, rank, col);

    // ---- 3 GAT layers
    const float* xcur = x;
    for (int layer = 0; layer < NUM_LAYERS; ++layer) {
        const float* Wl  = W + (size_t)layer * HIDDEN * HIDDEN;
        const float* asl = att_src + (size_t)layer * HEADS * OUT_CH;
        const float* adl = att_dst + (size_t)layer * HEADS * OUT_CH;
        const float* bl  = bias + (size_t)layer * HIDDEN;
        const float* gl  = bn_gamma + (size_t)layer * HIDDEN;
        const float* btl = bn_beta + (size_t)layer * HIDDEN;
        const float* ml  = bn_mean + (size_t)layer * HIDDEN;
        const float* vl  = bn_var + (size_t)layer * HIDDEN;

        gemm_xw<<<(N_NODES + 31) / 32, 256, 0, stream>>>(xcur, Wl, asl, adl, Hh, as4, ad4, N_NODES);
        aggregate_kernel<<<(N_NODES * 64 + 255) / 256, 256, 0, stream>>>(
            (const __half2*)Hh, as4, ad4, rowoff, col, bl, gl, btl, ml, vl, Xbuf, N_NODES);
        xcur = Xbuf;
    }

    // ---- fused pool + MLP (batch sorted -> contiguous ranges, no atomics)
    pool_fc_kernel<<<N_GRAPHS, 1024, 0, stream>>>(xcur, batch, fc1w, fc1b, fc2w, fc2b, out);
}